// Round 1
// baseline (4426.212 us; speedup 1.0000x reference)
//
#include <hip/hip_runtime.h>
#include <hip/hip_bf16.h>
#include <math.h>

// Qwen3Next GatedDeltaNet — round 0: all-fp32 correctness baseline.
// Stages: qkvz/ba GEMM -> causal depthwise conv4 + silu -> l2norm(q,k) ->
//         g/beta -> recurrent delta-rule scan -> gate+RMSnorm -> out GEMM.

#define T_LEN 1024
#define HK_N 16
#define HV_N 32
#define NQKVZ 12288
#define CDIM 8192

// ---------------- generic fp32 tiled GEMM: C[M,N] = A[M,K] @ B[K,N] ----------
__global__ __launch_bounds__(256) void gemm_f32(const float* __restrict__ A,
                                                const float* __restrict__ B,
                                                float* __restrict__ C,
                                                int M, int N, int K) {
  __shared__ __align__(16) float As[16][64];  // [k][m]
  __shared__ __align__(16) float Bs[16][64];  // [k][n]
  const int tid = threadIdx.x;
  const int tx = tid & 15, ty = tid >> 4;
  const int m0 = blockIdx.y * 64, n0 = blockIdx.x * 64;
  const int ar = tid >> 2, akc = (tid & 3) << 2;
  const int bk = tid >> 4, bn = (tid & 15) << 2;
  float acc[4][4] = {};
  for (int k0 = 0; k0 < K; k0 += 16) {
    float4 av = *reinterpret_cast<const float4*>(&A[(size_t)(m0 + ar) * K + k0 + akc]);
    float4 bv = *reinterpret_cast<const float4*>(&B[(size_t)(k0 + bk) * N + n0 + bn]);
    As[akc + 0][ar] = av.x;
    As[akc + 1][ar] = av.y;
    As[akc + 2][ar] = av.z;
    As[akc + 3][ar] = av.w;
    *reinterpret_cast<float4*>(&Bs[bk][bn]) = bv;
    __syncthreads();
#pragma unroll
    for (int kk = 0; kk < 16; ++kk) {
      float a[4], b[4];
#pragma unroll
      for (int i = 0; i < 4; ++i) a[i] = As[kk][ty * 4 + i];
#pragma unroll
      for (int j = 0; j < 4; ++j) b[j] = Bs[kk][tx * 4 + j];
#pragma unroll
      for (int i = 0; i < 4; ++i)
#pragma unroll
        for (int j = 0; j < 4; ++j) acc[i][j] = fmaf(a[i], b[j], acc[i][j]);
    }
    __syncthreads();
  }
#pragma unroll
  for (int i = 0; i < 4; ++i) {
#pragma unroll
    for (int j = 0; j < 4; ++j)
      C[(size_t)(m0 + ty * 4 + i) * N + n0 + tx * 4 + j] = acc[i][j];
  }
}

// ------------- causal depthwise conv (K=4) + silu, with qkvz gather ----------
// channel c: 0..2047 = q (head-major), 2048..4095 = k, 4096..8191 = v
__global__ void conv_silu(const float* __restrict__ qkvz,
                          const float* __restrict__ conv_w,
                          float* __restrict__ QK, float* __restrict__ V) {
  const int c = blockIdx.x * 256 + threadIdx.x;
  const int t = blockIdx.y;
  int col;
  if (c < 2048) {
    col = (c >> 7) * 768 + (c & 127);
  } else if (c < 4096) {
    const int c2 = c - 2048;
    col = (c2 >> 7) * 768 + 128 + (c2 & 127);
  } else {
    const int c2 = c - 4096;
    const int vh = c2 >> 7;
    col = (vh >> 1) * 768 + 256 + (vh & 1) * 128 + (c2 & 127);
  }
  float acc = 0.f;
#pragma unroll
  for (int s = 0; s < 4; ++s) {
    const int tt = t - 3 + s;
    if (tt >= 0) acc = fmaf(qkvz[(size_t)tt * NQKVZ + col], conv_w[c * 4 + s], acc);
  }
  const float y = acc / (1.f + expf(-acc));  // silu
  if (c < 4096) QK[(size_t)t * 4096 + c] = y;
  else          V[(size_t)t * 4096 + (c - 4096)] = y;
}

// ---------------- l2norm over DK for q and k (per t, per k-head) -------------
__global__ void l2norm_qk(float* __restrict__ QK) {
  const int h = blockIdx.x, t = blockIdx.y, l = threadIdx.x;  // 64 threads
  const size_t qb = (size_t)t * 4096 + h * 128;
  const size_t kb = qb + 2048;
  float q0 = QK[qb + l], q1 = QK[qb + l + 64];
  float k0 = QK[kb + l], k1 = QK[kb + l + 64];
  float sq = q0 * q0 + q1 * q1;
  float sk = k0 * k0 + k1 * k1;
#pragma unroll
  for (int off = 32; off; off >>= 1) {
    sq += __shfl_xor(sq, off);
    sk += __shfl_xor(sk, off);
  }
  const float rq = rsqrtf(sq + 1e-6f) * 0.08838834764831845f;  // * DK^-0.5
  const float rk = rsqrtf(sk + 1e-6f);
  QK[qb + l] = q0 * rq; QK[qb + l + 64] = q1 * rq;
  QK[kb + l] = k0 * rk; QK[kb + l + 64] = k1 * rk;
}

// ---------------- beta = sigmoid(b); eg = exp(-exp(A_log)*softplus(a+dt)) ----
__global__ void compute_gb(const float* __restrict__ ba,
                           const float* __restrict__ dt_bias,
                           const float* __restrict__ A_log,
                           float* __restrict__ eg, float* __restrict__ bet) {
  const int idx = blockIdx.x * 256 + threadIdx.x;  // t*32 + vh
  const int t = idx >> 5, vh = idx & 31;
  const float b = ba[t * 64 + (vh >> 1) * 4 + (vh & 1)];
  const float a = ba[t * 64 + (vh >> 1) * 4 + 2 + (vh & 1)];
  const float x = a + dt_bias[vh];
  const float sp = (x > 20.f) ? x : log1pf(expf(x));
  const float g = -expf(A_log[vh]) * sp;
  eg[idx] = expf(g);
  bet[idx] = 1.f / (1.f + expf(-b));
}

// ---------------- recurrent gated delta-rule scan ----------------------------
// One block per v-head (32 blocks x 128 threads). Thread j owns state column
// S[:,j] (128 floats in VGPRs). k/q broadcast via LDS; t+1 inputs prefetched.
__global__ __launch_bounds__(128) void scan_kernel(const float* __restrict__ QK,
                                                   const float* __restrict__ V,
                                                   const float* __restrict__ eg,
                                                   const float* __restrict__ bet,
                                                   float* __restrict__ O) {
  const int vh = blockIdx.x, kh = vh >> 1, j = threadIdx.x;
  __shared__ __align__(16) float lk[128];
  __shared__ __align__(16) float lq[128];
  float s[128];
#pragma unroll
  for (int d = 0; d < 128; ++d) s[d] = 0.f;
  lk[j] = QK[2048 + kh * 128 + j];
  lq[j] = QK[kh * 128 + j];
  __syncthreads();
  float vv  = V[vh * 128 + j];
  float egc = eg[vh];
  float bc  = bet[vh];
  for (int t = 0; t < T_LEN; ++t) {
    float nk = 0.f, nq = 0.f, nv = 0.f, ne = 0.f, nb = 0.f;
    if (t + 1 < T_LEN) {
      const size_t base = (size_t)(t + 1) * 4096;
      nk = QK[base + 2048 + kh * 128 + j];
      nq = QK[base + kh * 128 + j];
      nv = V[base + vh * 128 + j];
      ne = eg[(t + 1) * 32 + vh];
      nb = bet[(t + 1) * 32 + vh];
    }
    float kv0 = 0.f, kv1 = 0.f, kv2 = 0.f, kv3 = 0.f;
#pragma unroll
    for (int d = 0; d < 128; d += 4) {
      const float4 k4 = *reinterpret_cast<const float4*>(&lk[d]);
      s[d]     *= egc; kv0 = fmaf(k4.x, s[d],     kv0);
      s[d + 1] *= egc; kv1 = fmaf(k4.y, s[d + 1], kv1);
      s[d + 2] *= egc; kv2 = fmaf(k4.z, s[d + 2], kv2);
      s[d + 3] *= egc; kv3 = fmaf(k4.w, s[d + 3], kv3);
    }
    const float delta = (vv - ((kv0 + kv1) + (kv2 + kv3))) * bc;
    float o0 = 0.f, o1 = 0.f, o2 = 0.f, o3 = 0.f;
#pragma unroll
    for (int d = 0; d < 128; d += 4) {
      const float4 k4 = *reinterpret_cast<const float4*>(&lk[d]);
      const float4 q4 = *reinterpret_cast<const float4*>(&lq[d]);
      s[d]     = fmaf(k4.x, delta, s[d]);     o0 = fmaf(q4.x, s[d],     o0);
      s[d + 1] = fmaf(k4.y, delta, s[d + 1]); o1 = fmaf(q4.y, s[d + 1], o1);
      s[d + 2] = fmaf(k4.z, delta, s[d + 2]); o2 = fmaf(q4.z, s[d + 2], o2);
      s[d + 3] = fmaf(k4.w, delta, s[d + 3]); o3 = fmaf(q4.w, s[d + 3], o3);
    }
    O[(size_t)t * 4096 + vh * 128 + j] = (o0 + o1) + (o2 + o3);
    __syncthreads();
    lk[j] = nk;
    lq[j] = nq;
    __syncthreads();
    vv = nv; egc = ne; bc = nb;
  }
}

// ---------------- gated = rmsnorm(o * silu(z)) * norm_w ----------------------
__global__ void gate_norm(const float* __restrict__ O,
                          const float* __restrict__ qkvz,
                          const float* __restrict__ norm_w,
                          float* __restrict__ G) {
  const int vh = blockIdx.x, t = blockIdx.y, l = threadIdx.x;  // 64 threads
  const size_t ob = (size_t)t * 4096 + vh * 128;
  const size_t zb = (size_t)t * NQKVZ + (vh >> 1) * 768 + 512 + (vh & 1) * 128;
  const float o0 = O[ob + l], o1 = O[ob + l + 64];
  const float z0 = qkvz[zb + l], z1 = qkvz[zb + l + 64];
  const float g0 = o0 * z0 / (1.f + expf(-z0));
  const float g1 = o1 * z1 / (1.f + expf(-z1));
  float ss = g0 * g0 + g1 * g1;
#pragma unroll
  for (int off = 32; off; off >>= 1) ss += __shfl_xor(ss, off);
  const float r = rsqrtf(ss * (1.f / 128.f) + 1e-6f);
  G[ob + l]      = g0 * r * norm_w[l];
  G[ob + l + 64] = g1 * r * norm_w[l + 64];
}

extern "C" void kernel_launch(void* const* d_in, const int* in_sizes, int n_in,
                              void* d_out, int out_size, void* d_ws, size_t ws_size,
                              hipStream_t stream) {
  const float* X       = (const float*)d_in[0];
  const float* W_qkvz  = (const float*)d_in[1];
  const float* W_ba    = (const float*)d_in[2];
  const float* conv_w  = (const float*)d_in[3];
  const float* dt_bias = (const float*)d_in[4];
  const float* A_log   = (const float*)d_in[5];
  const float* norm_w  = (const float*)d_in[6];
  const float* W_out   = (const float*)d_in[7];
  float* out = (float*)d_out;

  float* ws   = (float*)d_ws;
  float* qkvz = ws;                               // 1024*12288 = 12,582,912 f
  float* ba   = qkvz + (size_t)T_LEN * NQKVZ;     //    65,536 f
  float* QK   = ba + (size_t)T_LEN * 64;          // 4,194,304 f (q|k post-conv)
  float* V    = QK + (size_t)T_LEN * 4096;        // 4,194,304 f
  float* eg   = V + (size_t)T_LEN * 4096;         //    32,768 f
  float* bet  = eg + (size_t)T_LEN * 32;          //    32,768 f
  float* O    = bet + (size_t)T_LEN * 32;         // 4,194,304 f
  float* G    = QK;  // alias: QK dead after scan; gated is same size (t x 4096)

  gemm_f32<<<dim3(NQKVZ / 64, T_LEN / 64), 256, 0, stream>>>(X, W_qkvz, qkvz, T_LEN, NQKVZ, 2048);
  gemm_f32<<<dim3(1, T_LEN / 64), 256, 0, stream>>>(X, W_ba, ba, T_LEN, 64, 2048);
  conv_silu<<<dim3(CDIM / 256, T_LEN), 256, 0, stream>>>(qkvz, conv_w, QK, V);
  l2norm_qk<<<dim3(HK_N, T_LEN), 64, 0, stream>>>(QK);
  compute_gb<<<dim3(T_LEN * 32 / 256), 256, 0, stream>>>(ba, dt_bias, A_log, eg, bet);
  scan_kernel<<<dim3(HV_N), 128, 0, stream>>>(QK, V, eg, bet, O);
  gate_norm<<<dim3(HV_N, T_LEN), 64, 0, stream>>>(O, qkvz, norm_w, G);
  gemm_f32<<<dim3(2048 / 64, T_LEN / 64), 256, 0, stream>>>(G, W_out, out, T_LEN, 2048, 4096);
}

// Round 2
// 1737.103 us; speedup vs baseline: 2.5480x; 2.5480x over previous
//
#include <hip/hip_runtime.h>
#include <hip/hip_bf16.h>
#include <math.h>

// Qwen3Next GatedDeltaNet — round 1: chunked (WY-form) delta-rule scan.
// Phase 1 (parallel, 512 blocks): per (chunk, v-head) compute U, W, B, decay
// scalars via in-chunk triangular solve. Phase 2 (serial over 16 chunks,
// 256 blocks): GEMM-shaped state propagation.

#define T_LEN 1024
#define HK_N 16
#define HV_N 32
#define NQKVZ 12288
#define CDIM 8192
#define CHUNK 64
#define NCHUNK 16

// ---------------- generic fp32 tiled GEMM: C[M,N] = A[M,K] @ B[K,N] ----------
__global__ __launch_bounds__(256) void gemm_f32(const float* __restrict__ A,
                                                const float* __restrict__ B,
                                                float* __restrict__ C,
                                                int M, int N, int K) {
  __shared__ __align__(16) float As[16][64];  // [k][m]
  __shared__ __align__(16) float Bs[16][64];  // [k][n]
  const int tid = threadIdx.x;
  const int tx = tid & 15, ty = tid >> 4;
  const int m0 = blockIdx.y * 64, n0 = blockIdx.x * 64;
  const int ar = tid >> 2, akc = (tid & 3) << 2;
  const int bk = tid >> 4, bn = (tid & 15) << 2;
  float acc[4][4] = {};
  for (int k0 = 0; k0 < K; k0 += 16) {
    float4 av = *reinterpret_cast<const float4*>(&A[(size_t)(m0 + ar) * K + k0 + akc]);
    float4 bv = *reinterpret_cast<const float4*>(&B[(size_t)(k0 + bk) * N + n0 + bn]);
    As[akc + 0][ar] = av.x;
    As[akc + 1][ar] = av.y;
    As[akc + 2][ar] = av.z;
    As[akc + 3][ar] = av.w;
    *reinterpret_cast<float4*>(&Bs[bk][bn]) = bv;
    __syncthreads();
#pragma unroll
    for (int kk = 0; kk < 16; ++kk) {
      float a[4], b[4];
#pragma unroll
      for (int i = 0; i < 4; ++i) a[i] = As[kk][ty * 4 + i];
#pragma unroll
      for (int j = 0; j < 4; ++j) b[j] = Bs[kk][tx * 4 + j];
#pragma unroll
      for (int i = 0; i < 4; ++i)
#pragma unroll
        for (int j = 0; j < 4; ++j) acc[i][j] = fmaf(a[i], b[j], acc[i][j]);
    }
    __syncthreads();
  }
#pragma unroll
  for (int i = 0; i < 4; ++i) {
#pragma unroll
    for (int j = 0; j < 4; ++j)
      C[(size_t)(m0 + ty * 4 + i) * N + n0 + tx * 4 + j] = acc[i][j];
  }
}

// ------------- causal depthwise conv (K=4) + silu, with qkvz gather ----------
__global__ void conv_silu(const float* __restrict__ qkvz,
                          const float* __restrict__ conv_w,
                          float* __restrict__ QK, float* __restrict__ V) {
  const int c = blockIdx.x * 256 + threadIdx.x;
  const int t = blockIdx.y;
  int col;
  if (c < 2048) {
    col = (c >> 7) * 768 + (c & 127);
  } else if (c < 4096) {
    const int c2 = c - 2048;
    col = (c2 >> 7) * 768 + 128 + (c2 & 127);
  } else {
    const int c2 = c - 4096;
    const int vh = c2 >> 7;
    col = (vh >> 1) * 768 + 256 + (vh & 1) * 128 + (c2 & 127);
  }
  float acc = 0.f;
#pragma unroll
  for (int s = 0; s < 4; ++s) {
    const int tt = t - 3 + s;
    if (tt >= 0) acc = fmaf(qkvz[(size_t)tt * NQKVZ + col], conv_w[c * 4 + s], acc);
  }
  const float y = acc / (1.f + expf(-acc));  // silu
  if (c < 4096) QK[(size_t)t * 4096 + c] = y;
  else          V[(size_t)t * 4096 + (c - 4096)] = y;
}

// ---------------- l2norm over DK for q and k (per t, per k-head) -------------
__global__ void l2norm_qk(float* __restrict__ QK) {
  const int h = blockIdx.x, t = blockIdx.y, l = threadIdx.x;  // 64 threads
  const size_t qb = (size_t)t * 4096 + h * 128;
  const size_t kb = qb + 2048;
  float q0 = QK[qb + l], q1 = QK[qb + l + 64];
  float k0 = QK[kb + l], k1 = QK[kb + l + 64];
  float sq = q0 * q0 + q1 * q1;
  float sk = k0 * k0 + k1 * k1;
#pragma unroll
  for (int off = 32; off; off >>= 1) {
    sq += __shfl_xor(sq, off);
    sk += __shfl_xor(sk, off);
  }
  const float rq = rsqrtf(sq + 1e-6f) * 0.08838834764831845f;  // * DK^-0.5
  const float rk = rsqrtf(sk + 1e-6f);
  QK[qb + l] = q0 * rq; QK[qb + l + 64] = q1 * rq;
  QK[kb + l] = k0 * rk; QK[kb + l + 64] = k1 * rk;
}

// -------- g = -exp(A_log)*softplus(a+dt_bias) (log-decay), beta = sigmoid ----
__global__ void compute_gb(const float* __restrict__ ba,
                           const float* __restrict__ dt_bias,
                           const float* __restrict__ A_log,
                           float* __restrict__ gg, float* __restrict__ bet) {
  const int idx = blockIdx.x * 256 + threadIdx.x;  // t*32 + vh
  const int t = idx >> 5, vh = idx & 31;
  const float b = ba[t * 64 + (vh >> 1) * 4 + (vh & 1)];
  const float a = ba[t * 64 + (vh >> 1) * 4 + 2 + (vh & 1)];
  const float x = a + dt_bias[vh];
  const float sp = (x > 20.f) ? x : log1pf(expf(x));
  gg[idx] = -expf(A_log[vh]) * sp;
  bet[idx] = 1.f / (1.f + expf(-b));
}

// ---------------- phase 1: per (chunk, v-head) intra-chunk precompute --------
// Outputs: U = M (beta*v), W = M (beta*gamma*k)  with M = (I+A)^{-1}
//          B[i][j] = e^{b_i-b_j} (q_i.k_j)  (j<=i),  gam/lam per-row scalars,
//          gend = gamma at chunk end.
__global__ __launch_bounds__(256) void phase1(
    const float* __restrict__ QK, const float* __restrict__ V,
    const float* __restrict__ g, const float* __restrict__ bet,
    float* __restrict__ U, float* __restrict__ W, float* __restrict__ Bm,
    float* __restrict__ gam, float* __restrict__ lam, float* __restrict__ gend) {
  const int vh = blockIdx.x, ch = blockIdx.y, kh = vh >> 1;
  const int tid = threadIdx.x;
  const int t0 = ch * CHUNK;
  __shared__ __align__(16) float Kl[64][132];
  __shared__ float Al[64][64];
  __shared__ __align__(16) float Xl[64][256];
  __shared__ float bs[64], gams[64], bets[64];

  const int row = tid >> 2;
  // 1. K tile -> LDS (row = tid>>2, 32 floats per thread)
  {
    const int cc = (tid & 3) * 32;
    const float* src = &QK[(size_t)(t0 + row) * 4096 + 2048 + kh * 128 + cc];
#pragma unroll
    for (int u = 0; u < 32; u += 4)
      *reinterpret_cast<float4*>(&Kl[row][cc + u]) =
          *reinterpret_cast<const float4*>(src + u);
  }
  // 2. inclusive cumsum of g over the chunk (wave 0)
  if (tid < 64) {
    float b = g[(size_t)(t0 + tid) * 32 + vh];
#pragma unroll
    for (int off = 1; off < 64; off <<= 1) {
      const float o = __shfl_up(b, off);
      if (tid >= off) b += o;
    }
    const float b63 = __shfl(b, 63);
    const float ga = expf(b);
    bs[tid] = b;
    gams[tid] = ga;
    bets[tid] = bet[(size_t)(t0 + tid) * 32 + vh];
    gam[(size_t)(t0 + tid) * 32 + vh] = ga;
    lam[(size_t)(t0 + tid) * 32 + vh] = expf(b63 - b);
    if (tid == 63) gend[ch * 32 + vh] = ga;
  }
  __syncthreads();
  // 3. A (LDS, strictly lower, decay+beta scaled) and B (global, j<=i)
  {
    const int j0 = (tid & 3) * 16;
    const float* qrow = &QK[(size_t)(t0 + row) * 4096 + kh * 128];
    float accA[16], accB[16];
#pragma unroll
    for (int jj = 0; jj < 16; ++jj) { accA[jj] = 0.f; accB[jj] = 0.f; }
    for (int d = 0; d < 128; d += 4) {
      const float4 qi = *reinterpret_cast<const float4*>(qrow + d);
      const float4 ki = *reinterpret_cast<const float4*>(&Kl[row][d]);
#pragma unroll
      for (int jj = 0; jj < 16; ++jj) {
        const float4 kj = *reinterpret_cast<const float4*>(&Kl[j0 + jj][d]);
        accA[jj] += ki.x * kj.x + ki.y * kj.y + ki.z * kj.z + ki.w * kj.w;
        accB[jj] += qi.x * kj.x + qi.y * kj.y + qi.z * kj.z + qi.w * kj.w;
      }
    }
    const float bi = bets[row], bvi = bs[row];
    float* Bout = &Bm[(((size_t)ch * 32 + vh) * 64 + row) * 64 + j0];
#pragma unroll
    for (int jj = 0; jj < 16; ++jj) {
      const int j = j0 + jj;
      const float dec = expf(bvi - bs[j]);
      Al[row][j] = (j < row) ? bi * dec * accA[jj] : 0.f;
      Bout[jj] = (j <= row) ? dec * accB[jj] : 0.f;
    }
  }
  // 4. X = [beta*v | beta*gamma*k]  (rhs of triangular system)
  {
    const int qu = tid & 3;
    if (qu < 2) {
      const float bi = bets[row];
      const float* vsrc = &V[(size_t)(t0 + row) * 4096 + vh * 128 + qu * 64];
#pragma unroll
      for (int u = 0; u < 64; u += 4) {
        const float4 v4 = *reinterpret_cast<const float4*>(vsrc + u);
        *reinterpret_cast<float4*>(&Xl[row][qu * 64 + u]) =
            make_float4(bi * v4.x, bi * v4.y, bi * v4.z, bi * v4.w);
      }
    } else {
      const float s = bets[row] * gams[row];
#pragma unroll
      for (int u = 0; u < 64; u += 4) {
        const float4 k4 = *reinterpret_cast<const float4*>(&Kl[row][(qu - 2) * 64 + u]);
        *reinterpret_cast<float4*>(&Xl[row][128 + (qu - 2) * 64 + u]) =
            make_float4(s * k4.x, s * k4.y, s * k4.z, s * k4.w);
      }
    }
  }
  __syncthreads();
  // 5. forward substitution (I+A) X = R, in-place; column-per-thread, no sync
  {
    const int cc = tid;
    for (int i = 1; i < 64; ++i) {
      float x = Xl[i][cc];
      for (int j = 0; j < i; ++j) x -= Al[i][j] * Xl[j][cc];
      Xl[i][cc] = x;
    }
    float* dst = (cc < 128)
                     ? &U[(((size_t)ch * 32 + vh) * 64) * 128 + cc]
                     : &W[(((size_t)ch * 32 + vh) * 64) * 128 + (cc - 128)];
#pragma unroll 4
    for (int j = 0; j < 64; ++j) dst[(size_t)j * 128] = Xl[j][cc];
  }
}

// ---------------- phase 2: serial over chunks, GEMM-shaped -------------------
// grid (32 v-heads, 8 tiles of 16 DV cols); one block per CU.
__global__ __launch_bounds__(256) void phase2(
    const float* __restrict__ QK, const float* __restrict__ U,
    const float* __restrict__ W, const float* __restrict__ Bm,
    const float* __restrict__ gam, const float* __restrict__ lam,
    const float* __restrict__ gend, float* __restrict__ O) {
  const int vh = blockIdx.x, vt = blockIdx.y, kh = vh >> 1;
  const int c0 = vt * 16, tid = threadIdx.x;
  const int r = tid >> 4, c = tid & 15;
  __shared__ __align__(16) float S0[128][16];
  __shared__ __align__(16) float Dl[64][16];
  __shared__ __align__(16) float Wl[64][132];
  __shared__ __align__(16) float Qg[64][132];
  __shared__ __align__(16) float Kll[64][132];
  __shared__ __align__(16) float Bl[64][68];

#pragma unroll
  for (int u = 0; u < 8; ++u) S0[r + 16 * u][c] = 0.f;
  __syncthreads();

  for (int ch = 0; ch < NCHUNK; ++ch) {
    const int t0 = ch * CHUNK;
    // stage W, gamma*q, lambda*k, B into LDS
    {
      const int i = tid >> 2, q4 = (tid & 3) * 32;
      const size_t wbase = (((size_t)ch * 32 + vh) * 64 + i) * 128 + q4;
      const float lami = lam[(size_t)(t0 + i) * 32 + vh];
      const float gami = gam[(size_t)(t0 + i) * 32 + vh];
      const float* qsrc = &QK[(size_t)(t0 + i) * 4096 + kh * 128 + q4];
#pragma unroll
      for (int u = 0; u < 32; u += 4) {
        *reinterpret_cast<float4*>(&Wl[i][q4 + u]) =
            *reinterpret_cast<const float4*>(&W[wbase + u]);
        const float4 qv = *reinterpret_cast<const float4*>(qsrc + u);
        *reinterpret_cast<float4*>(&Qg[i][q4 + u]) =
            make_float4(gami * qv.x, gami * qv.y, gami * qv.z, gami * qv.w);
        const float4 kv = *reinterpret_cast<const float4*>(qsrc + 2048 + u);
        *reinterpret_cast<float4*>(&Kll[i][q4 + u]) =
            make_float4(lami * kv.x, lami * kv.y, lami * kv.z, lami * kv.w);
      }
      const float* bsrc = &Bm[(((size_t)ch * 32 + vh) * 64 + i) * 64 + (tid & 3) * 16];
#pragma unroll
      for (int u = 0; u < 16; u += 4)
        *reinterpret_cast<float4*>(&Bl[i][(tid & 3) * 16 + u]) =
            *reinterpret_cast<const float4*>(bsrc + u);
    }
    const float ge = gend[ch * 32 + vh];
    __syncthreads();
    // delta = U - W @ S0
#pragma unroll
    for (int s = 0; s < 4; ++s) {
      const int i = r + 16 * s;
      float a = U[(((size_t)ch * 32 + vh) * 64 + i) * 128 + c0 + c];
      for (int d = 0; d < 128; d += 4) {
        const float4 w4 = *reinterpret_cast<const float4*>(&Wl[i][d]);
        a -= w4.x * S0[d][c] + w4.y * S0[d + 1][c] + w4.z * S0[d + 2][c] +
             w4.w * S0[d + 3][c];
      }
      Dl[i][c] = a;
    }
    __syncthreads();
    // o = (gamma q) @ S0 + B @ delta
#pragma unroll
    for (int s = 0; s < 4; ++s) {
      const int i = r + 16 * s;
      float a = 0.f;
      for (int d = 0; d < 128; d += 4) {
        const float4 q4 = *reinterpret_cast<const float4*>(&Qg[i][d]);
        a += q4.x * S0[d][c] + q4.y * S0[d + 1][c] + q4.z * S0[d + 2][c] +
             q4.w * S0[d + 3][c];
      }
      for (int j = 0; j < 64; j += 4) {
        const float4 b4 = *reinterpret_cast<const float4*>(&Bl[i][j]);
        a += b4.x * Dl[j][c] + b4.y * Dl[j + 1][c] + b4.z * Dl[j + 2][c] +
             b4.w * Dl[j + 3][c];
      }
      O[(size_t)(t0 + i) * 4096 + vh * 128 + c0 + c] = a;
    }
    __syncthreads();
    // S0 = gend * S0 + (lambda k)^T @ delta
    {
      float a[8];
#pragma unroll
      for (int sp = 0; sp < 8; ++sp) a[sp] = ge * S0[r + 16 * sp][c];
      for (int i = 0; i < 64; ++i) {
        const float dd = Dl[i][c];
#pragma unroll
        for (int sp = 0; sp < 8; ++sp) a[sp] += Kll[i][r + 16 * sp] * dd;
      }
#pragma unroll
      for (int sp = 0; sp < 8; ++sp) S0[r + 16 * sp][c] = a[sp];
    }
    __syncthreads();
  }
}

// ---------------- gated = rmsnorm(o * silu(z)) * norm_w ----------------------
__global__ void gate_norm(const float* __restrict__ O,
                          const float* __restrict__ qkvz,
                          const float* __restrict__ norm_w,
                          float* __restrict__ G) {
  const int vh = blockIdx.x, t = blockIdx.y, l = threadIdx.x;  // 64 threads
  const size_t ob = (size_t)t * 4096 + vh * 128;
  const size_t zb = (size_t)t * NQKVZ + (vh >> 1) * 768 + 512 + (vh & 1) * 128;
  const float o0 = O[ob + l], o1 = O[ob + l + 64];
  const float z0 = qkvz[zb + l], z1 = qkvz[zb + l + 64];
  const float g0 = o0 * z0 / (1.f + expf(-z0));
  const float g1 = o1 * z1 / (1.f + expf(-z1));
  float ss = g0 * g0 + g1 * g1;
#pragma unroll
  for (int off = 32; off; off >>= 1) ss += __shfl_xor(ss, off);
  const float rr = rsqrtf(ss * (1.f / 128.f) + 1e-6f);
  G[ob + l] = g0 * rr * norm_w[l];
  G[ob + l + 64] = g1 * rr * norm_w[l + 64];
}

extern "C" void kernel_launch(void* const* d_in, const int* in_sizes, int n_in,
                              void* d_out, int out_size, void* d_ws, size_t ws_size,
                              hipStream_t stream) {
  const float* X = (const float*)d_in[0];
  const float* W_qkvz = (const float*)d_in[1];
  const float* W_ba = (const float*)d_in[2];
  const float* conv_w = (const float*)d_in[3];
  const float* dt_bias = (const float*)d_in[4];
  const float* A_log = (const float*)d_in[5];
  const float* norm_w = (const float*)d_in[6];
  const float* W_out = (const float*)d_in[7];
  float* out = (float*)d_out;

  float* ws = (float*)d_ws;
  float* qkvz = ws;                                    // 12,582,912 f
  float* ba = qkvz + (size_t)T_LEN * NQKVZ;            //     65,536 f
  float* QK = ba + (size_t)T_LEN * 64;                 //  4,194,304 f
  float* V = QK + (size_t)T_LEN * 4096;                //  4,194,304 f
  float* gg = V + (size_t)T_LEN * 4096;                //     32,768 f
  float* bet = gg + (size_t)T_LEN * 32;                //     32,768 f
  float* gam = bet + (size_t)T_LEN * 32;               //     32,768 f
  float* lam = gam + (size_t)T_LEN * 32;               //     32,768 f
  float* gend = lam + (size_t)T_LEN * 32;              //        512 f
  float* U = gend + 512;                               //  4,194,304 f
  float* Wm = U + (size_t)NCHUNK * 32 * 64 * 128;      //  4,194,304 f
  float* Bm = Wm + (size_t)NCHUNK * 32 * 64 * 128;     //  2,097,152 f
  float* O = V;    // V dead after phase1
  float* G = Wm;   // W dead after phase2

  gemm_f32<<<dim3(NQKVZ / 64, T_LEN / 64), 256, 0, stream>>>(X, W_qkvz, qkvz, T_LEN, NQKVZ, 2048);
  gemm_f32<<<dim3(1, T_LEN / 64), 256, 0, stream>>>(X, W_ba, ba, T_LEN, 64, 2048);
  conv_silu<<<dim3(CDIM / 256, T_LEN), 256, 0, stream>>>(qkvz, conv_w, QK, V);
  l2norm_qk<<<dim3(HK_N, T_LEN), 64, 0, stream>>>(QK);
  compute_gb<<<dim3(T_LEN * 32 / 256), 256, 0, stream>>>(ba, dt_bias, A_log, gg, bet);
  phase1<<<dim3(HV_N, NCHUNK), 256, 0, stream>>>(QK, V, gg, bet, U, Wm, Bm, gam, lam, gend);
  phase2<<<dim3(HV_N, 8), 256, 0, stream>>>(QK, U, Wm, Bm, gam, lam, gend, O);
  gate_norm<<<dim3(HV_N, T_LEN), 64, 0, stream>>>(O, qkvz, norm_w, G);
  gemm_f32<<<dim3(2048 / 64, T_LEN / 64), 256, 0, stream>>>(G, W_out, out, T_LEN, 2048, 4096);
}

// Round 3
// 966.915 us; speedup vs baseline: 4.5777x; 1.7965x over previous
//
#include <hip/hip_runtime.h>
#include <hip/hip_bf16.h>
#include <math.h>

// Qwen3Next GatedDeltaNet — round 2: bf16 MFMA for the two big GEMMs
// (m97 structure: 128x128 tile, BK=32, global_load_lds width 16).
// Scan stays chunked fp32 (round 1).

#define T_LEN 1024
#define HK_N 16
#define HV_N 32
#define NQKVZ 12288
#define CDIM 8192
#define CHUNK 64
#define NCHUNK 16

typedef __bf16 bf16x8 __attribute__((ext_vector_type(8)));
typedef float f32x4 __attribute__((ext_vector_type(4)));

// ---------------- bf16 MFMA GEMM: C[M,N] = A[M,K] @ B[N,K]^T -----------------
// A row-major [M,K] bf16, B row-major [N,K] bf16 (pre-transposed weights),
// C fp32 [M,N]. 256 thr = 4 waves, each wave a 64x64 sub-tile (4x4 frags of
// 16x16x32). Requires M%128==0, N%128==0, K%32==0.
__global__ __launch_bounds__(256) void gemm_bf16(const __hip_bfloat16* __restrict__ A,
                                                 const __hip_bfloat16* __restrict__ B,
                                                 float* __restrict__ C,
                                                 int M, int N, int K) {
  __shared__ __align__(16) __hip_bfloat16 As[128 * 32];
  __shared__ __align__(16) __hip_bfloat16 Bs[128 * 32];
  const int tid = threadIdx.x;
  const int wid = tid >> 6, lane = tid & 63;
  const int wr = wid >> 1, wc = wid & 1;
  const int m0 = blockIdx.y * 128, n0 = blockIdx.x * 128;
  const int lrow = lane & 15, lk = lane >> 4;
  f32x4 acc[4][4] = {};

  for (int k0 = 0; k0 < K; k0 += 32) {
#pragma unroll
    for (int p = 0; p < 2; ++p) {
      const int c = p * 256 + wid * 64 + lane;  // chunk: row=c>>2, 8 elems at (c&3)*8
      const __hip_bfloat16* ga = A + (size_t)(m0 + (c >> 2)) * K + k0 + (c & 3) * 8;
      const __hip_bfloat16* gb = B + (size_t)(n0 + (c >> 2)) * K + k0 + (c & 3) * 8;
      __builtin_amdgcn_global_load_lds(
          (const __attribute__((address_space(1))) void*)ga,
          (__attribute__((address_space(3))) void*)(As + p * 2048 + wid * 512), 16, 0, 0);
      __builtin_amdgcn_global_load_lds(
          (const __attribute__((address_space(1))) void*)gb,
          (__attribute__((address_space(3))) void*)(Bs + p * 2048 + wid * 512), 16, 0, 0);
    }
    __syncthreads();
    bf16x8 af[4], bfv[4];
#pragma unroll
    for (int m = 0; m < 4; ++m)
      af[m] = *reinterpret_cast<const bf16x8*>(As + (wr * 64 + m * 16 + lrow) * 32 + lk * 8);
#pragma unroll
    for (int n = 0; n < 4; ++n)
      bfv[n] = *reinterpret_cast<const bf16x8*>(Bs + (wc * 64 + n * 16 + lrow) * 32 + lk * 8);
#pragma unroll
    for (int m = 0; m < 4; ++m)
#pragma unroll
      for (int n = 0; n < 4; ++n)
        acc[m][n] = __builtin_amdgcn_mfma_f32_16x16x32_bf16(af[m], bfv[n], acc[m][n], 0, 0, 0);
    __syncthreads();
  }
  // C/D layout: col = lane&15, row = (lane>>4)*4 + reg  [m89/m91 verified]
#pragma unroll
  for (int m = 0; m < 4; ++m)
#pragma unroll
    for (int n = 0; n < 4; ++n)
#pragma unroll
      for (int r = 0; r < 4; ++r)
        C[(size_t)(m0 + wr * 64 + m * 16 + lk * 4 + r) * N + n0 + wc * 64 + n * 16 + lrow] =
            acc[m][n][r];
}

// ---------------- fp32 -> bf16 elementwise cast ------------------------------
__global__ void cast_bf16(const float* __restrict__ src,
                          __hip_bfloat16* __restrict__ dst, int n) {
  const int i = (blockIdx.x * 256 + threadIdx.x) * 4;
  if (i < n) {
    const float4 v = *reinterpret_cast<const float4*>(src + i);
    ushort4 o;
    o.x = __bfloat16_as_ushort(__float2bfloat16(v.x));
    o.y = __bfloat16_as_ushort(__float2bfloat16(v.y));
    o.z = __bfloat16_as_ushort(__float2bfloat16(v.z));
    o.w = __bfloat16_as_ushort(__float2bfloat16(v.w));
    *reinterpret_cast<ushort4*>((void*)(dst + i)) = o;
  }
}

// ---------------- fp32 [K,N] -> bf16 [N,K] tiled transpose-cast --------------
__global__ __launch_bounds__(256) void transpose_cast(const float* __restrict__ src,
                                                      __hip_bfloat16* __restrict__ dst,
                                                      int K, int N) {
  __shared__ float tl[32][33];
  const int n0 = blockIdx.x * 32, k0 = blockIdx.y * 32;
  const int tx = threadIdx.x & 31, ty = threadIdx.x >> 5;  // ty 0..7
#pragma unroll
  for (int i = 0; i < 4; ++i)
    tl[ty + 8 * i][tx] = src[(size_t)(k0 + ty + 8 * i) * N + n0 + tx];
  __syncthreads();
#pragma unroll
  for (int i = 0; i < 4; ++i)
    dst[(size_t)(n0 + ty + 8 * i) * K + k0 + tx] = __float2bfloat16(tl[tx][ty + 8 * i]);
}

// ---------------- generic fp32 tiled GEMM (kept for tiny ba GEMM) ------------
__global__ __launch_bounds__(256) void gemm_f32(const float* __restrict__ A,
                                                const float* __restrict__ B,
                                                float* __restrict__ C,
                                                int M, int N, int K) {
  __shared__ __align__(16) float Asl[16][64];
  __shared__ __align__(16) float Bsl[16][64];
  const int tid = threadIdx.x;
  const int tx = tid & 15, ty = tid >> 4;
  const int m0 = blockIdx.y * 64, n0 = blockIdx.x * 64;
  const int ar = tid >> 2, akc = (tid & 3) << 2;
  const int bk = tid >> 4, bn = (tid & 15) << 2;
  float acc[4][4] = {};
  for (int k0 = 0; k0 < K; k0 += 16) {
    float4 av = *reinterpret_cast<const float4*>(&A[(size_t)(m0 + ar) * K + k0 + akc]);
    float4 bv = *reinterpret_cast<const float4*>(&B[(size_t)(k0 + bk) * N + n0 + bn]);
    Asl[akc + 0][ar] = av.x;
    Asl[akc + 1][ar] = av.y;
    Asl[akc + 2][ar] = av.z;
    Asl[akc + 3][ar] = av.w;
    *reinterpret_cast<float4*>(&Bsl[bk][bn]) = bv;
    __syncthreads();
#pragma unroll
    for (int kk = 0; kk < 16; ++kk) {
      float a[4], b[4];
#pragma unroll
      for (int i = 0; i < 4; ++i) a[i] = Asl[kk][ty * 4 + i];
#pragma unroll
      for (int j = 0; j < 4; ++j) b[j] = Bsl[kk][tx * 4 + j];
#pragma unroll
      for (int i = 0; i < 4; ++i)
#pragma unroll
        for (int j = 0; j < 4; ++j) acc[i][j] = fmaf(a[i], b[j], acc[i][j]);
    }
    __syncthreads();
  }
#pragma unroll
  for (int i = 0; i < 4; ++i)
#pragma unroll
    for (int j = 0; j < 4; ++j)
      C[(size_t)(m0 + ty * 4 + i) * N + n0 + tx * 4 + j] = acc[i][j];
}

// ------------- causal depthwise conv (K=4) + silu, with qkvz gather ----------
__global__ void conv_silu(const float* __restrict__ qkvz,
                          const float* __restrict__ conv_w,
                          float* __restrict__ QK, float* __restrict__ V) {
  const int c = blockIdx.x * 256 + threadIdx.x;
  const int t = blockIdx.y;
  int col;
  if (c < 2048) {
    col = (c >> 7) * 768 + (c & 127);
  } else if (c < 4096) {
    const int c2 = c - 2048;
    col = (c2 >> 7) * 768 + 128 + (c2 & 127);
  } else {
    const int c2 = c - 4096;
    const int vh = c2 >> 7;
    col = (vh >> 1) * 768 + 256 + (vh & 1) * 128 + (c2 & 127);
  }
  float acc = 0.f;
#pragma unroll
  for (int s = 0; s < 4; ++s) {
    const int tt = t - 3 + s;
    if (tt >= 0) acc = fmaf(qkvz[(size_t)tt * NQKVZ + col], conv_w[c * 4 + s], acc);
  }
  const float y = acc / (1.f + expf(-acc));  // silu
  if (c < 4096) QK[(size_t)t * 4096 + c] = y;
  else          V[(size_t)t * 4096 + (c - 4096)] = y;
}

// ---------------- l2norm over DK for q and k (per t, per k-head) -------------
__global__ void l2norm_qk(float* __restrict__ QK) {
  const int h = blockIdx.x, t = blockIdx.y, l = threadIdx.x;  // 64 threads
  const size_t qb = (size_t)t * 4096 + h * 128;
  const size_t kb = qb + 2048;
  float q0 = QK[qb + l], q1 = QK[qb + l + 64];
  float k0 = QK[kb + l], k1 = QK[kb + l + 64];
  float sq = q0 * q0 + q1 * q1;
  float sk = k0 * k0 + k1 * k1;
#pragma unroll
  for (int off = 32; off; off >>= 1) {
    sq += __shfl_xor(sq, off);
    sk += __shfl_xor(sk, off);
  }
  const float rq = rsqrtf(sq + 1e-6f) * 0.08838834764831845f;  // * DK^-0.5
  const float rk = rsqrtf(sk + 1e-6f);
  QK[qb + l] = q0 * rq; QK[qb + l + 64] = q1 * rq;
  QK[kb + l] = k0 * rk; QK[kb + l + 64] = k1 * rk;
}

// -------- g = -exp(A_log)*softplus(a+dt_bias) (log-decay), beta = sigmoid ----
__global__ void compute_gb(const float* __restrict__ ba,
                           const float* __restrict__ dt_bias,
                           const float* __restrict__ A_log,
                           float* __restrict__ gg, float* __restrict__ bet) {
  const int idx = blockIdx.x * 256 + threadIdx.x;  // t*32 + vh
  const int t = idx >> 5, vh = idx & 31;
  const float b = ba[t * 64 + (vh >> 1) * 4 + (vh & 1)];
  const float a = ba[t * 64 + (vh >> 1) * 4 + 2 + (vh & 1)];
  const float x = a + dt_bias[vh];
  const float sp = (x > 20.f) ? x : log1pf(expf(x));
  gg[idx] = -expf(A_log[vh]) * sp;
  bet[idx] = 1.f / (1.f + expf(-b));
}

// ---------------- phase 1: per (chunk, v-head) intra-chunk precompute --------
__global__ __launch_bounds__(256) void phase1(
    const float* __restrict__ QK, const float* __restrict__ V,
    const float* __restrict__ g, const float* __restrict__ bet,
    float* __restrict__ U, float* __restrict__ W, float* __restrict__ Bm,
    float* __restrict__ gam, float* __restrict__ lam, float* __restrict__ gend) {
  const int vh = blockIdx.x, ch = blockIdx.y, kh = vh >> 1;
  const int tid = threadIdx.x;
  const int t0 = ch * CHUNK;
  __shared__ __align__(16) float Kl[64][132];
  __shared__ float Al[64][64];
  __shared__ __align__(16) float Xl[64][256];
  __shared__ float bs[64], gams[64], bets[64];

  const int row = tid >> 2;
  {
    const int cc = (tid & 3) * 32;
    const float* src = &QK[(size_t)(t0 + row) * 4096 + 2048 + kh * 128 + cc];
#pragma unroll
    for (int u = 0; u < 32; u += 4)
      *reinterpret_cast<float4*>(&Kl[row][cc + u]) =
          *reinterpret_cast<const float4*>(src + u);
  }
  if (tid < 64) {
    float b = g[(size_t)(t0 + tid) * 32 + vh];
#pragma unroll
    for (int off = 1; off < 64; off <<= 1) {
      const float o = __shfl_up(b, off);
      if (tid >= off) b += o;
    }
    const float b63 = __shfl(b, 63);
    const float ga = expf(b);
    bs[tid] = b;
    gams[tid] = ga;
    bets[tid] = bet[(size_t)(t0 + tid) * 32 + vh];
    gam[(size_t)(t0 + tid) * 32 + vh] = ga;
    lam[(size_t)(t0 + tid) * 32 + vh] = expf(b63 - b);
    if (tid == 63) gend[ch * 32 + vh] = ga;
  }
  __syncthreads();
  {
    const int j0 = (tid & 3) * 16;
    const float* qrow = &QK[(size_t)(t0 + row) * 4096 + kh * 128];
    float accA[16], accB[16];
#pragma unroll
    for (int jj = 0; jj < 16; ++jj) { accA[jj] = 0.f; accB[jj] = 0.f; }
    for (int d = 0; d < 128; d += 4) {
      const float4 qi = *reinterpret_cast<const float4*>(qrow + d);
      const float4 ki = *reinterpret_cast<const float4*>(&Kl[row][d]);
#pragma unroll
      for (int jj = 0; jj < 16; ++jj) {
        const float4 kj = *reinterpret_cast<const float4*>(&Kl[j0 + jj][d]);
        accA[jj] += ki.x * kj.x + ki.y * kj.y + ki.z * kj.z + ki.w * kj.w;
        accB[jj] += qi.x * kj.x + qi.y * kj.y + qi.z * kj.z + qi.w * kj.w;
      }
    }
    const float bi = bets[row], bvi = bs[row];
    float* Bout = &Bm[(((size_t)ch * 32 + vh) * 64 + row) * 64 + j0];
#pragma unroll
    for (int jj = 0; jj < 16; ++jj) {
      const int j = j0 + jj;
      const float dec = expf(bvi - bs[j]);
      Al[row][j] = (j < row) ? bi * dec * accA[jj] : 0.f;
      Bout[jj] = (j <= row) ? dec * accB[jj] : 0.f;
    }
  }
  {
    const int qu = tid & 3;
    if (qu < 2) {
      const float bi = bets[row];
      const float* vsrc = &V[(size_t)(t0 + row) * 4096 + vh * 128 + qu * 64];
#pragma unroll
      for (int u = 0; u < 64; u += 4) {
        const float4 v4 = *reinterpret_cast<const float4*>(vsrc + u);
        *reinterpret_cast<float4*>(&Xl[row][qu * 64 + u]) =
            make_float4(bi * v4.x, bi * v4.y, bi * v4.z, bi * v4.w);
      }
    } else {
      const float s = bets[row] * gams[row];
#pragma unroll
      for (int u = 0; u < 64; u += 4) {
        const float4 k4 = *reinterpret_cast<const float4*>(&Kl[row][(qu - 2) * 64 + u]);
        *reinterpret_cast<float4*>(&Xl[row][128 + (qu - 2) * 64 + u]) =
            make_float4(s * k4.x, s * k4.y, s * k4.z, s * k4.w);
      }
    }
  }
  __syncthreads();
  {
    const int cc = tid;
    for (int i = 1; i < 64; ++i) {
      float x = Xl[i][cc];
      for (int j = 0; j < i; ++j) x -= Al[i][j] * Xl[j][cc];
      Xl[i][cc] = x;
    }
    float* dst = (cc < 128)
                     ? &U[(((size_t)ch * 32 + vh) * 64) * 128 + cc]
                     : &W[(((size_t)ch * 32 + vh) * 64) * 128 + (cc - 128)];
#pragma unroll 4
    for (int j = 0; j < 64; ++j) dst[(size_t)j * 128] = Xl[j][cc];
  }
}

// ---------------- phase 2: serial over chunks, GEMM-shaped -------------------
__global__ __launch_bounds__(256) void phase2(
    const float* __restrict__ QK, const float* __restrict__ U,
    const float* __restrict__ W, const float* __restrict__ Bm,
    const float* __restrict__ gam, const float* __restrict__ lam,
    const float* __restrict__ gend, float* __restrict__ O) {
  const int vh = blockIdx.x, vt = blockIdx.y, kh = vh >> 1;
  const int c0 = vt * 16, tid = threadIdx.x;
  const int r = tid >> 4, c = tid & 15;
  __shared__ __align__(16) float S0[128][16];
  __shared__ __align__(16) float Dl[64][16];
  __shared__ __align__(16) float Wl[64][132];
  __shared__ __align__(16) float Qg[64][132];
  __shared__ __align__(16) float Kll[64][132];
  __shared__ __align__(16) float Bl[64][68];

#pragma unroll
  for (int u = 0; u < 8; ++u) S0[r + 16 * u][c] = 0.f;
  __syncthreads();

  for (int ch = 0; ch < NCHUNK; ++ch) {
    const int t0 = ch * CHUNK;
    {
      const int i = tid >> 2, q4 = (tid & 3) * 32;
      const size_t wbase = (((size_t)ch * 32 + vh) * 64 + i) * 128 + q4;
      const float lami = lam[(size_t)(t0 + i) * 32 + vh];
      const float gami = gam[(size_t)(t0 + i) * 32 + vh];
      const float* qsrc = &QK[(size_t)(t0 + i) * 4096 + kh * 128 + q4];
#pragma unroll
      for (int u = 0; u < 32; u += 4) {
        *reinterpret_cast<float4*>(&Wl[i][q4 + u]) =
            *reinterpret_cast<const float4*>(&W[wbase + u]);
        const float4 qv = *reinterpret_cast<const float4*>(qsrc + u);
        *reinterpret_cast<float4*>(&Qg[i][q4 + u]) =
            make_float4(gami * qv.x, gami * qv.y, gami * qv.z, gami * qv.w);
        const float4 kv = *reinterpret_cast<const float4*>(qsrc + 2048 + u);
        *reinterpret_cast<float4*>(&Kll[i][q4 + u]) =
            make_float4(lami * kv.x, lami * kv.y, lami * kv.z, lami * kv.w);
      }
      const float* bsrc = &Bm[(((size_t)ch * 32 + vh) * 64 + i) * 64 + (tid & 3) * 16];
#pragma unroll
      for (int u = 0; u < 16; u += 4)
        *reinterpret_cast<float4*>(&Bl[i][(tid & 3) * 16 + u]) =
            *reinterpret_cast<const float4*>(bsrc + u);
    }
    const float ge = gend[ch * 32 + vh];
    __syncthreads();
#pragma unroll
    for (int s = 0; s < 4; ++s) {
      const int i = r + 16 * s;
      float a = U[(((size_t)ch * 32 + vh) * 64 + i) * 128 + c0 + c];
      for (int d = 0; d < 128; d += 4) {
        const float4 w4 = *reinterpret_cast<const float4*>(&Wl[i][d]);
        a -= w4.x * S0[d][c] + w4.y * S0[d + 1][c] + w4.z * S0[d + 2][c] +
             w4.w * S0[d + 3][c];
      }
      Dl[i][c] = a;
    }
    __syncthreads();
#pragma unroll
    for (int s = 0; s < 4; ++s) {
      const int i = r + 16 * s;
      float a = 0.f;
      for (int d = 0; d < 128; d += 4) {
        const float4 q4 = *reinterpret_cast<const float4*>(&Qg[i][d]);
        a += q4.x * S0[d][c] + q4.y * S0[d + 1][c] + q4.z * S0[d + 2][c] +
             q4.w * S0[d + 3][c];
      }
      for (int j = 0; j < 64; j += 4) {
        const float4 b4 = *reinterpret_cast<const float4*>(&Bl[i][j]);
        a += b4.x * Dl[j][c] + b4.y * Dl[j + 1][c] + b4.z * Dl[j + 2][c] +
             b4.w * Dl[j + 3][c];
      }
      O[(size_t)(t0 + i) * 4096 + vh * 128 + c0 + c] = a;
    }
    __syncthreads();
    {
      float a[8];
#pragma unroll
      for (int sp = 0; sp < 8; ++sp) a[sp] = ge * S0[r + 16 * sp][c];
      for (int i = 0; i < 64; ++i) {
        const float dd = Dl[i][c];
#pragma unroll
        for (int sp = 0; sp < 8; ++sp) a[sp] += Kll[i][r + 16 * sp] * dd;
      }
#pragma unroll
      for (int sp = 0; sp < 8; ++sp) S0[r + 16 * sp][c] = a[sp];
    }
    __syncthreads();
  }
}

// ------- gated = rmsnorm(o * silu(z)) * norm_w, emitted as bf16 --------------
__global__ void gate_norm(const float* __restrict__ O,
                          const float* __restrict__ qkvz,
                          const float* __restrict__ norm_w,
                          __hip_bfloat16* __restrict__ G) {
  const int vh = blockIdx.x, t = blockIdx.y, l = threadIdx.x;  // 64 threads
  const size_t ob = (size_t)t * 4096 + vh * 128;
  const size_t zb = (size_t)t * NQKVZ + (vh >> 1) * 768 + 512 + (vh & 1) * 128;
  const float o0 = O[ob + l], o1 = O[ob + l + 64];
  const float z0 = qkvz[zb + l], z1 = qkvz[zb + l + 64];
  const float g0 = o0 * z0 / (1.f + expf(-z0));
  const float g1 = o1 * z1 / (1.f + expf(-z1));
  float ss = g0 * g0 + g1 * g1;
#pragma unroll
  for (int off = 32; off; off >>= 1) ss += __shfl_xor(ss, off);
  const float rr = rsqrtf(ss * (1.f / 128.f) + 1e-6f);
  G[ob + l] = __float2bfloat16(g0 * rr * norm_w[l]);
  G[ob + l + 64] = __float2bfloat16(g1 * rr * norm_w[l + 64]);
}

extern "C" void kernel_launch(void* const* d_in, const int* in_sizes, int n_in,
                              void* d_out, int out_size, void* d_ws, size_t ws_size,
                              hipStream_t stream) {
  const float* X = (const float*)d_in[0];
  const float* W_qkvz = (const float*)d_in[1];
  const float* W_ba = (const float*)d_in[2];
  const float* conv_w = (const float*)d_in[3];
  const float* dt_bias = (const float*)d_in[4];
  const float* A_log = (const float*)d_in[5];
  const float* norm_w = (const float*)d_in[6];
  const float* W_out = (const float*)d_in[7];
  float* out = (float*)d_out;

  float* ws = (float*)d_ws;
  float* qkvz = ws;                                // 12,582,912 f
  float* ba = qkvz + (size_t)T_LEN * NQKVZ;        //     65,536 f
  float* QK = ba + (size_t)T_LEN * 64;             //  4,194,304 f
  float* V = QK + (size_t)T_LEN * 4096;            //  4,194,304 f
  float* U = V + (size_t)T_LEN * 4096;             //  4,194,304 f
  float* Wm = U + (size_t)NCHUNK * 32 * 64 * 128;  //  4,194,304 f
  float* Bm = Wm + (size_t)NCHUNK * 32 * 64 * 128; //  2,097,152 f
  float* gg = Bm + (size_t)NCHUNK * 32 * 64 * 64;  //     32,768 f
  float* bet = gg + (size_t)T_LEN * 32;            //     32,768 f
  float* gam = bet + (size_t)T_LEN * 32;           //     32,768 f
  float* lam = gam + (size_t)T_LEN * 32;           //     32,768 f
  float* gend = lam + (size_t)T_LEN * 32;          //        512 f
  // lifetime-aliased bf16 buffers:
  __hip_bfloat16* Wqkvz_t = (__hip_bfloat16*)V;    // 25.2M bf16 over V+U+Wm (dead until conv/phase1)
  __hip_bfloat16* Xb = (__hip_bfloat16*)Bm;        // 2M bf16 (Bm written later by phase1)
  __hip_bfloat16* Gb = (__hip_bfloat16*)Bm;        // 4M bf16 (Bm dead after phase2)
  __hip_bfloat16* Wout_t = (__hip_bfloat16*)qkvz;  // 8.4M bf16 (qkvz dead after gate_norm)
  float* O = V;                                    // V dead after phase1

  cast_bf16<<<dim3(T_LEN * 2048 / 4 / 256), 256, 0, stream>>>(X, Xb, T_LEN * 2048);
  transpose_cast<<<dim3(NQKVZ / 32, 2048 / 32), 256, 0, stream>>>(W_qkvz, Wqkvz_t, 2048, NQKVZ);
  gemm_bf16<<<dim3(NQKVZ / 128, T_LEN / 128), 256, 0, stream>>>(Xb, Wqkvz_t, qkvz, T_LEN, NQKVZ, 2048);
  gemm_f32<<<dim3(1, T_LEN / 64), 256, 0, stream>>>(X, W_ba, ba, T_LEN, 64, 2048);
  conv_silu<<<dim3(CDIM / 256, T_LEN), 256, 0, stream>>>(qkvz, conv_w, QK, V);
  l2norm_qk<<<dim3(HK_N, T_LEN), 64, 0, stream>>>(QK);
  compute_gb<<<dim3(T_LEN * 32 / 256), 256, 0, stream>>>(ba, dt_bias, A_log, gg, bet);
  phase1<<<dim3(HV_N, NCHUNK), 256, 0, stream>>>(QK, V, gg, bet, U, Wm, Bm, gam, lam, gend);
  phase2<<<dim3(HV_N, 8), 256, 0, stream>>>(QK, U, Wm, Bm, gam, lam, gend, O);
  gate_norm<<<dim3(HV_N, T_LEN), 64, 0, stream>>>(O, qkvz, norm_w, Gb);
  transpose_cast<<<dim3(2048 / 32, 4096 / 32), 256, 0, stream>>>(W_out, Wout_t, 4096, 2048);
  gemm_bf16<<<dim3(2048 / 128, T_LEN / 128), 256, 0, stream>>>(Gb, Wout_t, out, T_LEN, 2048, 4096);
}

// Round 4
// 536.238 us; speedup vs baseline: 8.2542x; 1.8031x over previous
//
#include <hip/hip_runtime.h>
#include <hip/hip_bf16.h>
#include <math.h>

// Qwen3Next GatedDeltaNet — round 3: MFMA chunked scan (phaseB) replacing the
// fp32 VALU phase2. phase1 emits bf16 operands (−W, Kᵀλ, γq, B) pre-swizzled
// for conflict-free LDS fragment reads; state S stays fp32 in accumulators.

#define T_LEN 1024
#define HK_N 16
#define HV_N 32
#define NQKVZ 12288
#define CDIM 8192
#define CHUNK 64
#define NCHUNK 16

typedef __bf16 bf16x8 __attribute__((ext_vector_type(8)));
typedef float f32x4 __attribute__((ext_vector_type(4)));

__device__ __forceinline__ ushort4 pack4(const f32x4 v) {
  ushort4 o;
  o.x = __bfloat16_as_ushort(__float2bfloat16(v[0]));
  o.y = __bfloat16_as_ushort(__float2bfloat16(v[1]));
  o.z = __bfloat16_as_ushort(__float2bfloat16(v[2]));
  o.w = __bfloat16_as_ushort(__float2bfloat16(v[3]));
  return o;
}

// ---------------- bf16 MFMA GEMM: C[M,N] = A[M,K] @ B[N,K]^T -----------------
__global__ __launch_bounds__(256) void gemm_bf16(const __hip_bfloat16* __restrict__ A,
                                                 const __hip_bfloat16* __restrict__ B,
                                                 float* __restrict__ C,
                                                 int M, int N, int K) {
  __shared__ __align__(16) __hip_bfloat16 As[128 * 32];
  __shared__ __align__(16) __hip_bfloat16 Bs[128 * 32];
  const int tid = threadIdx.x;
  const int wid = tid >> 6, lane = tid & 63;
  const int wr = wid >> 1, wc = wid & 1;
  const int m0 = blockIdx.y * 128, n0 = blockIdx.x * 128;
  const int lrow = lane & 15, lk = lane >> 4;
  f32x4 acc[4][4] = {};

  for (int k0 = 0; k0 < K; k0 += 32) {
#pragma unroll
    for (int p = 0; p < 2; ++p) {
      const int c = p * 256 + wid * 64 + lane;
      const __hip_bfloat16* ga = A + (size_t)(m0 + (c >> 2)) * K + k0 + (c & 3) * 8;
      const __hip_bfloat16* gb = B + (size_t)(n0 + (c >> 2)) * K + k0 + (c & 3) * 8;
      __builtin_amdgcn_global_load_lds(
          (const __attribute__((address_space(1))) void*)ga,
          (__attribute__((address_space(3))) void*)(As + p * 2048 + wid * 512), 16, 0, 0);
      __builtin_amdgcn_global_load_lds(
          (const __attribute__((address_space(1))) void*)gb,
          (__attribute__((address_space(3))) void*)(Bs + p * 2048 + wid * 512), 16, 0, 0);
    }
    __syncthreads();
    bf16x8 af[4], bfv[4];
#pragma unroll
    for (int m = 0; m < 4; ++m)
      af[m] = *reinterpret_cast<const bf16x8*>(As + (wr * 64 + m * 16 + lrow) * 32 + lk * 8);
#pragma unroll
    for (int n = 0; n < 4; ++n)
      bfv[n] = *reinterpret_cast<const bf16x8*>(Bs + (wc * 64 + n * 16 + lrow) * 32 + lk * 8);
#pragma unroll
    for (int m = 0; m < 4; ++m)
#pragma unroll
      for (int n = 0; n < 4; ++n)
        acc[m][n] = __builtin_amdgcn_mfma_f32_16x16x32_bf16(af[m], bfv[n], acc[m][n], 0, 0, 0);
    __syncthreads();
  }
#pragma unroll
  for (int m = 0; m < 4; ++m)
#pragma unroll
    for (int n = 0; n < 4; ++n)
#pragma unroll
      for (int r = 0; r < 4; ++r)
        C[(size_t)(m0 + wr * 64 + m * 16 + lk * 4 + r) * N + n0 + wc * 64 + n * 16 + lrow] =
            acc[m][n][r];
}

// ---------------- fp32 -> bf16 elementwise cast ------------------------------
__global__ void cast_bf16(const float* __restrict__ src,
                          __hip_bfloat16* __restrict__ dst, int n) {
  const int i = (blockIdx.x * 256 + threadIdx.x) * 4;
  if (i < n) {
    const float4 v = *reinterpret_cast<const float4*>(src + i);
    ushort4 o;
    o.x = __bfloat16_as_ushort(__float2bfloat16(v.x));
    o.y = __bfloat16_as_ushort(__float2bfloat16(v.y));
    o.z = __bfloat16_as_ushort(__float2bfloat16(v.z));
    o.w = __bfloat16_as_ushort(__float2bfloat16(v.w));
    *reinterpret_cast<ushort4*>((void*)(dst + i)) = o;
  }
}

// ---------------- fp32 [K,N] -> bf16 [N,K] tiled transpose-cast --------------
__global__ __launch_bounds__(256) void transpose_cast(const float* __restrict__ src,
                                                      __hip_bfloat16* __restrict__ dst,
                                                      int K, int N) {
  __shared__ float tl[32][33];
  const int n0 = blockIdx.x * 32, k0 = blockIdx.y * 32;
  const int tx = threadIdx.x & 31, ty = threadIdx.x >> 5;
#pragma unroll
  for (int i = 0; i < 4; ++i)
    tl[ty + 8 * i][tx] = src[(size_t)(k0 + ty + 8 * i) * N + n0 + tx];
  __syncthreads();
#pragma unroll
  for (int i = 0; i < 4; ++i)
    dst[(size_t)(n0 + ty + 8 * i) * K + k0 + tx] = __float2bfloat16(tl[tx][ty + 8 * i]);
}

// ---------------- generic fp32 tiled GEMM (tiny ba GEMM) ---------------------
__global__ __launch_bounds__(256) void gemm_f32(const float* __restrict__ A,
                                                const float* __restrict__ B,
                                                float* __restrict__ C,
                                                int M, int N, int K) {
  __shared__ __align__(16) float Asl[16][64];
  __shared__ __align__(16) float Bsl[16][64];
  const int tid = threadIdx.x;
  const int tx = tid & 15, ty = tid >> 4;
  const int m0 = blockIdx.y * 64, n0 = blockIdx.x * 64;
  const int ar = tid >> 2, akc = (tid & 3) << 2;
  const int bk = tid >> 4, bn = (tid & 15) << 2;
  float acc[4][4] = {};
  for (int k0 = 0; k0 < K; k0 += 16) {
    float4 av = *reinterpret_cast<const float4*>(&A[(size_t)(m0 + ar) * K + k0 + akc]);
    float4 bv = *reinterpret_cast<const float4*>(&B[(size_t)(k0 + bk) * N + n0 + bn]);
    Asl[akc + 0][ar] = av.x;
    Asl[akc + 1][ar] = av.y;
    Asl[akc + 2][ar] = av.z;
    Asl[akc + 3][ar] = av.w;
    *reinterpret_cast<float4*>(&Bsl[bk][bn]) = bv;
    __syncthreads();
#pragma unroll
    for (int kk = 0; kk < 16; ++kk) {
      float a[4], b[4];
#pragma unroll
      for (int i = 0; i < 4; ++i) a[i] = Asl[kk][ty * 4 + i];
#pragma unroll
      for (int j = 0; j < 4; ++j) b[j] = Bsl[kk][tx * 4 + j];
#pragma unroll
      for (int i = 0; i < 4; ++i)
#pragma unroll
        for (int j = 0; j < 4; ++j) acc[i][j] = fmaf(a[i], b[j], acc[i][j]);
    }
    __syncthreads();
  }
#pragma unroll
  for (int i = 0; i < 4; ++i)
#pragma unroll
    for (int j = 0; j < 4; ++j)
      C[(size_t)(m0 + ty * 4 + i) * N + n0 + tx * 4 + j] = acc[i][j];
}

// ------------- causal depthwise conv (K=4) + silu, with qkvz gather ----------
__global__ void conv_silu(const float* __restrict__ qkvz,
                          const float* __restrict__ conv_w,
                          float* __restrict__ QK, float* __restrict__ V) {
  const int c = blockIdx.x * 256 + threadIdx.x;
  const int t = blockIdx.y;
  int col;
  if (c < 2048) {
    col = (c >> 7) * 768 + (c & 127);
  } else if (c < 4096) {
    const int c2 = c - 2048;
    col = (c2 >> 7) * 768 + 128 + (c2 & 127);
  } else {
    const int c2 = c - 4096;
    const int vh = c2 >> 7;
    col = (vh >> 1) * 768 + 256 + (vh & 1) * 128 + (c2 & 127);
  }
  float acc = 0.f;
#pragma unroll
  for (int s = 0; s < 4; ++s) {
    const int tt = t - 3 + s;
    if (tt >= 0) acc = fmaf(qkvz[(size_t)tt * NQKVZ + col], conv_w[c * 4 + s], acc);
  }
  const float y = acc / (1.f + expf(-acc));  // silu
  if (c < 4096) QK[(size_t)t * 4096 + c] = y;
  else          V[(size_t)t * 4096 + (c - 4096)] = y;
}

// ---------------- l2norm over DK for q and k (per t, per k-head) -------------
__global__ void l2norm_qk(float* __restrict__ QK) {
  const int h = blockIdx.x, t = blockIdx.y, l = threadIdx.x;  // 64 threads
  const size_t qb = (size_t)t * 4096 + h * 128;
  const size_t kb = qb + 2048;
  float q0 = QK[qb + l], q1 = QK[qb + l + 64];
  float k0 = QK[kb + l], k1 = QK[kb + l + 64];
  float sq = q0 * q0 + q1 * q1;
  float sk = k0 * k0 + k1 * k1;
#pragma unroll
  for (int off = 32; off; off >>= 1) {
    sq += __shfl_xor(sq, off);
    sk += __shfl_xor(sk, off);
  }
  const float rq = rsqrtf(sq + 1e-6f) * 0.08838834764831845f;  // * DK^-0.5
  const float rk = rsqrtf(sk + 1e-6f);
  QK[qb + l] = q0 * rq; QK[qb + l + 64] = q1 * rq;
  QK[kb + l] = k0 * rk; QK[kb + l + 64] = k1 * rk;
}

// -------- g = -exp(A_log)*softplus(a+dt_bias) (log-decay), beta = sigmoid ----
__global__ void compute_gb(const float* __restrict__ ba,
                           const float* __restrict__ dt_bias,
                           const float* __restrict__ A_log,
                           float* __restrict__ gg, float* __restrict__ bet) {
  const int idx = blockIdx.x * 256 + threadIdx.x;  // t*32 + vh
  const int t = idx >> 5, vh = idx & 31;
  const float b = ba[t * 64 + (vh >> 1) * 4 + (vh & 1)];
  const float a = ba[t * 64 + (vh >> 1) * 4 + 2 + (vh & 1)];
  const float x = a + dt_bias[vh];
  const float sp = (x > 20.f) ? x : log1pf(expf(x));
  gg[idx] = -expf(A_log[vh]) * sp;
  bet[idx] = 1.f / (1.f + expf(-b));
}

// ---------------- phase 1: per (chunk, v-head) intra-chunk precompute --------
// Emits (bf16, pre-swizzled with idx ^ ((row&7)<<3) for conflict-free LDS
// fragment reads in phaseB):
//   Wb  [ch][h][64][128] = -(M βγk)     (negated!)
//   KTb [ch][h][128][64] = (λk)^T
//   Qgb [ch][h][64][128] = γq
//   Bb  [ch][h][64][64]  = e^{b_i-b_j}(q_i·k_j), j<=i
//   U   [ch][h][64][128] fp32 = M βv;  gend scalar per (ch,h).
__global__ __launch_bounds__(256) void phase1(
    const float* __restrict__ QK, const float* __restrict__ V,
    const float* __restrict__ g, const float* __restrict__ bet,
    float* __restrict__ U, __hip_bfloat16* __restrict__ Wb,
    __hip_bfloat16* __restrict__ KTb, __hip_bfloat16* __restrict__ Qgb,
    __hip_bfloat16* __restrict__ Bb, float* __restrict__ gend) {
  const int vh = blockIdx.x, ch = blockIdx.y, kh = vh >> 1;
  const int tid = threadIdx.x;
  const int t0 = ch * CHUNK;
  __shared__ __align__(16) float Kl[64][132];
  __shared__ float Al[64][64];
  __shared__ __align__(16) float Xl[64][256];
  __shared__ float bs[64], gams[64], bets[64], lams[64];

  const int row = tid >> 2;
  const size_t hb = (size_t)ch * 32 + vh;
  {
    const int cc = (tid & 3) * 32;
    const float* src = &QK[(size_t)(t0 + row) * 4096 + 2048 + kh * 128 + cc];
#pragma unroll
    for (int u = 0; u < 32; u += 4)
      *reinterpret_cast<float4*>(&Kl[row][cc + u]) =
          *reinterpret_cast<const float4*>(src + u);
  }
  if (tid < 64) {
    float b = g[(size_t)(t0 + tid) * 32 + vh];
#pragma unroll
    for (int off = 1; off < 64; off <<= 1) {
      const float o = __shfl_up(b, off);
      if (tid >= off) b += o;
    }
    const float b63 = __shfl(b, 63);
    const float ga = expf(b);
    bs[tid] = b;
    gams[tid] = ga;
    lams[tid] = expf(b63 - b);
    bets[tid] = bet[(size_t)(t0 + tid) * 32 + vh];
    if (tid == 63) gend[ch * 32 + vh] = ga;
  }
  __syncthreads();
  // KTb: [d][i] = lam_i * k[i][d], swizzled by d
  {
    const int i = tid & 63;
    const float li = lams[i];
    __hip_bfloat16* kt = &KTb[hb * 128 * 64];
    const int dbase = (tid >> 6) * 32;
#pragma unroll
    for (int dd = 0; dd < 32; ++dd) {
      const int d = dbase + dd;
      kt[(size_t)d * 64 + (i ^ ((d & 7) << 3))] = __float2bfloat16(li * Kl[i][d]);
    }
  }
  // A (LDS, strictly lower), Bb (bf16 swizzled), Qgb (bf16 swizzled)
  {
    const int j0 = (tid & 3) * 16;
    const float* qrow = &QK[(size_t)(t0 + row) * 4096 + kh * 128];
    const float gai = gams[row];
    __hip_bfloat16* qg = &Qgb[(hb * 64 + row) * 128];
    float accA[16], accB[16];
#pragma unroll
    for (int jj = 0; jj < 16; ++jj) { accA[jj] = 0.f; accB[jj] = 0.f; }
    for (int d = 0; d < 128; d += 4) {
      const float4 qi = *reinterpret_cast<const float4*>(qrow + d);
      const float4 ki = *reinterpret_cast<const float4*>(&Kl[row][d]);
      if ((d >> 5) == (tid & 3)) {
        ushort4 qq;
        qq.x = __bfloat16_as_ushort(__float2bfloat16(gai * qi.x));
        qq.y = __bfloat16_as_ushort(__float2bfloat16(gai * qi.y));
        qq.z = __bfloat16_as_ushort(__float2bfloat16(gai * qi.z));
        qq.w = __bfloat16_as_ushort(__float2bfloat16(gai * qi.w));
        *reinterpret_cast<ushort4*>(&qg[d ^ ((row & 7) << 3)]) = qq;
      }
#pragma unroll
      for (int jj = 0; jj < 16; ++jj) {
        const float4 kj = *reinterpret_cast<const float4*>(&Kl[j0 + jj][d]);
        accA[jj] += ki.x * kj.x + ki.y * kj.y + ki.z * kj.z + ki.w * kj.w;
        accB[jj] += qi.x * kj.x + qi.y * kj.y + qi.z * kj.z + qi.w * kj.w;
      }
    }
    const float bi = bets[row], bvi = bs[row];
    __hip_bfloat16* Bout = &Bb[(hb * 64 + row) * 64];
#pragma unroll
    for (int jj = 0; jj < 16; ++jj) {
      const int j = j0 + jj;
      const float dec = expf(bvi - bs[j]);
      Al[row][j] = (j < row) ? bi * dec * accA[jj] : 0.f;
      Bout[j ^ ((row & 7) << 3)] =
          __float2bfloat16((j <= row) ? dec * accB[jj] : 0.f);
    }
  }
  // X = [beta*v | beta*gamma*k]
  {
    const int qu = tid & 3;
    if (qu < 2) {
      const float bi = bets[row];
      const float* vsrc = &V[(size_t)(t0 + row) * 4096 + vh * 128 + qu * 64];
#pragma unroll
      for (int u = 0; u < 64; u += 4) {
        const float4 v4 = *reinterpret_cast<const float4*>(vsrc + u);
        *reinterpret_cast<float4*>(&Xl[row][qu * 64 + u]) =
            make_float4(bi * v4.x, bi * v4.y, bi * v4.z, bi * v4.w);
      }
    } else {
      const float s = bets[row] * gams[row];
#pragma unroll
      for (int u = 0; u < 64; u += 4) {
        const float4 k4 = *reinterpret_cast<const float4*>(&Kl[row][(qu - 2) * 64 + u]);
        *reinterpret_cast<float4*>(&Xl[row][128 + (qu - 2) * 64 + u]) =
            make_float4(s * k4.x, s * k4.y, s * k4.z, s * k4.w);
      }
    }
  }
  __syncthreads();
  // forward substitution (I+A) X = R; cols 0..127 -> U fp32, 128..255 -> -Wb
  {
    const int cc = tid;
    for (int i = 1; i < 64; ++i) {
      float x = Xl[i][cc];
      for (int j = 0; j < i; ++j) x -= Al[i][j] * Xl[j][cc];
      Xl[i][cc] = x;
    }
    if (cc < 128) {
      float* dst = &U[hb * 64 * 128 + cc];
#pragma unroll 4
      for (int j = 0; j < 64; ++j) dst[(size_t)j * 128] = Xl[j][cc];
    } else {
      const int d = cc - 128;
      __hip_bfloat16* dst = &Wb[hb * 64 * 128];
#pragma unroll 4
      for (int j = 0; j < 64; ++j)
        dst[(size_t)j * 128 + (d ^ ((j & 7) << 3))] = __float2bfloat16(-Xl[j][cc]);
    }
  }
}

// ---------------- phaseB: serial MFMA state propagation ----------------------
// grid (32 heads, 4 slices of 32 DV-cols) x 128 thr (2 waves, 16 cols/wave).
// Per chunk/wave: delta = U + (-W)@S (16 MFMA); o = γq@S + B@δ (24 MFMA);
// S = ge*S + Kᵀλ@δ (16 MFMA). Master S fp32 in accumulators.
__global__ __launch_bounds__(128) void phaseB(
    const float* __restrict__ Ug, const __hip_bfloat16* __restrict__ Wb,
    const __hip_bfloat16* __restrict__ KTb, const __hip_bfloat16* __restrict__ Qgb,
    const __hip_bfloat16* __restrict__ Bb, const float* __restrict__ gendg,
    float* __restrict__ Og) {
  const int vh = blockIdx.x, slice = blockIdx.y;
  const int tid = threadIdx.x, lane = tid & 63, w = tid >> 6;
  const int l15 = lane & 15, l4 = lane >> 4;
  const int cg = slice * 32 + w * 16;
  const int swz = (l15 & 7) << 3;

  __shared__ __hip_bfloat16 Wl[2][8192];
  __shared__ __hip_bfloat16 KTl[2][8192];
  __shared__ __hip_bfloat16 Qgl[2][8192];
  __shared__ __hip_bfloat16 Bl[2][4096];
  __shared__ __hip_bfloat16 Sop[2][2048];  // [wave][col*128 + dk^swz]
  __shared__ __hip_bfloat16 dLs[2][1024];  // [wave][col*64 + i^swz]

  f32x4 accS[8] = {};
  for (int x = lane; x < 1024; x += 64) reinterpret_cast<uint*>(Sop[w])[x] = 0;

  float ubuf[4][4];
#define STAGE(b_, c_) do {                                                      \
    const size_t hb_ = ((size_t)(c_) * 32 + vh);                                \
    _Pragma("unroll") for (int it = 0; it < 8; ++it) {                          \
      __builtin_amdgcn_global_load_lds(                                         \
          (const __attribute__((address_space(1))) void*)(Wb + hb_ * 8192 + it * 1024 + tid * 8), \
          (__attribute__((address_space(3))) void*)(&Wl[b_][it * 1024 + tid * 8]), 16, 0, 0); \
      __builtin_amdgcn_global_load_lds(                                         \
          (const __attribute__((address_space(1))) void*)(KTb + hb_ * 8192 + it * 1024 + tid * 8), \
          (__attribute__((address_space(3))) void*)(&KTl[b_][it * 1024 + tid * 8]), 16, 0, 0); \
      __builtin_amdgcn_global_load_lds(                                         \
          (const __attribute__((address_space(1))) void*)(Qgb + hb_ * 8192 + it * 1024 + tid * 8), \
          (__attribute__((address_space(3))) void*)(&Qgl[b_][it * 1024 + tid * 8]), 16, 0, 0); \
      if (it < 4)                                                               \
        __builtin_amdgcn_global_load_lds(                                       \
            (const __attribute__((address_space(1))) void*)(Bb + hb_ * 4096 + it * 1024 + tid * 8), \
            (__attribute__((address_space(3))) void*)(&Bl[b_][it * 1024 + tid * 8]), 16, 0, 0); \
    }                                                                           \
  } while (0)
#define UPREF(c_) do {                                                          \
    const float* up_ = Ug + ((size_t)(c_) * 32 + vh) * 64 * 128 + cg + l15;     \
    _Pragma("unroll") for (int m_ = 0; m_ < 4; ++m_)                            \
      _Pragma("unroll") for (int r_ = 0; r_ < 4; ++r_)                          \
        ubuf[m_][r_] = up_[(size_t)(m_ * 16 + l4 * 4 + r_) * 128];              \
  } while (0)

  STAGE(0, 0);
  UPREF(0);
  __syncthreads();
  int buf = 0;
  for (int ch = 0; ch < NCHUNK; ++ch) {
    if (ch + 1 < NCHUNK) STAGE(buf ^ 1, ch + 1);
    f32x4 acc_d[4];
#pragma unroll
    for (int m = 0; m < 4; ++m) {
      f32x4 t;
      t[0] = ubuf[m][0]; t[1] = ubuf[m][1]; t[2] = ubuf[m][2]; t[3] = ubuf[m][3];
      acc_d[m] = t;
    }
    if (ch + 1 < NCHUNK) UPREF(ch + 1);
    // op1: delta = U + (-W) @ S
#pragma unroll
    for (int t = 0; t < 4; ++t) {
      const bf16x8 bS = *reinterpret_cast<const bf16x8*>(
          &Sop[w][l15 * 128 + ((t * 32 + l4 * 8) ^ swz)]);
#pragma unroll
      for (int m = 0; m < 4; ++m) {
        const bf16x8 aW = *reinterpret_cast<const bf16x8*>(
            &Wl[buf][(m * 16 + l15) * 128 + ((t * 32 + l4 * 8) ^ swz)]);
        acc_d[m] = __builtin_amdgcn_mfma_f32_16x16x32_bf16(aW, bS, acc_d[m], 0, 0, 0);
      }
    }
    // delta^T -> wave-local LDS (bf16)
#pragma unroll
    for (int m = 0; m < 4; ++m)
      *reinterpret_cast<ushort4*>(&dLs[w][l15 * 64 + ((m * 16 + l4 * 4) ^ swz)]) =
          pack4(acc_d[m]);
    // opO: o = γq @ S + B @ δ
    f32x4 acc_o[4] = {};
#pragma unroll
    for (int t = 0; t < 4; ++t) {
      const bf16x8 bS = *reinterpret_cast<const bf16x8*>(
          &Sop[w][l15 * 128 + ((t * 32 + l4 * 8) ^ swz)]);
#pragma unroll
      for (int m = 0; m < 4; ++m) {
        const bf16x8 aQ = *reinterpret_cast<const bf16x8*>(
            &Qgl[buf][(m * 16 + l15) * 128 + ((t * 32 + l4 * 8) ^ swz)]);
        acc_o[m] = __builtin_amdgcn_mfma_f32_16x16x32_bf16(aQ, bS, acc_o[m], 0, 0, 0);
      }
    }
#pragma unroll
    for (int t2 = 0; t2 < 2; ++t2) {
      const bf16x8 bD = *reinterpret_cast<const bf16x8*>(
          &dLs[w][l15 * 64 + ((t2 * 32 + l4 * 8) ^ swz)]);
#pragma unroll
      for (int m = 0; m < 4; ++m) {
        const bf16x8 aB = *reinterpret_cast<const bf16x8*>(
            &Bl[buf][(m * 16 + l15) * 64 + ((t2 * 32 + l4 * 8) ^ swz)]);
        acc_o[m] = __builtin_amdgcn_mfma_f32_16x16x32_bf16(aB, bD, acc_o[m], 0, 0, 0);
      }
    }
    float* ob = Og + (size_t)(ch * 64) * 4096 + (size_t)vh * 128 + cg + l15;
#pragma unroll
    for (int m = 0; m < 4; ++m)
#pragma unroll
      for (int r = 0; r < 4; ++r)
        ob[(size_t)(m * 16 + l4 * 4 + r) * 4096] = acc_o[m][r];
    // op3: S = ge*S + Kᵀλ @ δ
    const float ge = gendg[ch * 32 + vh];
#pragma unroll
    for (int f = 0; f < 8; ++f) {
      accS[f][0] *= ge; accS[f][1] *= ge; accS[f][2] *= ge; accS[f][3] *= ge;
    }
#pragma unroll
    for (int t2 = 0; t2 < 2; ++t2) {
      const bf16x8 bD = *reinterpret_cast<const bf16x8*>(
          &dLs[w][l15 * 64 + ((t2 * 32 + l4 * 8) ^ swz)]);
#pragma unroll
      for (int f = 0; f < 8; ++f) {
        const bf16x8 aK = *reinterpret_cast<const bf16x8*>(
            &KTl[buf][(f * 16 + l15) * 64 + ((t2 * 32 + l4 * 8) ^ swz)]);
        accS[f] = __builtin_amdgcn_mfma_f32_16x16x32_bf16(aK, bD, accS[f], 0, 0, 0);
      }
    }
    // refresh S operand copy for next chunk
#pragma unroll
    for (int f = 0; f < 8; ++f)
      *reinterpret_cast<ushort4*>(&Sop[w][l15 * 128 + ((f * 16 + l4 * 4) ^ swz)]) =
          pack4(accS[f]);
    __syncthreads();
    buf ^= 1;
  }
#undef STAGE
#undef UPREF
}

// ------- gated = rmsnorm(o * silu(z)) * norm_w, emitted as bf16 --------------
__global__ void gate_norm(const float* __restrict__ O,
                          const float* __restrict__ qkvz,
                          const float* __restrict__ norm_w,
                          __hip_bfloat16* __restrict__ G) {
  const int vh = blockIdx.x, t = blockIdx.y, l = threadIdx.x;  // 64 threads
  const size_t ob = (size_t)t * 4096 + vh * 128;
  const size_t zb = (size_t)t * NQKVZ + (vh >> 1) * 768 + 512 + (vh & 1) * 128;
  const float o0 = O[ob + l], o1 = O[ob + l + 64];
  const float z0 = qkvz[zb + l], z1 = qkvz[zb + l + 64];
  const float g0 = o0 * z0 / (1.f + expf(-z0));
  const float g1 = o1 * z1 / (1.f + expf(-z1));
  float ss = g0 * g0 + g1 * g1;
#pragma unroll
  for (int off = 32; off; off >>= 1) ss += __shfl_xor(ss, off);
  const float rr = rsqrtf(ss * (1.f / 128.f) + 1e-6f);
  G[ob + l] = __float2bfloat16(g0 * rr * norm_w[l]);
  G[ob + l + 64] = __float2bfloat16(g1 * rr * norm_w[l + 64]);
}

extern "C" void kernel_launch(void* const* d_in, const int* in_sizes, int n_in,
                              void* d_out, int out_size, void* d_ws, size_t ws_size,
                              hipStream_t stream) {
  const float* X = (const float*)d_in[0];
  const float* W_qkvz = (const float*)d_in[1];
  const float* W_ba = (const float*)d_in[2];
  const float* conv_w = (const float*)d_in[3];
  const float* dt_bias = (const float*)d_in[4];
  const float* A_log = (const float*)d_in[5];
  const float* norm_w = (const float*)d_in[6];
  const float* W_out = (const float*)d_in[7];
  float* out = (float*)d_out;

  float* ws = (float*)d_ws;
  float* qkvz = ws;                                // 12,582,912 f
  float* ba = qkvz + (size_t)T_LEN * NQKVZ;        //     65,536 f
  float* QK = ba + (size_t)T_LEN * 64;             //  4,194,304 f
  float* V = QK + (size_t)T_LEN * 4096;            //  4,194,304 f
  float* U = V + (size_t)T_LEN * 4096;             //  4,194,304 f
  float* Wb_f = U + (size_t)NCHUNK * 32 * 64 * 128;//  2,097,152 f (bf16 x 4.19M)
  float* KT_f = Wb_f + 2097152;                    //  2,097,152 f
  float* Qg_f = KT_f + 2097152;                    //  2,097,152 f
  float* Bb_f = Qg_f + 2097152;                    //  1,048,576 f (bf16 x 2.10M)
  float* gg = Bb_f + 1048576;                      //     32,768 f
  float* bet = gg + 32768;                         //     32,768 f
  float* gend = bet + 32768;                       //        512 f

  __hip_bfloat16* Wb = (__hip_bfloat16*)Wb_f;
  __hip_bfloat16* KTb = (__hip_bfloat16*)KT_f;
  __hip_bfloat16* Qgb = (__hip_bfloat16*)Qg_f;
  __hip_bfloat16* Bb = (__hip_bfloat16*)Bb_f;
  // lifetime aliases:
  __hip_bfloat16* Wqkvz_t = (__hip_bfloat16*)V;    // spans V+U+Wb+KT = 25.17M bf16 (dead after 1st gemm)
  __hip_bfloat16* Xb = (__hip_bfloat16*)Qg_f;      // dead after 1st gemm; Qgb written by phase1 later
  __hip_bfloat16* Gb = (__hip_bfloat16*)Bb_f;      // Bb dead after phaseB
  __hip_bfloat16* Wout_t = (__hip_bfloat16*)qkvz;  // qkvz dead after gate_norm
  float* O = V;                                    // V dead after phase1

  cast_bf16<<<dim3(T_LEN * 2048 / 4 / 256), 256, 0, stream>>>(X, Xb, T_LEN * 2048);
  transpose_cast<<<dim3(NQKVZ / 32, 2048 / 32), 256, 0, stream>>>(W_qkvz, Wqkvz_t, 2048, NQKVZ);
  gemm_bf16<<<dim3(NQKVZ / 128, T_LEN / 128), 256, 0, stream>>>(Xb, Wqkvz_t, qkvz, T_LEN, NQKVZ, 2048);
  gemm_f32<<<dim3(1, T_LEN / 64), 256, 0, stream>>>(X, W_ba, ba, T_LEN, 64, 2048);
  conv_silu<<<dim3(CDIM / 256, T_LEN), 256, 0, stream>>>(qkvz, conv_w, QK, V);
  l2norm_qk<<<dim3(HK_N, T_LEN), 64, 0, stream>>>(QK);
  compute_gb<<<dim3(T_LEN * 32 / 256), 256, 0, stream>>>(ba, dt_bias, A_log, gg, bet);
  phase1<<<dim3(HV_N, NCHUNK), 256, 0, stream>>>(QK, V, gg, bet, U, Wb, KTb, Qgb, Bb, gend);
  phaseB<<<dim3(HV_N, 4), 128, 0, stream>>>(U, Wb, KTb, Qgb, Bb, gend, O);
  gate_norm<<<dim3(HV_N, T_LEN), 64, 0, stream>>>(O, qkvz, norm_w, Gb);
  transpose_cast<<<dim3(2048 / 32, 4096 / 32), 256, 0, stream>>>(W_out, Wout_t, 4096, 2048);
  gemm_bf16<<<dim3(2048 / 128, T_LEN / 128), 256, 0, stream>>>(Gb, Wout_t, out, T_LEN, 2048, 4096);
}

// Round 5
// 467.557 us; speedup vs baseline: 9.4667x; 1.1469x over previous
//
#include <hip/hip_runtime.h>
#include <hip/hip_bf16.h>
#include <math.h>

// Qwen3Next GatedDeltaNet — round 4: phase1 rewritten with register-resident
// right-looking triangular solve (was: serial LDS-latency-bound loop at
// 1 wave/SIMD). LDS 114->51 KB (2 blocks/CU), Al padded to kill 32-way
// write conflicts. Everything else unchanged from round 3.

#define T_LEN 1024
#define HK_N 16
#define HV_N 32
#define NQKVZ 12288
#define CDIM 8192
#define CHUNK 64
#define NCHUNK 16

typedef __bf16 bf16x8 __attribute__((ext_vector_type(8)));
typedef float f32x4 __attribute__((ext_vector_type(4)));

__device__ __forceinline__ ushort4 pack4(const f32x4 v) {
  ushort4 o;
  o.x = __bfloat16_as_ushort(__float2bfloat16(v[0]));
  o.y = __bfloat16_as_ushort(__float2bfloat16(v[1]));
  o.z = __bfloat16_as_ushort(__float2bfloat16(v[2]));
  o.w = __bfloat16_as_ushort(__float2bfloat16(v[3]));
  return o;
}

// ---------------- bf16 MFMA GEMM: C[M,N] = A[M,K] @ B[N,K]^T -----------------
__global__ __launch_bounds__(256) void gemm_bf16(const __hip_bfloat16* __restrict__ A,
                                                 const __hip_bfloat16* __restrict__ B,
                                                 float* __restrict__ C,
                                                 int M, int N, int K) {
  __shared__ __align__(16) __hip_bfloat16 As[128 * 32];
  __shared__ __align__(16) __hip_bfloat16 Bs[128 * 32];
  const int tid = threadIdx.x;
  const int wid = tid >> 6, lane = tid & 63;
  const int wr = wid >> 1, wc = wid & 1;
  const int m0 = blockIdx.y * 128, n0 = blockIdx.x * 128;
  const int lrow = lane & 15, lk = lane >> 4;
  f32x4 acc[4][4] = {};

  for (int k0 = 0; k0 < K; k0 += 32) {
#pragma unroll
    for (int p = 0; p < 2; ++p) {
      const int c = p * 256 + wid * 64 + lane;
      const __hip_bfloat16* ga = A + (size_t)(m0 + (c >> 2)) * K + k0 + (c & 3) * 8;
      const __hip_bfloat16* gb = B + (size_t)(n0 + (c >> 2)) * K + k0 + (c & 3) * 8;
      __builtin_amdgcn_global_load_lds(
          (const __attribute__((address_space(1))) void*)ga,
          (__attribute__((address_space(3))) void*)(As + p * 2048 + wid * 512), 16, 0, 0);
      __builtin_amdgcn_global_load_lds(
          (const __attribute__((address_space(1))) void*)gb,
          (__attribute__((address_space(3))) void*)(Bs + p * 2048 + wid * 512), 16, 0, 0);
    }
    __syncthreads();
    bf16x8 af[4], bfv[4];
#pragma unroll
    for (int m = 0; m < 4; ++m)
      af[m] = *reinterpret_cast<const bf16x8*>(As + (wr * 64 + m * 16 + lrow) * 32 + lk * 8);
#pragma unroll
    for (int n = 0; n < 4; ++n)
      bfv[n] = *reinterpret_cast<const bf16x8*>(Bs + (wc * 64 + n * 16 + lrow) * 32 + lk * 8);
#pragma unroll
    for (int m = 0; m < 4; ++m)
#pragma unroll
      for (int n = 0; n < 4; ++n)
        acc[m][n] = __builtin_amdgcn_mfma_f32_16x16x32_bf16(af[m], bfv[n], acc[m][n], 0, 0, 0);
    __syncthreads();
  }
#pragma unroll
  for (int m = 0; m < 4; ++m)
#pragma unroll
    for (int n = 0; n < 4; ++n)
#pragma unroll
      for (int r = 0; r < 4; ++r)
        C[(size_t)(m0 + wr * 64 + m * 16 + lk * 4 + r) * N + n0 + wc * 64 + n * 16 + lrow] =
            acc[m][n][r];
}

// ---------------- fp32 -> bf16 elementwise cast ------------------------------
__global__ void cast_bf16(const float* __restrict__ src,
                          __hip_bfloat16* __restrict__ dst, int n) {
  const int i = (blockIdx.x * 256 + threadIdx.x) * 4;
  if (i < n) {
    const float4 v = *reinterpret_cast<const float4*>(src + i);
    ushort4 o;
    o.x = __bfloat16_as_ushort(__float2bfloat16(v.x));
    o.y = __bfloat16_as_ushort(__float2bfloat16(v.y));
    o.z = __bfloat16_as_ushort(__float2bfloat16(v.z));
    o.w = __bfloat16_as_ushort(__float2bfloat16(v.w));
    *reinterpret_cast<ushort4*>((void*)(dst + i)) = o;
  }
}

// ---------------- fp32 [K,N] -> bf16 [N,K] tiled transpose-cast --------------
__global__ __launch_bounds__(256) void transpose_cast(const float* __restrict__ src,
                                                      __hip_bfloat16* __restrict__ dst,
                                                      int K, int N) {
  __shared__ float tl[32][33];
  const int n0 = blockIdx.x * 32, k0 = blockIdx.y * 32;
  const int tx = threadIdx.x & 31, ty = threadIdx.x >> 5;
#pragma unroll
  for (int i = 0; i < 4; ++i)
    tl[ty + 8 * i][tx] = src[(size_t)(k0 + ty + 8 * i) * N + n0 + tx];
  __syncthreads();
#pragma unroll
  for (int i = 0; i < 4; ++i)
    dst[(size_t)(n0 + ty + 8 * i) * K + k0 + tx] = __float2bfloat16(tl[tx][ty + 8 * i]);
}

// ---------------- generic fp32 tiled GEMM (tiny ba GEMM) ---------------------
__global__ __launch_bounds__(256) void gemm_f32(const float* __restrict__ A,
                                                const float* __restrict__ B,
                                                float* __restrict__ C,
                                                int M, int N, int K) {
  __shared__ __align__(16) float Asl[16][64];
  __shared__ __align__(16) float Bsl[16][64];
  const int tid = threadIdx.x;
  const int tx = tid & 15, ty = tid >> 4;
  const int m0 = blockIdx.y * 64, n0 = blockIdx.x * 64;
  const int ar = tid >> 2, akc = (tid & 3) << 2;
  const int bk = tid >> 4, bn = (tid & 15) << 2;
  float acc[4][4] = {};
  for (int k0 = 0; k0 < K; k0 += 16) {
    float4 av = *reinterpret_cast<const float4*>(&A[(size_t)(m0 + ar) * K + k0 + akc]);
    float4 bv = *reinterpret_cast<const float4*>(&B[(size_t)(k0 + bk) * N + n0 + bn]);
    Asl[akc + 0][ar] = av.x;
    Asl[akc + 1][ar] = av.y;
    Asl[akc + 2][ar] = av.z;
    Asl[akc + 3][ar] = av.w;
    *reinterpret_cast<float4*>(&Bsl[bk][bn]) = bv;
    __syncthreads();
#pragma unroll
    for (int kk = 0; kk < 16; ++kk) {
      float a[4], b[4];
#pragma unroll
      for (int i = 0; i < 4; ++i) a[i] = Asl[kk][ty * 4 + i];
#pragma unroll
      for (int j = 0; j < 4; ++j) b[j] = Bsl[kk][tx * 4 + j];
#pragma unroll
      for (int i = 0; i < 4; ++i)
#pragma unroll
        for (int j = 0; j < 4; ++j) acc[i][j] = fmaf(a[i], b[j], acc[i][j]);
    }
    __syncthreads();
  }
#pragma unroll
  for (int i = 0; i < 4; ++i)
#pragma unroll
    for (int j = 0; j < 4; ++j)
      C[(size_t)(m0 + ty * 4 + i) * N + n0 + tx * 4 + j] = acc[i][j];
}

// ------------- causal depthwise conv (K=4) + silu, with qkvz gather ----------
__global__ void conv_silu(const float* __restrict__ qkvz,
                          const float* __restrict__ conv_w,
                          float* __restrict__ QK, float* __restrict__ V) {
  const int c = blockIdx.x * 256 + threadIdx.x;
  const int t = blockIdx.y;
  int col;
  if (c < 2048) {
    col = (c >> 7) * 768 + (c & 127);
  } else if (c < 4096) {
    const int c2 = c - 2048;
    col = (c2 >> 7) * 768 + 128 + (c2 & 127);
  } else {
    const int c2 = c - 4096;
    const int vh = c2 >> 7;
    col = (vh >> 1) * 768 + 256 + (vh & 1) * 128 + (c2 & 127);
  }
  float acc = 0.f;
#pragma unroll
  for (int s = 0; s < 4; ++s) {
    const int tt = t - 3 + s;
    if (tt >= 0) acc = fmaf(qkvz[(size_t)tt * NQKVZ + col], conv_w[c * 4 + s], acc);
  }
  const float y = acc / (1.f + expf(-acc));  // silu
  if (c < 4096) QK[(size_t)t * 4096 + c] = y;
  else          V[(size_t)t * 4096 + (c - 4096)] = y;
}

// ---------------- l2norm over DK for q and k (per t, per k-head) -------------
__global__ void l2norm_qk(float* __restrict__ QK) {
  const int h = blockIdx.x, t = blockIdx.y, l = threadIdx.x;  // 64 threads
  const size_t qb = (size_t)t * 4096 + h * 128;
  const size_t kb = qb + 2048;
  float q0 = QK[qb + l], q1 = QK[qb + l + 64];
  float k0 = QK[kb + l], k1 = QK[kb + l + 64];
  float sq = q0 * q0 + q1 * q1;
  float sk = k0 * k0 + k1 * k1;
#pragma unroll
  for (int off = 32; off; off >>= 1) {
    sq += __shfl_xor(sq, off);
    sk += __shfl_xor(sk, off);
  }
  const float rq = rsqrtf(sq + 1e-6f) * 0.08838834764831845f;  // * DK^-0.5
  const float rk = rsqrtf(sk + 1e-6f);
  QK[qb + l] = q0 * rq; QK[qb + l + 64] = q1 * rq;
  QK[kb + l] = k0 * rk; QK[kb + l + 64] = k1 * rk;
}

// -------- g = -exp(A_log)*softplus(a+dt_bias) (log-decay), beta = sigmoid ----
__global__ void compute_gb(const float* __restrict__ ba,
                           const float* __restrict__ dt_bias,
                           const float* __restrict__ A_log,
                           float* __restrict__ gg, float* __restrict__ bet) {
  const int idx = blockIdx.x * 256 + threadIdx.x;  // t*32 + vh
  const int t = idx >> 5, vh = idx & 31;
  const float b = ba[t * 64 + (vh >> 1) * 4 + (vh & 1)];
  const float a = ba[t * 64 + (vh >> 1) * 4 + 2 + (vh & 1)];
  const float x = a + dt_bias[vh];
  const float sp = (x > 20.f) ? x : log1pf(expf(x));
  gg[idx] = -expf(A_log[vh]) * sp;
  bet[idx] = 1.f / (1.f + expf(-b));
}

// ---------------- phase 1: per (chunk, v-head) intra-chunk precompute --------
// Emits (bf16, pre-swizzled with idx ^ ((row&7)<<3)):
//   Wb  [ch][h][64][128] = -(M βγk)   KTb [ch][h][128][64] = (λk)^T
//   Qgb [ch][h][64][128] = γq         Bb  [ch][h][64][64]  = decayed QK^T (j<=i)
//   U   [ch][h][64][128] fp32 = M βv; gend per (ch,h).
// Round 4: triangular solve is register-resident right-looking (fully
// unrolled), RHS loaded straight from global; Al padded [64][65].
__global__ __launch_bounds__(256, 2) void phase1(
    const float* __restrict__ QK, const float* __restrict__ V,
    const float* __restrict__ g, const float* __restrict__ bet,
    float* __restrict__ U, __hip_bfloat16* __restrict__ Wb,
    __hip_bfloat16* __restrict__ KTb, __hip_bfloat16* __restrict__ Qgb,
    __hip_bfloat16* __restrict__ Bb, float* __restrict__ gend) {
  const int vh = blockIdx.x, ch = blockIdx.y, kh = vh >> 1;
  const int tid = threadIdx.x;
  const int t0 = ch * CHUNK;
  __shared__ __align__(16) float Kl[64][132];
  __shared__ float Al[64][65];
  __shared__ float bs[64], gams[64], bets[64], lams[64];

  const int row = tid >> 2;
  const size_t hb = (size_t)ch * 32 + vh;
  // 1. K tile -> LDS
  {
    const int cc = (tid & 3) * 32;
    const float* src = &QK[(size_t)(t0 + row) * 4096 + 2048 + kh * 128 + cc];
#pragma unroll
    for (int u = 0; u < 32; u += 4)
      *reinterpret_cast<float4*>(&Kl[row][cc + u]) =
          *reinterpret_cast<const float4*>(src + u);
  }
  // 2. inclusive cumsum of g; decay scalars
  if (tid < 64) {
    float b = g[(size_t)(t0 + tid) * 32 + vh];
#pragma unroll
    for (int off = 1; off < 64; off <<= 1) {
      const float o = __shfl_up(b, off);
      if (tid >= off) b += o;
    }
    const float b63 = __shfl(b, 63);
    const float ga = expf(b);
    bs[tid] = b;
    gams[tid] = ga;
    lams[tid] = expf(b63 - b);
    bets[tid] = bet[(size_t)(t0 + tid) * 32 + vh];
    if (tid == 63) gend[ch * 32 + vh] = ga;
  }
  __syncthreads();
  // 3. KTb: [d][i] = lam_i * k[i][d], swizzled by d
  {
    const int i = tid & 63;
    const float li = lams[i];
    __hip_bfloat16* kt = &KTb[hb * 128 * 64];
    const int dbase = (tid >> 6) * 32;
#pragma unroll
    for (int dd = 0; dd < 32; ++dd) {
      const int d = dbase + dd;
      kt[(size_t)d * 64 + (i ^ ((d & 7) << 3))] = __float2bfloat16(li * Kl[i][d]);
    }
  }
  // 4. A (LDS, strictly lower, padded), Bb (bf16 swizzled), Qgb (bf16 swizzled)
  {
    const int j0 = (tid & 3) * 16;
    const float* qrow = &QK[(size_t)(t0 + row) * 4096 + kh * 128];
    const float gai = gams[row];
    __hip_bfloat16* qg = &Qgb[(hb * 64 + row) * 128];
    float accA[16], accB[16];
#pragma unroll
    for (int jj = 0; jj < 16; ++jj) { accA[jj] = 0.f; accB[jj] = 0.f; }
    for (int d = 0; d < 128; d += 4) {
      const float4 qi = *reinterpret_cast<const float4*>(qrow + d);
      const float4 ki = *reinterpret_cast<const float4*>(&Kl[row][d]);
      if ((d >> 5) == (tid & 3)) {
        ushort4 qq;
        qq.x = __bfloat16_as_ushort(__float2bfloat16(gai * qi.x));
        qq.y = __bfloat16_as_ushort(__float2bfloat16(gai * qi.y));
        qq.z = __bfloat16_as_ushort(__float2bfloat16(gai * qi.z));
        qq.w = __bfloat16_as_ushort(__float2bfloat16(gai * qi.w));
        *reinterpret_cast<ushort4*>(&qg[d ^ ((row & 7) << 3)]) = qq;
      }
#pragma unroll
      for (int jj = 0; jj < 16; ++jj) {
        const float4 kj = *reinterpret_cast<const float4*>(&Kl[j0 + jj][d]);
        accA[jj] += ki.x * kj.x + ki.y * kj.y + ki.z * kj.z + ki.w * kj.w;
        accB[jj] += qi.x * kj.x + qi.y * kj.y + qi.z * kj.z + qi.w * kj.w;
      }
    }
    const float bi = bets[row], bvi = bs[row];
    __hip_bfloat16* Bout = &Bb[(hb * 64 + row) * 64];
#pragma unroll
    for (int jj = 0; jj < 16; ++jj) {
      const int j = j0 + jj;
      const float dec = expf(bvi - bs[j]);
      Al[row][j] = (j < row) ? bi * dec * accA[jj] : 0.f;
      Bout[j ^ ((row & 7) << 3)] =
          __float2bfloat16((j <= row) ? dec * accB[jj] : 0.f);
    }
  }
  __syncthreads();
  // 5. register-resident right-looking solve of (I+A) x = rhs, column tid.
  {
    const int cc = tid;
    float x[64];
    const bool isV = cc < 128;
    const float* src = isV ? &V[(size_t)t0 * 4096 + vh * 128 + cc]
                           : &QK[(size_t)t0 * 4096 + 2048 + kh * 128 + (cc - 128)];
#pragma unroll
    for (int i = 0; i < 64; ++i) {
      const float sc = isV ? bets[i] : bets[i] * gams[i];
      x[i] = sc * src[(size_t)i * 4096];
    }
#pragma unroll
    for (int j = 0; j < 63; ++j)
#pragma unroll
      for (int i = j + 1; i < 64; ++i)
        x[i] = fmaf(-Al[i][j], x[j], x[i]);
    if (isV) {
      float* dst = &U[hb * 64 * 128 + cc];
#pragma unroll
      for (int i = 0; i < 64; ++i) dst[(size_t)i * 128] = x[i];
    } else {
      const int d = cc - 128;
      __hip_bfloat16* dst = &Wb[hb * 64 * 128];
#pragma unroll
      for (int i = 0; i < 64; ++i)
        dst[(size_t)i * 128 + (d ^ ((i & 7) << 3))] = __float2bfloat16(-x[i]);
    }
  }
}

// ---------------- phaseB: serial MFMA state propagation ----------------------
__global__ __launch_bounds__(128) void phaseB(
    const float* __restrict__ Ug, const __hip_bfloat16* __restrict__ Wb,
    const __hip_bfloat16* __restrict__ KTb, const __hip_bfloat16* __restrict__ Qgb,
    const __hip_bfloat16* __restrict__ Bb, const float* __restrict__ gendg,
    float* __restrict__ Og) {
  const int vh = blockIdx.x, slice = blockIdx.y;
  const int tid = threadIdx.x, lane = tid & 63, w = tid >> 6;
  const int l15 = lane & 15, l4 = lane >> 4;
  const int cg = slice * 32 + w * 16;
  const int swz = (l15 & 7) << 3;

  __shared__ __hip_bfloat16 Wl[2][8192];
  __shared__ __hip_bfloat16 KTl[2][8192];
  __shared__ __hip_bfloat16 Qgl[2][8192];
  __shared__ __hip_bfloat16 Bl[2][4096];
  __shared__ __hip_bfloat16 Sop[2][2048];
  __shared__ __hip_bfloat16 dLs[2][1024];

  f32x4 accS[8] = {};
  for (int x = lane; x < 1024; x += 64) reinterpret_cast<uint*>(Sop[w])[x] = 0;

  float ubuf[4][4];
#define STAGE(b_, c_) do {                                                      \
    const size_t hb_ = ((size_t)(c_) * 32 + vh);                                \
    _Pragma("unroll") for (int it = 0; it < 8; ++it) {                          \
      __builtin_amdgcn_global_load_lds(                                         \
          (const __attribute__((address_space(1))) void*)(Wb + hb_ * 8192 + it * 1024 + tid * 8), \
          (__attribute__((address_space(3))) void*)(&Wl[b_][it * 1024 + tid * 8]), 16, 0, 0); \
      __builtin_amdgcn_global_load_lds(                                         \
          (const __attribute__((address_space(1))) void*)(KTb + hb_ * 8192 + it * 1024 + tid * 8), \
          (__attribute__((address_space(3))) void*)(&KTl[b_][it * 1024 + tid * 8]), 16, 0, 0); \
      __builtin_amdgcn_global_load_lds(                                         \
          (const __attribute__((address_space(1))) void*)(Qgb + hb_ * 8192 + it * 1024 + tid * 8), \
          (__attribute__((address_space(3))) void*)(&Qgl[b_][it * 1024 + tid * 8]), 16, 0, 0); \
      if (it < 4)                                                               \
        __builtin_amdgcn_global_load_lds(                                       \
            (const __attribute__((address_space(1))) void*)(Bb + hb_ * 4096 + it * 1024 + tid * 8), \
            (__attribute__((address_space(3))) void*)(&Bl[b_][it * 1024 + tid * 8]), 16, 0, 0); \
    }                                                                           \
  } while (0)
#define UPREF(c_) do {                                                          \
    const float* up_ = Ug + ((size_t)(c_) * 32 + vh) * 64 * 128 + cg + l15;     \
    _Pragma("unroll") for (int m_ = 0; m_ < 4; ++m_)                            \
      _Pragma("unroll") for (int r_ = 0; r_ < 4; ++r_)                          \
        ubuf[m_][r_] = up_[(size_t)(m_ * 16 + l4 * 4 + r_) * 128];              \
  } while (0)

  STAGE(0, 0);
  UPREF(0);
  __syncthreads();
  int buf = 0;
  for (int ch = 0; ch < NCHUNK; ++ch) {
    if (ch + 1 < NCHUNK) STAGE(buf ^ 1, ch + 1);
    f32x4 acc_d[4];
#pragma unroll
    for (int m = 0; m < 4; ++m) {
      f32x4 t;
      t[0] = ubuf[m][0]; t[1] = ubuf[m][1]; t[2] = ubuf[m][2]; t[3] = ubuf[m][3];
      acc_d[m] = t;
    }
    if (ch + 1 < NCHUNK) UPREF(ch + 1);
    // op1: delta = U + (-W) @ S
#pragma unroll
    for (int t = 0; t < 4; ++t) {
      const bf16x8 bS = *reinterpret_cast<const bf16x8*>(
          &Sop[w][l15 * 128 + ((t * 32 + l4 * 8) ^ swz)]);
#pragma unroll
      for (int m = 0; m < 4; ++m) {
        const bf16x8 aW = *reinterpret_cast<const bf16x8*>(
            &Wl[buf][(m * 16 + l15) * 128 + ((t * 32 + l4 * 8) ^ swz)]);
        acc_d[m] = __builtin_amdgcn_mfma_f32_16x16x32_bf16(aW, bS, acc_d[m], 0, 0, 0);
      }
    }
#pragma unroll
    for (int m = 0; m < 4; ++m)
      *reinterpret_cast<ushort4*>(&dLs[w][l15 * 64 + ((m * 16 + l4 * 4) ^ swz)]) =
          pack4(acc_d[m]);
    // opO: o = γq @ S + B @ δ
    f32x4 acc_o[4] = {};
#pragma unroll
    for (int t = 0; t < 4; ++t) {
      const bf16x8 bS = *reinterpret_cast<const bf16x8*>(
          &Sop[w][l15 * 128 + ((t * 32 + l4 * 8) ^ swz)]);
#pragma unroll
      for (int m = 0; m < 4; ++m) {
        const bf16x8 aQ = *reinterpret_cast<const bf16x8*>(
            &Qgl[buf][(m * 16 + l15) * 128 + ((t * 32 + l4 * 8) ^ swz)]);
        acc_o[m] = __builtin_amdgcn_mfma_f32_16x16x32_bf16(aQ, bS, acc_o[m], 0, 0, 0);
      }
    }
#pragma unroll
    for (int t2 = 0; t2 < 2; ++t2) {
      const bf16x8 bD = *reinterpret_cast<const bf16x8*>(
          &dLs[w][l15 * 64 + ((t2 * 32 + l4 * 8) ^ swz)]);
#pragma unroll
      for (int m = 0; m < 4; ++m) {
        const bf16x8 aB = *reinterpret_cast<const bf16x8*>(
            &Bl[buf][(m * 16 + l15) * 64 + ((t2 * 32 + l4 * 8) ^ swz)]);
        acc_o[m] = __builtin_amdgcn_mfma_f32_16x16x32_bf16(aB, bD, acc_o[m], 0, 0, 0);
      }
    }
    float* ob = Og + (size_t)(ch * 64) * 4096 + (size_t)vh * 128 + cg + l15;
#pragma unroll
    for (int m = 0; m < 4; ++m)
#pragma unroll
      for (int r = 0; r < 4; ++r)
        ob[(size_t)(m * 16 + l4 * 4 + r) * 4096] = acc_o[m][r];
    // op3: S = ge*S + Kᵀλ @ δ
    const float ge = gendg[ch * 32 + vh];
#pragma unroll
    for (int f = 0; f < 8; ++f) {
      accS[f][0] *= ge; accS[f][1] *= ge; accS[f][2] *= ge; accS[f][3] *= ge;
    }
#pragma unroll
    for (int t2 = 0; t2 < 2; ++t2) {
      const bf16x8 bD = *reinterpret_cast<const bf16x8*>(
          &dLs[w][l15 * 64 + ((t2 * 32 + l4 * 8) ^ swz)]);
#pragma unroll
      for (int f = 0; f < 8; ++f) {
        const bf16x8 aK = *reinterpret_cast<const bf16x8*>(
            &KTl[buf][(f * 16 + l15) * 64 + ((t2 * 32 + l4 * 8) ^ swz)]);
        accS[f] = __builtin_amdgcn_mfma_f32_16x16x32_bf16(aK, bD, accS[f], 0, 0, 0);
      }
    }
#pragma unroll
    for (int f = 0; f < 8; ++f)
      *reinterpret_cast<ushort4*>(&Sop[w][l15 * 128 + ((f * 16 + l4 * 4) ^ swz)]) =
          pack4(accS[f]);
    __syncthreads();
    buf ^= 1;
  }
#undef STAGE
#undef UPREF
}

// ------- gated = rmsnorm(o * silu(z)) * norm_w, emitted as bf16 --------------
__global__ void gate_norm(const float* __restrict__ O,
                          const float* __restrict__ qkvz,
                          const float* __restrict__ norm_w,
                          __hip_bfloat16* __restrict__ G) {
  const int vh = blockIdx.x, t = blockIdx.y, l = threadIdx.x;  // 64 threads
  const size_t ob = (size_t)t * 4096 + vh * 128;
  const size_t zb = (size_t)t * NQKVZ + (vh >> 1) * 768 + 512 + (vh & 1) * 128;
  const float o0 = O[ob + l], o1 = O[ob + l + 64];
  const float z0 = qkvz[zb + l], z1 = qkvz[zb + l + 64];
  const float g0 = o0 * z0 / (1.f + expf(-z0));
  const float g1 = o1 * z1 / (1.f + expf(-z1));
  float ss = g0 * g0 + g1 * g1;
#pragma unroll
  for (int off = 32; off; off >>= 1) ss += __shfl_xor(ss, off);
  const float rr = rsqrtf(ss * (1.f / 128.f) + 1e-6f);
  G[ob + l] = __float2bfloat16(g0 * rr * norm_w[l]);
  G[ob + l + 64] = __float2bfloat16(g1 * rr * norm_w[l + 64]);
}

extern "C" void kernel_launch(void* const* d_in, const int* in_sizes, int n_in,
                              void* d_out, int out_size, void* d_ws, size_t ws_size,
                              hipStream_t stream) {
  const float* X = (const float*)d_in[0];
  const float* W_qkvz = (const float*)d_in[1];
  const float* W_ba = (const float*)d_in[2];
  const float* conv_w = (const float*)d_in[3];
  const float* dt_bias = (const float*)d_in[4];
  const float* A_log = (const float*)d_in[5];
  const float* norm_w = (const float*)d_in[6];
  const float* W_out = (const float*)d_in[7];
  float* out = (float*)d_out;

  float* ws = (float*)d_ws;
  float* qkvz = ws;                                // 12,582,912 f
  float* ba = qkvz + (size_t)T_LEN * NQKVZ;        //     65,536 f
  float* QK = ba + (size_t)T_LEN * 64;             //  4,194,304 f
  float* V = QK + (size_t)T_LEN * 4096;            //  4,194,304 f
  float* U = V + (size_t)T_LEN * 4096;             //  4,194,304 f
  float* Wb_f = U + (size_t)NCHUNK * 32 * 64 * 128;//  2,097,152 f (bf16 x 4.19M)
  float* KT_f = Wb_f + 2097152;                    //  2,097,152 f
  float* Qg_f = KT_f + 2097152;                    //  2,097,152 f
  float* Bb_f = Qg_f + 2097152;                    //  1,048,576 f (bf16 x 2.10M)
  float* gg = Bb_f + 1048576;                      //     32,768 f
  float* bet = gg + 32768;                         //     32,768 f
  float* gend = bet + 32768;                       //        512 f

  __hip_bfloat16* Wb = (__hip_bfloat16*)Wb_f;
  __hip_bfloat16* KTb = (__hip_bfloat16*)KT_f;
  __hip_bfloat16* Qgb = (__hip_bfloat16*)Qg_f;
  __hip_bfloat16* Bb = (__hip_bfloat16*)Bb_f;
  // lifetime aliases:
  __hip_bfloat16* Wqkvz_t = (__hip_bfloat16*)V;    // spans V+U+Wb+KT (dead after 1st gemm)
  __hip_bfloat16* Xb = (__hip_bfloat16*)Qg_f;      // dead after 1st gemm
  __hip_bfloat16* Gb = (__hip_bfloat16*)Bb_f;      // Bb dead after phaseB
  __hip_bfloat16* Wout_t = (__hip_bfloat16*)qkvz;  // qkvz dead after gate_norm
  float* O = V;                                    // V dead after phase1

  cast_bf16<<<dim3(T_LEN * 2048 / 4 / 256), 256, 0, stream>>>(X, Xb, T_LEN * 2048);
  transpose_cast<<<dim3(NQKVZ / 32, 2048 / 32), 256, 0, stream>>>(W_qkvz, Wqkvz_t, 2048, NQKVZ);
  gemm_bf16<<<dim3(NQKVZ / 128, T_LEN / 128), 256, 0, stream>>>(Xb, Wqkvz_t, qkvz, T_LEN, NQKVZ, 2048);
  gemm_f32<<<dim3(1, T_LEN / 64), 256, 0, stream>>>(X, W_ba, ba, T_LEN, 64, 2048);
  conv_silu<<<dim3(CDIM / 256, T_LEN), 256, 0, stream>>>(qkvz, conv_w, QK, V);
  l2norm_qk<<<dim3(HK_N, T_LEN), 64, 0, stream>>>(QK);
  compute_gb<<<dim3(T_LEN * 32 / 256), 256, 0, stream>>>(ba, dt_bias, A_log, gg, bet);
  phase1<<<dim3(HV_N, NCHUNK), 256, 0, stream>>>(QK, V, gg, bet, U, Wb, KTb, Qgb, Bb, gend);
  phaseB<<<dim3(HV_N, 4), 128, 0, stream>>>(U, Wb, KTb, Qgb, Bb, gend, O);
  gate_norm<<<dim3(HV_N, T_LEN), 64, 0, stream>>>(O, qkvz, norm_w, Gb);
  transpose_cast<<<dim3(2048 / 32, 4096 / 32), 256, 0, stream>>>(W_out, Wout_t, 4096, 2048);
  gemm_bf16<<<dim3(2048 / 128, T_LEN / 128), 256, 0, stream>>>(Gb, Wout_t, out, T_LEN, 2048, 4096);
}

// Round 6
// 376.945 us; speedup vs baseline: 11.7423x; 1.2404x over previous
//
#include <hip/hip_runtime.h>
#include <hip/hip_bf16.h>
#include <math.h>

// Qwen3Next GatedDeltaNet — round 5: ba GEMM (was 127 µs at 0.7% occupancy,
// grid=16 blocks) replaced by split-K ba_gemm (256 blocks) + reduction fused
// into compute_gb. Everything else unchanged from round 4.

#define T_LEN 1024
#define HK_N 16
#define HV_N 32
#define NQKVZ 12288
#define CDIM 8192
#define CHUNK 64
#define NCHUNK 16

typedef __bf16 bf16x8 __attribute__((ext_vector_type(8)));
typedef float f32x4 __attribute__((ext_vector_type(4)));

__device__ __forceinline__ ushort4 pack4(const f32x4 v) {
  ushort4 o;
  o.x = __bfloat16_as_ushort(__float2bfloat16(v[0]));
  o.y = __bfloat16_as_ushort(__float2bfloat16(v[1]));
  o.z = __bfloat16_as_ushort(__float2bfloat16(v[2]));
  o.w = __bfloat16_as_ushort(__float2bfloat16(v[3]));
  return o;
}

// ---------------- bf16 MFMA GEMM: C[M,N] = A[M,K] @ B[N,K]^T -----------------
__global__ __launch_bounds__(256) void gemm_bf16(const __hip_bfloat16* __restrict__ A,
                                                 const __hip_bfloat16* __restrict__ B,
                                                 float* __restrict__ C,
                                                 int M, int N, int K) {
  __shared__ __align__(16) __hip_bfloat16 As[128 * 32];
  __shared__ __align__(16) __hip_bfloat16 Bs[128 * 32];
  const int tid = threadIdx.x;
  const int wid = tid >> 6, lane = tid & 63;
  const int wr = wid >> 1, wc = wid & 1;
  const int m0 = blockIdx.y * 128, n0 = blockIdx.x * 128;
  const int lrow = lane & 15, lk = lane >> 4;
  f32x4 acc[4][4] = {};

  for (int k0 = 0; k0 < K; k0 += 32) {
#pragma unroll
    for (int p = 0; p < 2; ++p) {
      const int c = p * 256 + wid * 64 + lane;
      const __hip_bfloat16* ga = A + (size_t)(m0 + (c >> 2)) * K + k0 + (c & 3) * 8;
      const __hip_bfloat16* gb = B + (size_t)(n0 + (c >> 2)) * K + k0 + (c & 3) * 8;
      __builtin_amdgcn_global_load_lds(
          (const __attribute__((address_space(1))) void*)ga,
          (__attribute__((address_space(3))) void*)(As + p * 2048 + wid * 512), 16, 0, 0);
      __builtin_amdgcn_global_load_lds(
          (const __attribute__((address_space(1))) void*)gb,
          (__attribute__((address_space(3))) void*)(Bs + p * 2048 + wid * 512), 16, 0, 0);
    }
    __syncthreads();
    bf16x8 af[4], bfv[4];
#pragma unroll
    for (int m = 0; m < 4; ++m)
      af[m] = *reinterpret_cast<const bf16x8*>(As + (wr * 64 + m * 16 + lrow) * 32 + lk * 8);
#pragma unroll
    for (int n = 0; n < 4; ++n)
      bfv[n] = *reinterpret_cast<const bf16x8*>(Bs + (wc * 64 + n * 16 + lrow) * 32 + lk * 8);
#pragma unroll
    for (int m = 0; m < 4; ++m)
#pragma unroll
      for (int n = 0; n < 4; ++n)
        acc[m][n] = __builtin_amdgcn_mfma_f32_16x16x32_bf16(af[m], bfv[n], acc[m][n], 0, 0, 0);
    __syncthreads();
  }
#pragma unroll
  for (int m = 0; m < 4; ++m)
#pragma unroll
    for (int n = 0; n < 4; ++n)
#pragma unroll
      for (int r = 0; r < 4; ++r)
        C[(size_t)(m0 + wr * 64 + m * 16 + lk * 4 + r) * N + n0 + wc * 64 + n * 16 + lrow] =
            acc[m][n][r];
}

// ---------------- fp32 -> bf16 elementwise cast ------------------------------
__global__ void cast_bf16(const float* __restrict__ src,
                          __hip_bfloat16* __restrict__ dst, int n) {
  const int i = (blockIdx.x * 256 + threadIdx.x) * 4;
  if (i < n) {
    const float4 v = *reinterpret_cast<const float4*>(src + i);
    ushort4 o;
    o.x = __bfloat16_as_ushort(__float2bfloat16(v.x));
    o.y = __bfloat16_as_ushort(__float2bfloat16(v.y));
    o.z = __bfloat16_as_ushort(__float2bfloat16(v.z));
    o.w = __bfloat16_as_ushort(__float2bfloat16(v.w));
    *reinterpret_cast<ushort4*>((void*)(dst + i)) = o;
  }
}

// ---------------- fp32 [K,N] -> bf16 [N,K] tiled transpose-cast --------------
__global__ __launch_bounds__(256) void transpose_cast(const float* __restrict__ src,
                                                      __hip_bfloat16* __restrict__ dst,
                                                      int K, int N) {
  __shared__ float tl[32][33];
  const int n0 = blockIdx.x * 32, k0 = blockIdx.y * 32;
  const int tx = threadIdx.x & 31, ty = threadIdx.x >> 5;
#pragma unroll
  for (int i = 0; i < 4; ++i)
    tl[ty + 8 * i][tx] = src[(size_t)(k0 + ty + 8 * i) * N + n0 + tx];
  __syncthreads();
#pragma unroll
  for (int i = 0; i < 4; ++i)
    dst[(size_t)(n0 + ty + 8 * i) * K + k0 + tx] = __float2bfloat16(tl[tx][ty + 8 * i]);
}

// --------- split-K ba GEMM: X[1024,2048] @ Wba[2048,64] -> P[4][1024][64] ----
// grid (64 t-tiles, 4 k-slices) x 256 thr. Thread = (4 rows, 1 col).
__global__ __launch_bounds__(256) void ba_gemm(const float* __restrict__ X,
                                               const float* __restrict__ Wba,
                                               float* __restrict__ P) {
  __shared__ __align__(16) float Xs[16][512];
  const int tt = blockIdx.x, ks = blockIdx.y;
  const int tid = threadIdx.x;
  const int c = tid & 63, r4 = tid >> 6;
  const float* xsrc = X + (size_t)(tt * 16) * 2048 + ks * 512;
#pragma unroll
  for (int u = 0; u < 8; ++u) {
    const int flat = (u * 256 + tid) * 4;
    const int r = flat >> 9, k = flat & 511;
    *reinterpret_cast<float4*>(&Xs[r][k]) =
        *reinterpret_cast<const float4*>(&xsrc[(size_t)r * 2048 + k]);
  }
  __syncthreads();
  float acc[4] = {};
  const float* wp = Wba + (size_t)(ks * 512) * 64 + c;
  for (int k = 0; k < 512; k += 8) {
    float w[8];
#pragma unroll
    for (int u = 0; u < 8; ++u) w[u] = wp[(size_t)(k + u) * 64];
#pragma unroll
    for (int u = 0; u < 8; ++u)
#pragma unroll
      for (int i = 0; i < 4; ++i)
        acc[i] = fmaf(Xs[r4 * 4 + i][k + u], w[u], acc[i]);
  }
  float* pp = P + ((size_t)ks * 1024 + tt * 16 + r4 * 4) * 64 + c;
#pragma unroll
  for (int i = 0; i < 4; ++i) pp[(size_t)i * 64] = acc[i];
}

// ------------- causal depthwise conv (K=4) + silu, with qkvz gather ----------
__global__ void conv_silu(const float* __restrict__ qkvz,
                          const float* __restrict__ conv_w,
                          float* __restrict__ QK, float* __restrict__ V) {
  const int c = blockIdx.x * 256 + threadIdx.x;
  const int t = blockIdx.y;
  int col;
  if (c < 2048) {
    col = (c >> 7) * 768 + (c & 127);
  } else if (c < 4096) {
    const int c2 = c - 2048;
    col = (c2 >> 7) * 768 + 128 + (c2 & 127);
  } else {
    const int c2 = c - 4096;
    const int vh = c2 >> 7;
    col = (vh >> 1) * 768 + 256 + (vh & 1) * 128 + (c2 & 127);
  }
  float acc = 0.f;
#pragma unroll
  for (int s = 0; s < 4; ++s) {
    const int tt = t - 3 + s;
    if (tt >= 0) acc = fmaf(qkvz[(size_t)tt * NQKVZ + col], conv_w[c * 4 + s], acc);
  }
  const float y = acc / (1.f + expf(-acc));  // silu
  if (c < 4096) QK[(size_t)t * 4096 + c] = y;
  else          V[(size_t)t * 4096 + (c - 4096)] = y;
}

// ---------------- l2norm over DK for q and k (per t, per k-head) -------------
__global__ void l2norm_qk(float* __restrict__ QK) {
  const int h = blockIdx.x, t = blockIdx.y, l = threadIdx.x;  // 64 threads
  const size_t qb = (size_t)t * 4096 + h * 128;
  const size_t kb = qb + 2048;
  float q0 = QK[qb + l], q1 = QK[qb + l + 64];
  float k0 = QK[kb + l], k1 = QK[kb + l + 64];
  float sq = q0 * q0 + q1 * q1;
  float sk = k0 * k0 + k1 * k1;
#pragma unroll
  for (int off = 32; off; off >>= 1) {
    sq += __shfl_xor(sq, off);
    sk += __shfl_xor(sk, off);
  }
  const float rq = rsqrtf(sq + 1e-6f) * 0.08838834764831845f;  // * DK^-0.5
  const float rk = rsqrtf(sk + 1e-6f);
  QK[qb + l] = q0 * rq; QK[qb + l + 64] = q1 * rq;
  QK[kb + l] = k0 * rk; QK[kb + l + 64] = k1 * rk;
}

// ------ g/beta from split-K partials: sum 4 slices, then softplus/sigmoid ----
__global__ void compute_gb(const float* __restrict__ P,
                           const float* __restrict__ dt_bias,
                           const float* __restrict__ A_log,
                           float* __restrict__ gg, float* __restrict__ bet) {
  const int idx = blockIdx.x * 256 + threadIdx.x;  // t*32 + vh
  const int t = idx >> 5, vh = idx & 31;
  const int cb = (vh >> 1) * 4 + (vh & 1);
  float b = 0.f, a = 0.f;
#pragma unroll
  for (int s = 0; s < 4; ++s) {
    b += P[((size_t)s * 1024 + t) * 64 + cb];
    a += P[((size_t)s * 1024 + t) * 64 + cb + 2];
  }
  const float x = a + dt_bias[vh];
  const float sp = (x > 20.f) ? x : log1pf(expf(x));
  gg[idx] = -expf(A_log[vh]) * sp;
  bet[idx] = 1.f / (1.f + expf(-b));
}

// ---------------- phase 1: per (chunk, v-head) intra-chunk precompute --------
__global__ __launch_bounds__(256, 2) void phase1(
    const float* __restrict__ QK, const float* __restrict__ V,
    const float* __restrict__ g, const float* __restrict__ bet,
    float* __restrict__ U, __hip_bfloat16* __restrict__ Wb,
    __hip_bfloat16* __restrict__ KTb, __hip_bfloat16* __restrict__ Qgb,
    __hip_bfloat16* __restrict__ Bb, float* __restrict__ gend) {
  const int vh = blockIdx.x, ch = blockIdx.y, kh = vh >> 1;
  const int tid = threadIdx.x;
  const int t0 = ch * CHUNK;
  __shared__ __align__(16) float Kl[64][132];
  __shared__ float Al[64][65];
  __shared__ float bs[64], gams[64], bets[64], lams[64];

  const int row = tid >> 2;
  const size_t hb = (size_t)ch * 32 + vh;
  {
    const int cc = (tid & 3) * 32;
    const float* src = &QK[(size_t)(t0 + row) * 4096 + 2048 + kh * 128 + cc];
#pragma unroll
    for (int u = 0; u < 32; u += 4)
      *reinterpret_cast<float4*>(&Kl[row][cc + u]) =
          *reinterpret_cast<const float4*>(src + u);
  }
  if (tid < 64) {
    float b = g[(size_t)(t0 + tid) * 32 + vh];
#pragma unroll
    for (int off = 1; off < 64; off <<= 1) {
      const float o = __shfl_up(b, off);
      if (tid >= off) b += o;
    }
    const float b63 = __shfl(b, 63);
    const float ga = expf(b);
    bs[tid] = b;
    gams[tid] = ga;
    lams[tid] = expf(b63 - b);
    bets[tid] = bet[(size_t)(t0 + tid) * 32 + vh];
    if (tid == 63) gend[ch * 32 + vh] = ga;
  }
  __syncthreads();
  {
    const int i = tid & 63;
    const float li = lams[i];
    __hip_bfloat16* kt = &KTb[hb * 128 * 64];
    const int dbase = (tid >> 6) * 32;
#pragma unroll
    for (int dd = 0; dd < 32; ++dd) {
      const int d = dbase + dd;
      kt[(size_t)d * 64 + (i ^ ((d & 7) << 3))] = __float2bfloat16(li * Kl[i][d]);
    }
  }
  {
    const int j0 = (tid & 3) * 16;
    const float* qrow = &QK[(size_t)(t0 + row) * 4096 + kh * 128];
    const float gai = gams[row];
    __hip_bfloat16* qg = &Qgb[(hb * 64 + row) * 128];
    float accA[16], accB[16];
#pragma unroll
    for (int jj = 0; jj < 16; ++jj) { accA[jj] = 0.f; accB[jj] = 0.f; }
    for (int d = 0; d < 128; d += 4) {
      const float4 qi = *reinterpret_cast<const float4*>(qrow + d);
      const float4 ki = *reinterpret_cast<const float4*>(&Kl[row][d]);
      if ((d >> 5) == (tid & 3)) {
        ushort4 qq;
        qq.x = __bfloat16_as_ushort(__float2bfloat16(gai * qi.x));
        qq.y = __bfloat16_as_ushort(__float2bfloat16(gai * qi.y));
        qq.z = __bfloat16_as_ushort(__float2bfloat16(gai * qi.z));
        qq.w = __bfloat16_as_ushort(__float2bfloat16(gai * qi.w));
        *reinterpret_cast<ushort4*>(&qg[d ^ ((row & 7) << 3)]) = qq;
      }
#pragma unroll
      for (int jj = 0; jj < 16; ++jj) {
        const float4 kj = *reinterpret_cast<const float4*>(&Kl[j0 + jj][d]);
        accA[jj] += ki.x * kj.x + ki.y * kj.y + ki.z * kj.z + ki.w * kj.w;
        accB[jj] += qi.x * kj.x + qi.y * kj.y + qi.z * kj.z + qi.w * kj.w;
      }
    }
    const float bi = bets[row], bvi = bs[row];
    __hip_bfloat16* Bout = &Bb[(hb * 64 + row) * 64];
#pragma unroll
    for (int jj = 0; jj < 16; ++jj) {
      const int j = j0 + jj;
      const float dec = expf(bvi - bs[j]);
      Al[row][j] = (j < row) ? bi * dec * accA[jj] : 0.f;
      Bout[j ^ ((row & 7) << 3)] =
          __float2bfloat16((j <= row) ? dec * accB[jj] : 0.f);
    }
  }
  __syncthreads();
  // register-resident right-looking solve of (I+A) x = rhs, column tid.
  {
    const int cc = tid;
    float x[64];
    const bool isV = cc < 128;
    const float* src = isV ? &V[(size_t)t0 * 4096 + vh * 128 + cc]
                           : &QK[(size_t)t0 * 4096 + 2048 + kh * 128 + (cc - 128)];
#pragma unroll
    for (int i = 0; i < 64; ++i) {
      const float sc = isV ? bets[i] : bets[i] * gams[i];
      x[i] = sc * src[(size_t)i * 4096];
    }
#pragma unroll
    for (int j = 0; j < 63; ++j)
#pragma unroll
      for (int i = j + 1; i < 64; ++i)
        x[i] = fmaf(-Al[i][j], x[j], x[i]);
    if (isV) {
      float* dst = &U[hb * 64 * 128 + cc];
#pragma unroll
      for (int i = 0; i < 64; ++i) dst[(size_t)i * 128] = x[i];
    } else {
      const int d = cc - 128;
      __hip_bfloat16* dst = &Wb[hb * 64 * 128];
#pragma unroll
      for (int i = 0; i < 64; ++i)
        dst[(size_t)i * 128 + (d ^ ((i & 7) << 3))] = __float2bfloat16(-x[i]);
    }
  }
}

// ---------------- phaseB: serial MFMA state propagation ----------------------
__global__ __launch_bounds__(128) void phaseB(
    const float* __restrict__ Ug, const __hip_bfloat16* __restrict__ Wb,
    const __hip_bfloat16* __restrict__ KTb, const __hip_bfloat16* __restrict__ Qgb,
    const __hip_bfloat16* __restrict__ Bb, const float* __restrict__ gendg,
    float* __restrict__ Og) {
  const int vh = blockIdx.x, slice = blockIdx.y;
  const int tid = threadIdx.x, lane = tid & 63, w = tid >> 6;
  const int l15 = lane & 15, l4 = lane >> 4;
  const int cg = slice * 32 + w * 16;
  const int swz = (l15 & 7) << 3;

  __shared__ __hip_bfloat16 Wl[2][8192];
  __shared__ __hip_bfloat16 KTl[2][8192];
  __shared__ __hip_bfloat16 Qgl[2][8192];
  __shared__ __hip_bfloat16 Bl[2][4096];
  __shared__ __hip_bfloat16 Sop[2][2048];
  __shared__ __hip_bfloat16 dLs[2][1024];

  f32x4 accS[8] = {};
  for (int x = lane; x < 1024; x += 64) reinterpret_cast<uint*>(Sop[w])[x] = 0;

  float ubuf[4][4];
#define STAGE(b_, c_) do {                                                      \
    const size_t hb_ = ((size_t)(c_) * 32 + vh);                                \
    _Pragma("unroll") for (int it = 0; it < 8; ++it) {                          \
      __builtin_amdgcn_global_load_lds(                                         \
          (const __attribute__((address_space(1))) void*)(Wb + hb_ * 8192 + it * 1024 + tid * 8), \
          (__attribute__((address_space(3))) void*)(&Wl[b_][it * 1024 + tid * 8]), 16, 0, 0); \
      __builtin_amdgcn_global_load_lds(                                         \
          (const __attribute__((address_space(1))) void*)(KTb + hb_ * 8192 + it * 1024 + tid * 8), \
          (__attribute__((address_space(3))) void*)(&KTl[b_][it * 1024 + tid * 8]), 16, 0, 0); \
      __builtin_amdgcn_global_load_lds(                                         \
          (const __attribute__((address_space(1))) void*)(Qgb + hb_ * 8192 + it * 1024 + tid * 8), \
          (__attribute__((address_space(3))) void*)(&Qgl[b_][it * 1024 + tid * 8]), 16, 0, 0); \
      if (it < 4)                                                               \
        __builtin_amdgcn_global_load_lds(                                       \
            (const __attribute__((address_space(1))) void*)(Bb + hb_ * 4096 + it * 1024 + tid * 8), \
            (__attribute__((address_space(3))) void*)(&Bl[b_][it * 1024 + tid * 8]), 16, 0, 0); \
    }                                                                           \
  } while (0)
#define UPREF(c_) do {                                                          \
    const float* up_ = Ug + ((size_t)(c_) * 32 + vh) * 64 * 128 + cg + l15;     \
    _Pragma("unroll") for (int m_ = 0; m_ < 4; ++m_)                            \
      _Pragma("unroll") for (int r_ = 0; r_ < 4; ++r_)                          \
        ubuf[m_][r_] = up_[(size_t)(m_ * 16 + l4 * 4 + r_) * 128];              \
  } while (0)

  STAGE(0, 0);
  UPREF(0);
  __syncthreads();
  int buf = 0;
  for (int ch = 0; ch < NCHUNK; ++ch) {
    if (ch + 1 < NCHUNK) STAGE(buf ^ 1, ch + 1);
    f32x4 acc_d[4];
#pragma unroll
    for (int m = 0; m < 4; ++m) {
      f32x4 t;
      t[0] = ubuf[m][0]; t[1] = ubuf[m][1]; t[2] = ubuf[m][2]; t[3] = ubuf[m][3];
      acc_d[m] = t;
    }
    if (ch + 1 < NCHUNK) UPREF(ch + 1);
    // op1: delta = U + (-W) @ S
#pragma unroll
    for (int t = 0; t < 4; ++t) {
      const bf16x8 bS = *reinterpret_cast<const bf16x8*>(
          &Sop[w][l15 * 128 + ((t * 32 + l4 * 8) ^ swz)]);
#pragma unroll
      for (int m = 0; m < 4; ++m) {
        const bf16x8 aW = *reinterpret_cast<const bf16x8*>(
            &Wl[buf][(m * 16 + l15) * 128 + ((t * 32 + l4 * 8) ^ swz)]);
        acc_d[m] = __builtin_amdgcn_mfma_f32_16x16x32_bf16(aW, bS, acc_d[m], 0, 0, 0);
      }
    }
#pragma unroll
    for (int m = 0; m < 4; ++m)
      *reinterpret_cast<ushort4*>(&dLs[w][l15 * 64 + ((m * 16 + l4 * 4) ^ swz)]) =
          pack4(acc_d[m]);
    // opO: o = γq @ S + B @ δ
    f32x4 acc_o[4] = {};
#pragma unroll
    for (int t = 0; t < 4; ++t) {
      const bf16x8 bS = *reinterpret_cast<const bf16x8*>(
          &Sop[w][l15 * 128 + ((t * 32 + l4 * 8) ^ swz)]);
#pragma unroll
      for (int m = 0; m < 4; ++m) {
        const bf16x8 aQ = *reinterpret_cast<const bf16x8*>(
            &Qgl[buf][(m * 16 + l15) * 128 + ((t * 32 + l4 * 8) ^ swz)]);
        acc_o[m] = __builtin_amdgcn_mfma_f32_16x16x32_bf16(aQ, bS, acc_o[m], 0, 0, 0);
      }
    }
#pragma unroll
    for (int t2 = 0; t2 < 2; ++t2) {
      const bf16x8 bD = *reinterpret_cast<const bf16x8*>(
          &dLs[w][l15 * 64 + ((t2 * 32 + l4 * 8) ^ swz)]);
#pragma unroll
      for (int m = 0; m < 4; ++m) {
        const bf16x8 aB = *reinterpret_cast<const bf16x8*>(
            &Bl[buf][(m * 16 + l15) * 64 + ((t2 * 32 + l4 * 8) ^ swz)]);
        acc_o[m] = __builtin_amdgcn_mfma_f32_16x16x32_bf16(aB, bD, acc_o[m], 0, 0, 0);
      }
    }
    float* ob = Og + (size_t)(ch * 64) * 4096 + (size_t)vh * 128 + cg + l15;
#pragma unroll
    for (int m = 0; m < 4; ++m)
#pragma unroll
      for (int r = 0; r < 4; ++r)
        ob[(size_t)(m * 16 + l4 * 4 + r) * 4096] = acc_o[m][r];
    // op3: S = ge*S + Kᵀλ @ δ
    const float ge = gendg[ch * 32 + vh];
#pragma unroll
    for (int f = 0; f < 8; ++f) {
      accS[f][0] *= ge; accS[f][1] *= ge; accS[f][2] *= ge; accS[f][3] *= ge;
    }
#pragma unroll
    for (int t2 = 0; t2 < 2; ++t2) {
      const bf16x8 bD = *reinterpret_cast<const bf16x8*>(
          &dLs[w][l15 * 64 + ((t2 * 32 + l4 * 8) ^ swz)]);
#pragma unroll
      for (int f = 0; f < 8; ++f) {
        const bf16x8 aK = *reinterpret_cast<const bf16x8*>(
            &KTl[buf][(f * 16 + l15) * 64 + ((t2 * 32 + l4 * 8) ^ swz)]);
        accS[f] = __builtin_amdgcn_mfma_f32_16x16x32_bf16(aK, bD, accS[f], 0, 0, 0);
      }
    }
#pragma unroll
    for (int f = 0; f < 8; ++f)
      *reinterpret_cast<ushort4*>(&Sop[w][l15 * 128 + ((f * 16 + l4 * 4) ^ swz)]) =
          pack4(accS[f]);
    __syncthreads();
    buf ^= 1;
  }
#undef STAGE
#undef UPREF
}

// ------- gated = rmsnorm(o * silu(z)) * norm_w, emitted as bf16 --------------
__global__ void gate_norm(const float* __restrict__ O,
                          const float* __restrict__ qkvz,
                          const float* __restrict__ norm_w,
                          __hip_bfloat16* __restrict__ G) {
  const int vh = blockIdx.x, t = blockIdx.y, l = threadIdx.x;  // 64 threads
  const size_t ob = (size_t)t * 4096 + vh * 128;
  const size_t zb = (size_t)t * NQKVZ + (vh >> 1) * 768 + 512 + (vh & 1) * 128;
  const float o0 = O[ob + l], o1 = O[ob + l + 64];
  const float z0 = qkvz[zb + l], z1 = qkvz[zb + l + 64];
  const float g0 = o0 * z0 / (1.f + expf(-z0));
  const float g1 = o1 * z1 / (1.f + expf(-z1));
  float ss = g0 * g0 + g1 * g1;
#pragma unroll
  for (int off = 32; off; off >>= 1) ss += __shfl_xor(ss, off);
  const float rr = rsqrtf(ss * (1.f / 128.f) + 1e-6f);
  G[ob + l] = __float2bfloat16(g0 * rr * norm_w[l]);
  G[ob + l + 64] = __float2bfloat16(g1 * rr * norm_w[l + 64]);
}

extern "C" void kernel_launch(void* const* d_in, const int* in_sizes, int n_in,
                              void* d_out, int out_size, void* d_ws, size_t ws_size,
                              hipStream_t stream) {
  const float* X = (const float*)d_in[0];
  const float* W_qkvz = (const float*)d_in[1];
  const float* W_ba = (const float*)d_in[2];
  const float* conv_w = (const float*)d_in[3];
  const float* dt_bias = (const float*)d_in[4];
  const float* A_log = (const float*)d_in[5];
  const float* norm_w = (const float*)d_in[6];
  const float* W_out = (const float*)d_in[7];
  float* out = (float*)d_out;

  float* ws = (float*)d_ws;
  float* qkvz = ws;                                // 12,582,912 f
  float* P = qkvz + (size_t)T_LEN * NQKVZ;         //    262,144 f (ba partials)
  float* QK = P + 262144;                          //  4,194,304 f
  float* V = QK + (size_t)T_LEN * 4096;            //  4,194,304 f
  float* U = V + (size_t)T_LEN * 4096;             //  4,194,304 f
  float* Wb_f = U + (size_t)NCHUNK * 32 * 64 * 128;//  2,097,152 f (bf16 x 4.19M)
  float* KT_f = Wb_f + 2097152;                    //  2,097,152 f
  float* Qg_f = KT_f + 2097152;                    //  2,097,152 f
  float* Bb_f = Qg_f + 2097152;                    //  1,048,576 f (bf16 x 2.10M)
  float* gg = Bb_f + 1048576;                      //     32,768 f
  float* bet = gg + 32768;                         //     32,768 f
  float* gend = bet + 32768;                       //        512 f

  __hip_bfloat16* Wb = (__hip_bfloat16*)Wb_f;
  __hip_bfloat16* KTb = (__hip_bfloat16*)KT_f;
  __hip_bfloat16* Qgb = (__hip_bfloat16*)Qg_f;
  __hip_bfloat16* Bb = (__hip_bfloat16*)Bb_f;
  // lifetime aliases:
  __hip_bfloat16* Wqkvz_t = (__hip_bfloat16*)V;    // spans V+U+Wb+KT (dead after 1st gemm)
  __hip_bfloat16* Xb = (__hip_bfloat16*)Qg_f;      // dead after 1st gemm
  __hip_bfloat16* Gb = (__hip_bfloat16*)Bb_f;      // Bb dead after phaseB
  __hip_bfloat16* Wout_t = (__hip_bfloat16*)qkvz;  // qkvz dead after gate_norm
  float* O = V;                                    // V dead after phase1

  cast_bf16<<<dim3(T_LEN * 2048 / 4 / 256), 256, 0, stream>>>(X, Xb, T_LEN * 2048);
  transpose_cast<<<dim3(NQKVZ / 32, 2048 / 32), 256, 0, stream>>>(W_qkvz, Wqkvz_t, 2048, NQKVZ);
  gemm_bf16<<<dim3(NQKVZ / 128, T_LEN / 128), 256, 0, stream>>>(Xb, Wqkvz_t, qkvz, T_LEN, NQKVZ, 2048);
  ba_gemm<<<dim3(64, 4), 256, 0, stream>>>(X, W_ba, P);
  conv_silu<<<dim3(CDIM / 256, T_LEN), 256, 0, stream>>>(qkvz, conv_w, QK, V);
  l2norm_qk<<<dim3(HK_N, T_LEN), 64, 0, stream>>>(QK);
  compute_gb<<<dim3(T_LEN * 32 / 256), 256, 0, stream>>>(P, dt_bias, A_log, gg, bet);
  phase1<<<dim3(HV_N, NCHUNK), 256, 0, stream>>>(QK, V, gg, bet, U, Wb, KTb, Qgb, Bb, gend);
  phaseB<<<dim3(HV_N, 4), 128, 0, stream>>>(U, Wb, KTb, Qgb, Bb, gend, O);
  gate_norm<<<dim3(HV_N, T_LEN), 64, 0, stream>>>(O, qkvz, norm_w, Gb);
  transpose_cast<<<dim3(2048 / 32, 4096 / 32), 256, 0, stream>>>(W_out, Wout_t, 4096, 2048);
  gemm_bf16<<<dim3(2048 / 128, T_LEN / 128), 256, 0, stream>>>(Gb, Wout_t, out, T_LEN, 2048, 4096);
}

// Round 7
// 343.468 us; speedup vs baseline: 12.8868x; 1.0975x over previous
//
#include <hip/hip_runtime.h>
#include <hip/hip_bf16.h>
#include <math.h>

// Qwen3Next GatedDeltaNet — round 6: (1) gemm_bf16 BK 32->64 (halves the
// vmcnt(0)+barrier drains that dominate the latency-bound profile),
// (2) out-GEMM split-K2 via grid.z + add2 (128->256 blocks),
// (3) conv_silu rolling-window rewrite (4x -> 1x input reads).

#define T_LEN 1024
#define HK_N 16
#define HV_N 32
#define NQKVZ 12288
#define CDIM 8192
#define CHUNK 64
#define NCHUNK 16

typedef __bf16 bf16x8 __attribute__((ext_vector_type(8)));
typedef float f32x4 __attribute__((ext_vector_type(4)));

__device__ __forceinline__ ushort4 pack4(const f32x4 v) {
  ushort4 o;
  o.x = __bfloat16_as_ushort(__float2bfloat16(v[0]));
  o.y = __bfloat16_as_ushort(__float2bfloat16(v[1]));
  o.z = __bfloat16_as_ushort(__float2bfloat16(v[2]));
  o.w = __bfloat16_as_ushort(__float2bfloat16(v[3]));
  return o;
}

// ------- bf16 MFMA GEMM: C[M,N] (+= z-partials) = A[M,ldk] @ B[N,ldk]^T ------
// BK=64. blockIdx.z selects a K-chunk of length Klen at offset z*Klen; the
// z-th partial is written to C + z*M*N. 256 thr = 4 waves (2x2 of 64x64).
__global__ __launch_bounds__(256) void gemm_bf16(const __hip_bfloat16* __restrict__ A,
                                                 const __hip_bfloat16* __restrict__ B,
                                                 float* __restrict__ C,
                                                 int M, int N, int Klen, int ldk) {
  __shared__ __align__(16) __hip_bfloat16 As[128 * 64];
  __shared__ __align__(16) __hip_bfloat16 Bs[128 * 64];
  const int tid = threadIdx.x;
  const int wid = tid >> 6, lane = tid & 63;
  const int wr = wid >> 1, wc = wid & 1;
  const int m0 = blockIdx.y * 128, n0 = blockIdx.x * 128;
  const size_t kbase = (size_t)blockIdx.z * Klen;
  float* Cz = C + (size_t)blockIdx.z * M * N;
  const int lrow = lane & 15, lk = lane >> 4;
  f32x4 acc[4][4] = {};

  for (int k0 = 0; k0 < Klen; k0 += 64) {
#pragma unroll
    for (int it = 0; it < 4; ++it) {
      const int c = it * 256 + tid;  // chunk: row = c>>3, 8 elems at (c&7)*8
      const int row = c >> 3, col8 = (c & 7) * 8;
      const __hip_bfloat16* ga = A + (size_t)(m0 + row) * ldk + kbase + k0 + col8;
      const __hip_bfloat16* gb = B + (size_t)(n0 + row) * ldk + kbase + k0 + col8;
      __builtin_amdgcn_global_load_lds(
          (const __attribute__((address_space(1))) void*)ga,
          (__attribute__((address_space(3))) void*)(As + it * 2048 + tid * 8), 16, 0, 0);
      __builtin_amdgcn_global_load_lds(
          (const __attribute__((address_space(1))) void*)gb,
          (__attribute__((address_space(3))) void*)(Bs + it * 2048 + tid * 8), 16, 0, 0);
    }
    __syncthreads();
#pragma unroll
    for (int kk = 0; kk < 2; ++kk) {
      bf16x8 af[4], bfv[4];
#pragma unroll
      for (int m = 0; m < 4; ++m)
        af[m] = *reinterpret_cast<const bf16x8*>(
            As + (wr * 64 + m * 16 + lrow) * 64 + kk * 32 + lk * 8);
#pragma unroll
      for (int n = 0; n < 4; ++n)
        bfv[n] = *reinterpret_cast<const bf16x8*>(
            Bs + (wc * 64 + n * 16 + lrow) * 64 + kk * 32 + lk * 8);
#pragma unroll
      for (int m = 0; m < 4; ++m)
#pragma unroll
        for (int n = 0; n < 4; ++n)
          acc[m][n] = __builtin_amdgcn_mfma_f32_16x16x32_bf16(af[m], bfv[n], acc[m][n], 0, 0, 0);
    }
    __syncthreads();
  }
#pragma unroll
  for (int m = 0; m < 4; ++m)
#pragma unroll
    for (int n = 0; n < 4; ++n)
#pragma unroll
      for (int r = 0; r < 4; ++r)
        Cz[(size_t)(m0 + wr * 64 + m * 16 + lk * 4 + r) * N + n0 + wc * 64 + n * 16 + lrow] =
            acc[m][n][r];
}

// ---------------- out = P0 + P1 (split-K reduction) --------------------------
__global__ void add2(const float* __restrict__ P, float* __restrict__ out, int n) {
  const int i = (blockIdx.x * 256 + threadIdx.x) * 4;
  if (i < n) {
    const float4 a = *reinterpret_cast<const float4*>(P + i);
    const float4 b = *reinterpret_cast<const float4*>(P + n + i);
    *reinterpret_cast<float4*>(out + i) =
        make_float4(a.x + b.x, a.y + b.y, a.z + b.z, a.w + b.w);
  }
}

// ---------------- fp32 -> bf16 elementwise cast ------------------------------
__global__ void cast_bf16(const float* __restrict__ src,
                          __hip_bfloat16* __restrict__ dst, int n) {
  const int i = (blockIdx.x * 256 + threadIdx.x) * 4;
  if (i < n) {
    const float4 v = *reinterpret_cast<const float4*>(src + i);
    ushort4 o;
    o.x = __bfloat16_as_ushort(__float2bfloat16(v.x));
    o.y = __bfloat16_as_ushort(__float2bfloat16(v.y));
    o.z = __bfloat16_as_ushort(__float2bfloat16(v.z));
    o.w = __bfloat16_as_ushort(__float2bfloat16(v.w));
    *reinterpret_cast<ushort4*>((void*)(dst + i)) = o;
  }
}

// ---------------- fp32 [K,N] -> bf16 [N,K] tiled transpose-cast --------------
__global__ __launch_bounds__(256) void transpose_cast(const float* __restrict__ src,
                                                      __hip_bfloat16* __restrict__ dst,
                                                      int K, int N) {
  __shared__ float tl[32][33];
  const int n0 = blockIdx.x * 32, k0 = blockIdx.y * 32;
  const int tx = threadIdx.x & 31, ty = threadIdx.x >> 5;
#pragma unroll
  for (int i = 0; i < 4; ++i)
    tl[ty + 8 * i][tx] = src[(size_t)(k0 + ty + 8 * i) * N + n0 + tx];
  __syncthreads();
#pragma unroll
  for (int i = 0; i < 4; ++i)
    dst[(size_t)(n0 + ty + 8 * i) * K + k0 + tx] = __float2bfloat16(tl[tx][ty + 8 * i]);
}

// --------- split-K ba GEMM: X[1024,2048] @ Wba[2048,64] -> P[4][1024][64] ----
__global__ __launch_bounds__(256) void ba_gemm(const float* __restrict__ X,
                                               const float* __restrict__ Wba,
                                               float* __restrict__ P) {
  __shared__ __align__(16) float Xs[16][512];
  const int tt = blockIdx.x, ks = blockIdx.y;
  const int tid = threadIdx.x;
  const int c = tid & 63, r4 = tid >> 6;
  const float* xsrc = X + (size_t)(tt * 16) * 2048 + ks * 512;
#pragma unroll
  for (int u = 0; u < 8; ++u) {
    const int flat = (u * 256 + tid) * 4;
    const int r = flat >> 9, k = flat & 511;
    *reinterpret_cast<float4*>(&Xs[r][k]) =
        *reinterpret_cast<const float4*>(&xsrc[(size_t)r * 2048 + k]);
  }
  __syncthreads();
  float acc[4] = {};
  const float* wp = Wba + (size_t)(ks * 512) * 64 + c;
  for (int k = 0; k < 512; k += 8) {
    float w[8];
#pragma unroll
    for (int u = 0; u < 8; ++u) w[u] = wp[(size_t)(k + u) * 64];
#pragma unroll
    for (int u = 0; u < 8; ++u)
#pragma unroll
      for (int i = 0; i < 4; ++i)
        acc[i] = fmaf(Xs[r4 * 4 + i][k + u], w[u], acc[i]);
  }
  float* pp = P + ((size_t)ks * 1024 + tt * 16 + r4 * 4) * 64 + c;
#pragma unroll
  for (int i = 0; i < 4; ++i) pp[(size_t)i * 64] = acc[i];
}

// ------ causal depthwise conv (K=4) + silu, rolling-window over t ------------
// grid (32 ch-blocks, 32 t-tiles) x 256 thr; thread = one channel, 32 t's.
__global__ void conv_silu(const float* __restrict__ qkvz,
                          const float* __restrict__ conv_w,
                          float* __restrict__ QK, float* __restrict__ V) {
  const int c = blockIdx.x * 256 + threadIdx.x;
  const int t0 = blockIdx.y * 32;
  int col;
  if (c < 2048) {
    col = (c >> 7) * 768 + (c & 127);
  } else if (c < 4096) {
    const int c2 = c - 2048;
    col = (c2 >> 7) * 768 + 128 + (c2 & 127);
  } else {
    const int c2 = c - 4096;
    const int vh = c2 >> 7;
    col = (vh >> 1) * 768 + 256 + (vh & 1) * 128 + (c2 & 127);
  }
  const float4 w = *reinterpret_cast<const float4*>(&conv_w[c * 4]);
  float x0, x1, x2;
  if (t0 == 0) {
    x0 = 0.f; x1 = 0.f; x2 = 0.f;
  } else {
    x0 = qkvz[(size_t)(t0 - 3) * NQKVZ + col];
    x1 = qkvz[(size_t)(t0 - 2) * NQKVZ + col];
    x2 = qkvz[(size_t)(t0 - 1) * NQKVZ + col];
  }
#pragma unroll 4
  for (int tt = 0; tt < 32; ++tt) {
    const int t = t0 + tt;
    const float x3 = qkvz[(size_t)t * NQKVZ + col];
    float acc = x0 * w.x;
    acc = fmaf(x1, w.y, acc);
    acc = fmaf(x2, w.z, acc);
    acc = fmaf(x3, w.w, acc);
    const float y = acc / (1.f + expf(-acc));  // silu
    if (c < 4096) QK[(size_t)t * 4096 + c] = y;
    else          V[(size_t)t * 4096 + (c - 4096)] = y;
    x0 = x1; x1 = x2; x2 = x3;
  }
}

// ---------------- l2norm over DK for q and k (per t, per k-head) -------------
__global__ void l2norm_qk(float* __restrict__ QK) {
  const int h = blockIdx.x, t = blockIdx.y, l = threadIdx.x;  // 64 threads
  const size_t qb = (size_t)t * 4096 + h * 128;
  const size_t kb = qb + 2048;
  float q0 = QK[qb + l], q1 = QK[qb + l + 64];
  float k0 = QK[kb + l], k1 = QK[kb + l + 64];
  float sq = q0 * q0 + q1 * q1;
  float sk = k0 * k0 + k1 * k1;
#pragma unroll
  for (int off = 32; off; off >>= 1) {
    sq += __shfl_xor(sq, off);
    sk += __shfl_xor(sk, off);
  }
  const float rq = rsqrtf(sq + 1e-6f) * 0.08838834764831845f;  // * DK^-0.5
  const float rk = rsqrtf(sk + 1e-6f);
  QK[qb + l] = q0 * rq; QK[qb + l + 64] = q1 * rq;
  QK[kb + l] = k0 * rk; QK[kb + l + 64] = k1 * rk;
}

// ------ g/beta from split-K partials: sum 4 slices, then softplus/sigmoid ----
__global__ void compute_gb(const float* __restrict__ P,
                           const float* __restrict__ dt_bias,
                           const float* __restrict__ A_log,
                           float* __restrict__ gg, float* __restrict__ bet) {
  const int idx = blockIdx.x * 256 + threadIdx.x;  // t*32 + vh
  const int t = idx >> 5, vh = idx & 31;
  const int cb = (vh >> 1) * 4 + (vh & 1);
  float b = 0.f, a = 0.f;
#pragma unroll
  for (int s = 0; s < 4; ++s) {
    b += P[((size_t)s * 1024 + t) * 64 + cb];
    a += P[((size_t)s * 1024 + t) * 64 + cb + 2];
  }
  const float x = a + dt_bias[vh];
  const float sp = (x > 20.f) ? x : log1pf(expf(x));
  gg[idx] = -expf(A_log[vh]) * sp;
  bet[idx] = 1.f / (1.f + expf(-b));
}

// ---------------- phase 1: per (chunk, v-head) intra-chunk precompute --------
__global__ __launch_bounds__(256, 2) void phase1(
    const float* __restrict__ QK, const float* __restrict__ V,
    const float* __restrict__ g, const float* __restrict__ bet,
    float* __restrict__ U, __hip_bfloat16* __restrict__ Wb,
    __hip_bfloat16* __restrict__ KTb, __hip_bfloat16* __restrict__ Qgb,
    __hip_bfloat16* __restrict__ Bb, float* __restrict__ gend) {
  const int vh = blockIdx.x, ch = blockIdx.y, kh = vh >> 1;
  const int tid = threadIdx.x;
  const int t0 = ch * CHUNK;
  __shared__ __align__(16) float Kl[64][132];
  __shared__ float Al[64][65];
  __shared__ float bs[64], gams[64], bets[64], lams[64];

  const int row = tid >> 2;
  const size_t hb = (size_t)ch * 32 + vh;
  {
    const int cc = (tid & 3) * 32;
    const float* src = &QK[(size_t)(t0 + row) * 4096 + 2048 + kh * 128 + cc];
#pragma unroll
    for (int u = 0; u < 32; u += 4)
      *reinterpret_cast<float4*>(&Kl[row][cc + u]) =
          *reinterpret_cast<const float4*>(src + u);
  }
  if (tid < 64) {
    float b = g[(size_t)(t0 + tid) * 32 + vh];
#pragma unroll
    for (int off = 1; off < 64; off <<= 1) {
      const float o = __shfl_up(b, off);
      if (tid >= off) b += o;
    }
    const float b63 = __shfl(b, 63);
    const float ga = expf(b);
    bs[tid] = b;
    gams[tid] = ga;
    lams[tid] = expf(b63 - b);
    bets[tid] = bet[(size_t)(t0 + tid) * 32 + vh];
    if (tid == 63) gend[ch * 32 + vh] = ga;
  }
  __syncthreads();
  {
    const int i = tid & 63;
    const float li = lams[i];
    __hip_bfloat16* kt = &KTb[hb * 128 * 64];
    const int dbase = (tid >> 6) * 32;
#pragma unroll
    for (int dd = 0; dd < 32; ++dd) {
      const int d = dbase + dd;
      kt[(size_t)d * 64 + (i ^ ((d & 7) << 3))] = __float2bfloat16(li * Kl[i][d]);
    }
  }
  {
    const int j0 = (tid & 3) * 16;
    const float* qrow = &QK[(size_t)(t0 + row) * 4096 + kh * 128];
    const float gai = gams[row];
    __hip_bfloat16* qg = &Qgb[(hb * 64 + row) * 128];
    float accA[16], accB[16];
#pragma unroll
    for (int jj = 0; jj < 16; ++jj) { accA[jj] = 0.f; accB[jj] = 0.f; }
    for (int d = 0; d < 128; d += 4) {
      const float4 qi = *reinterpret_cast<const float4*>(qrow + d);
      const float4 ki = *reinterpret_cast<const float4*>(&Kl[row][d]);
      if ((d >> 5) == (tid & 3)) {
        ushort4 qq;
        qq.x = __bfloat16_as_ushort(__float2bfloat16(gai * qi.x));
        qq.y = __bfloat16_as_ushort(__float2bfloat16(gai * qi.y));
        qq.z = __bfloat16_as_ushort(__float2bfloat16(gai * qi.z));
        qq.w = __bfloat16_as_ushort(__float2bfloat16(gai * qi.w));
        *reinterpret_cast<ushort4*>(&qg[d ^ ((row & 7) << 3)]) = qq;
      }
#pragma unroll
      for (int jj = 0; jj < 16; ++jj) {
        const float4 kj = *reinterpret_cast<const float4*>(&Kl[j0 + jj][d]);
        accA[jj] += ki.x * kj.x + ki.y * kj.y + ki.z * kj.z + ki.w * kj.w;
        accB[jj] += qi.x * kj.x + qi.y * kj.y + qi.z * kj.z + qi.w * kj.w;
      }
    }
    const float bi = bets[row], bvi = bs[row];
    __hip_bfloat16* Bout = &Bb[(hb * 64 + row) * 64];
#pragma unroll
    for (int jj = 0; jj < 16; ++jj) {
      const int j = j0 + jj;
      const float dec = expf(bvi - bs[j]);
      Al[row][j] = (j < row) ? bi * dec * accA[jj] : 0.f;
      Bout[j ^ ((row & 7) << 3)] =
          __float2bfloat16((j <= row) ? dec * accB[jj] : 0.f);
    }
  }
  __syncthreads();
  // register-resident right-looking solve of (I+A) x = rhs, column tid.
  {
    const int cc = tid;
    float x[64];
    const bool isV = cc < 128;
    const float* src = isV ? &V[(size_t)t0 * 4096 + vh * 128 + cc]
                           : &QK[(size_t)t0 * 4096 + 2048 + kh * 128 + (cc - 128)];
#pragma unroll
    for (int i = 0; i < 64; ++i) {
      const float sc = isV ? bets[i] : bets[i] * gams[i];
      x[i] = sc * src[(size_t)i * 4096];
    }
#pragma unroll
    for (int j = 0; j < 63; ++j)
#pragma unroll
      for (int i = j + 1; i < 64; ++i)
        x[i] = fmaf(-Al[i][j], x[j], x[i]);
    if (isV) {
      float* dst = &U[hb * 64 * 128 + cc];
#pragma unroll
      for (int i = 0; i < 64; ++i) dst[(size_t)i * 128] = x[i];
    } else {
      const int d = cc - 128;
      __hip_bfloat16* dst = &Wb[hb * 64 * 128];
#pragma unroll
      for (int i = 0; i < 64; ++i)
        dst[(size_t)i * 128 + (d ^ ((i & 7) << 3))] = __float2bfloat16(-x[i]);
    }
  }
}

// ---------------- phaseB: serial MFMA state propagation ----------------------
__global__ __launch_bounds__(128) void phaseB(
    const float* __restrict__ Ug, const __hip_bfloat16* __restrict__ Wb,
    const __hip_bfloat16* __restrict__ KTb, const __hip_bfloat16* __restrict__ Qgb,
    const __hip_bfloat16* __restrict__ Bb, const float* __restrict__ gendg,
    float* __restrict__ Og) {
  const int vh = blockIdx.x, slice = blockIdx.y;
  const int tid = threadIdx.x, lane = tid & 63, w = tid >> 6;
  const int l15 = lane & 15, l4 = lane >> 4;
  const int cg = slice * 32 + w * 16;
  const int swz = (l15 & 7) << 3;

  __shared__ __hip_bfloat16 Wl[2][8192];
  __shared__ __hip_bfloat16 KTl[2][8192];
  __shared__ __hip_bfloat16 Qgl[2][8192];
  __shared__ __hip_bfloat16 Bl[2][4096];
  __shared__ __hip_bfloat16 Sop[2][2048];
  __shared__ __hip_bfloat16 dLs[2][1024];

  f32x4 accS[8] = {};
  for (int x = lane; x < 1024; x += 64) reinterpret_cast<uint*>(Sop[w])[x] = 0;

  float ubuf[4][4];
#define STAGE(b_, c_) do {                                                      \
    const size_t hb_ = ((size_t)(c_) * 32 + vh);                                \
    _Pragma("unroll") for (int it = 0; it < 8; ++it) {                          \
      __builtin_amdgcn_global_load_lds(                                         \
          (const __attribute__((address_space(1))) void*)(Wb + hb_ * 8192 + it * 1024 + tid * 8), \
          (__attribute__((address_space(3))) void*)(&Wl[b_][it * 1024 + tid * 8]), 16, 0, 0); \
      __builtin_amdgcn_global_load_lds(                                         \
          (const __attribute__((address_space(1))) void*)(KTb + hb_ * 8192 + it * 1024 + tid * 8), \
          (__attribute__((address_space(3))) void*)(&KTl[b_][it * 1024 + tid * 8]), 16, 0, 0); \
      __builtin_amdgcn_global_load_lds(                                         \
          (const __attribute__((address_space(1))) void*)(Qgb + hb_ * 8192 + it * 1024 + tid * 8), \
          (__attribute__((address_space(3))) void*)(&Qgl[b_][it * 1024 + tid * 8]), 16, 0, 0); \
      if (it < 4)                                                               \
        __builtin_amdgcn_global_load_lds(                                       \
            (const __attribute__((address_space(1))) void*)(Bb + hb_ * 4096 + it * 1024 + tid * 8), \
            (__attribute__((address_space(3))) void*)(&Bl[b_][it * 1024 + tid * 8]), 16, 0, 0); \
    }                                                                           \
  } while (0)
#define UPREF(c_) do {                                                          \
    const float* up_ = Ug + ((size_t)(c_) * 32 + vh) * 64 * 128 + cg + l15;     \
    _Pragma("unroll") for (int m_ = 0; m_ < 4; ++m_)                            \
      _Pragma("unroll") for (int r_ = 0; r_ < 4; ++r_)                          \
        ubuf[m_][r_] = up_[(size_t)(m_ * 16 + l4 * 4 + r_) * 128];              \
  } while (0)

  STAGE(0, 0);
  UPREF(0);
  __syncthreads();
  int buf = 0;
  for (int ch = 0; ch < NCHUNK; ++ch) {
    if (ch + 1 < NCHUNK) STAGE(buf ^ 1, ch + 1);
    f32x4 acc_d[4];
#pragma unroll
    for (int m = 0; m < 4; ++m) {
      f32x4 t;
      t[0] = ubuf[m][0]; t[1] = ubuf[m][1]; t[2] = ubuf[m][2]; t[3] = ubuf[m][3];
      acc_d[m] = t;
    }
    if (ch + 1 < NCHUNK) UPREF(ch + 1);
    // op1: delta = U + (-W) @ S
#pragma unroll
    for (int t = 0; t < 4; ++t) {
      const bf16x8 bS = *reinterpret_cast<const bf16x8*>(
          &Sop[w][l15 * 128 + ((t * 32 + l4 * 8) ^ swz)]);
#pragma unroll
      for (int m = 0; m < 4; ++m) {
        const bf16x8 aW = *reinterpret_cast<const bf16x8*>(
            &Wl[buf][(m * 16 + l15) * 128 + ((t * 32 + l4 * 8) ^ swz)]);
        acc_d[m] = __builtin_amdgcn_mfma_f32_16x16x32_bf16(aW, bS, acc_d[m], 0, 0, 0);
      }
    }
#pragma unroll
    for (int m = 0; m < 4; ++m)
      *reinterpret_cast<ushort4*>(&dLs[w][l15 * 64 + ((m * 16 + l4 * 4) ^ swz)]) =
          pack4(acc_d[m]);
    // opO: o = γq @ S + B @ δ
    f32x4 acc_o[4] = {};
#pragma unroll
    for (int t = 0; t < 4; ++t) {
      const bf16x8 bS = *reinterpret_cast<const bf16x8*>(
          &Sop[w][l15 * 128 + ((t * 32 + l4 * 8) ^ swz)]);
#pragma unroll
      for (int m = 0; m < 4; ++m) {
        const bf16x8 aQ = *reinterpret_cast<const bf16x8*>(
            &Qgl[buf][(m * 16 + l15) * 128 + ((t * 32 + l4 * 8) ^ swz)]);
        acc_o[m] = __builtin_amdgcn_mfma_f32_16x16x32_bf16(aQ, bS, acc_o[m], 0, 0, 0);
      }
    }
#pragma unroll
    for (int t2 = 0; t2 < 2; ++t2) {
      const bf16x8 bD = *reinterpret_cast<const bf16x8*>(
          &dLs[w][l15 * 64 + ((t2 * 32 + l4 * 8) ^ swz)]);
#pragma unroll
      for (int m = 0; m < 4; ++m) {
        const bf16x8 aB = *reinterpret_cast<const bf16x8*>(
            &Bl[buf][(m * 16 + l15) * 64 + ((t2 * 32 + l4 * 8) ^ swz)]);
        acc_o[m] = __builtin_amdgcn_mfma_f32_16x16x32_bf16(aB, bD, acc_o[m], 0, 0, 0);
      }
    }
    float* ob = Og + (size_t)(ch * 64) * 4096 + (size_t)vh * 128 + cg + l15;
#pragma unroll
    for (int m = 0; m < 4; ++m)
#pragma unroll
      for (int r = 0; r < 4; ++r)
        ob[(size_t)(m * 16 + l4 * 4 + r) * 4096] = acc_o[m][r];
    // op3: S = ge*S + Kᵀλ @ δ
    const float ge = gendg[ch * 32 + vh];
#pragma unroll
    for (int f = 0; f < 8; ++f) {
      accS[f][0] *= ge; accS[f][1] *= ge; accS[f][2] *= ge; accS[f][3] *= ge;
    }
#pragma unroll
    for (int t2 = 0; t2 < 2; ++t2) {
      const bf16x8 bD = *reinterpret_cast<const bf16x8*>(
          &dLs[w][l15 * 64 + ((t2 * 32 + l4 * 8) ^ swz)]);
#pragma unroll
      for (int f = 0; f < 8; ++f) {
        const bf16x8 aK = *reinterpret_cast<const bf16x8*>(
            &KTl[buf][(f * 16 + l15) * 64 + ((t2 * 32 + l4 * 8) ^ swz)]);
        accS[f] = __builtin_amdgcn_mfma_f32_16x16x32_bf16(aK, bD, accS[f], 0, 0, 0);
      }
    }
#pragma unroll
    for (int f = 0; f < 8; ++f)
      *reinterpret_cast<ushort4*>(&Sop[w][l15 * 128 + ((f * 16 + l4 * 4) ^ swz)]) =
          pack4(accS[f]);
    __syncthreads();
    buf ^= 1;
  }
#undef STAGE
#undef UPREF
}

// ------- gated = rmsnorm(o * silu(z)) * norm_w, emitted as bf16 --------------
__global__ void gate_norm(const float* __restrict__ O,
                          const float* __restrict__ qkvz,
                          const float* __restrict__ norm_w,
                          __hip_bfloat16* __restrict__ G) {
  const int vh = blockIdx.x, t = blockIdx.y, l = threadIdx.x;  // 64 threads
  const size_t ob = (size_t)t * 4096 + vh * 128;
  const size_t zb = (size_t)t * NQKVZ + (vh >> 1) * 768 + 512 + (vh & 1) * 128;
  const float o0 = O[ob + l], o1 = O[ob + l + 64];
  const float z0 = qkvz[zb + l], z1 = qkvz[zb + l + 64];
  const float g0 = o0 * z0 / (1.f + expf(-z0));
  const float g1 = o1 * z1 / (1.f + expf(-z1));
  float ss = g0 * g0 + g1 * g1;
#pragma unroll
  for (int off = 32; off; off >>= 1) ss += __shfl_xor(ss, off);
  const float rr = rsqrtf(ss * (1.f / 128.f) + 1e-6f);
  G[ob + l] = __float2bfloat16(g0 * rr * norm_w[l]);
  G[ob + l + 64] = __float2bfloat16(g1 * rr * norm_w[l + 64]);
}

extern "C" void kernel_launch(void* const* d_in, const int* in_sizes, int n_in,
                              void* d_out, int out_size, void* d_ws, size_t ws_size,
                              hipStream_t stream) {
  const float* X = (const float*)d_in[0];
  const float* W_qkvz = (const float*)d_in[1];
  const float* W_ba = (const float*)d_in[2];
  const float* conv_w = (const float*)d_in[3];
  const float* dt_bias = (const float*)d_in[4];
  const float* A_log = (const float*)d_in[5];
  const float* norm_w = (const float*)d_in[6];
  const float* W_out = (const float*)d_in[7];
  float* out = (float*)d_out;

  float* ws = (float*)d_ws;
  float* qkvz = ws;                                // 12,582,912 f
  float* P = qkvz + (size_t)T_LEN * NQKVZ;         //    262,144 f (ba partials)
  float* QK = P + 262144;                          //  4,194,304 f
  float* V = QK + (size_t)T_LEN * 4096;            //  4,194,304 f
  float* U = V + (size_t)T_LEN * 4096;             //  4,194,304 f
  float* Wb_f = U + (size_t)NCHUNK * 32 * 64 * 128;//  2,097,152 f (bf16 x 4.19M)
  float* KT_f = Wb_f + 2097152;                    //  2,097,152 f
  float* Qg_f = KT_f + 2097152;                    //  2,097,152 f
  float* Bb_f = Qg_f + 2097152;                    //  1,048,576 f (bf16 x 2.10M)
  float* gg = Bb_f + 1048576;                      //     32,768 f
  float* bet = gg + 32768;                         //     32,768 f
  float* gend = bet + 32768;                       //        512 f

  __hip_bfloat16* Wb = (__hip_bfloat16*)Wb_f;
  __hip_bfloat16* KTb = (__hip_bfloat16*)KT_f;
  __hip_bfloat16* Qgb = (__hip_bfloat16*)Qg_f;
  __hip_bfloat16* Bb = (__hip_bfloat16*)Bb_f;
  // lifetime aliases:
  __hip_bfloat16* Wqkvz_t = (__hip_bfloat16*)V;    // spans V+U+Wb+KT (dead after 1st gemm)
  __hip_bfloat16* Xb = (__hip_bfloat16*)Qg_f;      // dead after 1st gemm
  __hip_bfloat16* Gb = (__hip_bfloat16*)Bb_f;      // Bb dead after phaseB
  __hip_bfloat16* Wout_t = (__hip_bfloat16*)qkvz;  // qkvz dead after gate_norm
  float* O = V;                                    // V dead after phase1
  float* Pout = U;                                 // U dead after phaseB; 2x 2,097,152 f

  cast_bf16<<<dim3(T_LEN * 2048 / 4 / 256), 256, 0, stream>>>(X, Xb, T_LEN * 2048);
  transpose_cast<<<dim3(NQKVZ / 32, 2048 / 32), 256, 0, stream>>>(W_qkvz, Wqkvz_t, 2048, NQKVZ);
  gemm_bf16<<<dim3(NQKVZ / 128, T_LEN / 128, 1), 256, 0, stream>>>(Xb, Wqkvz_t, qkvz, T_LEN, NQKVZ, 2048, 2048);
  ba_gemm<<<dim3(64, 4), 256, 0, stream>>>(X, W_ba, P);
  conv_silu<<<dim3(CDIM / 256, T_LEN / 32), 256, 0, stream>>>(qkvz, conv_w, QK, V);
  l2norm_qk<<<dim3(HK_N, T_LEN), 64, 0, stream>>>(QK);
  compute_gb<<<dim3(T_LEN * 32 / 256), 256, 0, stream>>>(P, dt_bias, A_log, gg, bet);
  phase1<<<dim3(HV_N, NCHUNK), 256, 0, stream>>>(QK, V, gg, bet, U, Wb, KTb, Qgb, Bb, gend);
  phaseB<<<dim3(HV_N, 4), 128, 0, stream>>>(U, Wb, KTb, Qgb, Bb, gend, O);
  gate_norm<<<dim3(HV_N, T_LEN), 64, 0, stream>>>(O, qkvz, norm_w, Gb);
  transpose_cast<<<dim3(2048 / 32, 4096 / 32), 256, 0, stream>>>(W_out, Wout_t, 4096, 2048);
  gemm_bf16<<<dim3(2048 / 128, T_LEN / 128, 2), 256, 0, stream>>>(Gb, Wout_t, Pout, T_LEN, 2048, 2048, 4096);
  add2<<<dim3(T_LEN * 2048 / 4 / 256), 256, 0, stream>>>(Pout, out, T_LEN * 2048);
}

// Round 8
// 319.795 us; speedup vs baseline: 13.8408x; 1.0740x over previous
//
#include <hip/hip_runtime.h>
#include <hip/hip_bf16.h>
#include <math.h>

// Qwen3Next GatedDeltaNet — round 7: T2 XOR swizzle in gemm_bf16 (BK=64 made
// LDS rows 128 B -> 16-way bank conflict on ds_read_b128; 18.9M conflict
// cycles = 29% of the dispatch). Swizzle is both-sides: pre-swizzled global
// source (LDS dest linear, required by global_load_lds) + XOR'd ds_read.

#define T_LEN 1024
#define HK_N 16
#define HV_N 32
#define NQKVZ 12288
#define CDIM 8192
#define CHUNK 64
#define NCHUNK 16

typedef __bf16 bf16x8 __attribute__((ext_vector_type(8)));
typedef float f32x4 __attribute__((ext_vector_type(4)));

__device__ __forceinline__ ushort4 pack4(const f32x4 v) {
  ushort4 o;
  o.x = __bfloat16_as_ushort(__float2bfloat16(v[0]));
  o.y = __bfloat16_as_ushort(__float2bfloat16(v[1]));
  o.z = __bfloat16_as_ushort(__float2bfloat16(v[2]));
  o.w = __bfloat16_as_ushort(__float2bfloat16(v[3]));
  return o;
}

// ------- bf16 MFMA GEMM: C[M,N] (+= z-partials) = A[M,ldk] @ B[N,ldk]^T ------
// BK=64, T2 st-style swizzle: 8-elem chunk c8 of row r stored at c8^(r&7).
__global__ __launch_bounds__(256) void gemm_bf16(const __hip_bfloat16* __restrict__ A,
                                                 const __hip_bfloat16* __restrict__ B,
                                                 float* __restrict__ C,
                                                 int M, int N, int Klen, int ldk) {
  __shared__ __align__(16) __hip_bfloat16 As[128 * 64];
  __shared__ __align__(16) __hip_bfloat16 Bs[128 * 64];
  const int tid = threadIdx.x;
  const int wid = tid >> 6, lane = tid & 63;
  const int wr = wid >> 1, wc = wid & 1;
  const int m0 = blockIdx.y * 128, n0 = blockIdx.x * 128;
  const size_t kbase = (size_t)blockIdx.z * Klen;
  float* Cz = C + (size_t)blockIdx.z * M * N;
  const int lrow = lane & 15, lk = lane >> 4;
  const int rswz = (lrow & 7) * 8;
  f32x4 acc[4][4] = {};

  for (int k0 = 0; k0 < Klen; k0 += 64) {
#pragma unroll
    for (int it = 0; it < 4; ++it) {
      const int c = it * 256 + tid;
      const int row = c >> 3;
      const int col8 = ((c & 7) ^ (row & 7)) * 8;  // pre-swizzled source
      const __hip_bfloat16* ga = A + (size_t)(m0 + row) * ldk + kbase + k0 + col8;
      const __hip_bfloat16* gb = B + (size_t)(n0 + row) * ldk + kbase + k0 + col8;
      __builtin_amdgcn_global_load_lds(
          (const __attribute__((address_space(1))) void*)ga,
          (__attribute__((address_space(3))) void*)(As + it * 2048 + tid * 8), 16, 0, 0);
      __builtin_amdgcn_global_load_lds(
          (const __attribute__((address_space(1))) void*)gb,
          (__attribute__((address_space(3))) void*)(Bs + it * 2048 + tid * 8), 16, 0, 0);
    }
    __syncthreads();
#pragma unroll
    for (int kk = 0; kk < 2; ++kk) {
      bf16x8 af[4], bfv[4];
#pragma unroll
      for (int m = 0; m < 4; ++m)
        af[m] = *reinterpret_cast<const bf16x8*>(
            As + (wr * 64 + m * 16 + lrow) * 64 + ((kk * 32 + lk * 8) ^ rswz));
#pragma unroll
      for (int n = 0; n < 4; ++n)
        bfv[n] = *reinterpret_cast<const bf16x8*>(
            Bs + (wc * 64 + n * 16 + lrow) * 64 + ((kk * 32 + lk * 8) ^ rswz));
#pragma unroll
      for (int m = 0; m < 4; ++m)
#pragma unroll
        for (int n = 0; n < 4; ++n)
          acc[m][n] = __builtin_amdgcn_mfma_f32_16x16x32_bf16(af[m], bfv[n], acc[m][n], 0, 0, 0);
    }
    __syncthreads();
  }
#pragma unroll
  for (int m = 0; m < 4; ++m)
#pragma unroll
    for (int n = 0; n < 4; ++n)
#pragma unroll
      for (int r = 0; r < 4; ++r)
        Cz[(size_t)(m0 + wr * 64 + m * 16 + lk * 4 + r) * N + n0 + wc * 64 + n * 16 + lrow] =
            acc[m][n][r];
}

// ---------------- out = P0 + P1 (split-K reduction) --------------------------
__global__ void add2(const float* __restrict__ P, float* __restrict__ out, int n) {
  const int i = (blockIdx.x * 256 + threadIdx.x) * 4;
  if (i < n) {
    const float4 a = *reinterpret_cast<const float4*>(P + i);
    const float4 b = *reinterpret_cast<const float4*>(P + n + i);
    *reinterpret_cast<float4*>(out + i) =
        make_float4(a.x + b.x, a.y + b.y, a.z + b.z, a.w + b.w);
  }
}

// ---------------- fp32 -> bf16 elementwise cast ------------------------------
__global__ void cast_bf16(const float* __restrict__ src,
                          __hip_bfloat16* __restrict__ dst, int n) {
  const int i = (blockIdx.x * 256 + threadIdx.x) * 4;
  if (i < n) {
    const float4 v = *reinterpret_cast<const float4*>(src + i);
    ushort4 o;
    o.x = __bfloat16_as_ushort(__float2bfloat16(v.x));
    o.y = __bfloat16_as_ushort(__float2bfloat16(v.y));
    o.z = __bfloat16_as_ushort(__float2bfloat16(v.z));
    o.w = __bfloat16_as_ushort(__float2bfloat16(v.w));
    *reinterpret_cast<ushort4*>((void*)(dst + i)) = o;
  }
}

// ---------------- fp32 [K,N] -> bf16 [N,K] tiled transpose-cast --------------
__global__ __launch_bounds__(256) void transpose_cast(const float* __restrict__ src,
                                                      __hip_bfloat16* __restrict__ dst,
                                                      int K, int N) {
  __shared__ float tl[32][33];
  const int n0 = blockIdx.x * 32, k0 = blockIdx.y * 32;
  const int tx = threadIdx.x & 31, ty = threadIdx.x >> 5;
#pragma unroll
  for (int i = 0; i < 4; ++i)
    tl[ty + 8 * i][tx] = src[(size_t)(k0 + ty + 8 * i) * N + n0 + tx];
  __syncthreads();
#pragma unroll
  for (int i = 0; i < 4; ++i)
    dst[(size_t)(n0 + ty + 8 * i) * K + k0 + tx] = __float2bfloat16(tl[tx][ty + 8 * i]);
}

// --------- split-K ba GEMM: X[1024,2048] @ Wba[2048,64] -> P[4][1024][64] ----
__global__ __launch_bounds__(256) void ba_gemm(const float* __restrict__ X,
                                               const float* __restrict__ Wba,
                                               float* __restrict__ P) {
  __shared__ __align__(16) float Xs[16][512];
  const int tt = blockIdx.x, ks = blockIdx.y;
  const int tid = threadIdx.x;
  const int c = tid & 63, r4 = tid >> 6;
  const float* xsrc = X + (size_t)(tt * 16) * 2048 + ks * 512;
#pragma unroll
  for (int u = 0; u < 8; ++u) {
    const int flat = (u * 256 + tid) * 4;
    const int r = flat >> 9, k = flat & 511;
    *reinterpret_cast<float4*>(&Xs[r][k]) =
        *reinterpret_cast<const float4*>(&xsrc[(size_t)r * 2048 + k]);
  }
  __syncthreads();
  float acc[4] = {};
  const float* wp = Wba + (size_t)(ks * 512) * 64 + c;
  for (int k = 0; k < 512; k += 8) {
    float w[8];
#pragma unroll
    for (int u = 0; u < 8; ++u) w[u] = wp[(size_t)(k + u) * 64];
#pragma unroll
    for (int u = 0; u < 8; ++u)
#pragma unroll
      for (int i = 0; i < 4; ++i)
        acc[i] = fmaf(Xs[r4 * 4 + i][k + u], w[u], acc[i]);
  }
  float* pp = P + ((size_t)ks * 1024 + tt * 16 + r4 * 4) * 64 + c;
#pragma unroll
  for (int i = 0; i < 4; ++i) pp[(size_t)i * 64] = acc[i];
}

// ------ causal depthwise conv (K=4) + silu, rolling-window over t ------------
__global__ void conv_silu(const float* __restrict__ qkvz,
                          const float* __restrict__ conv_w,
                          float* __restrict__ QK, float* __restrict__ V) {
  const int c = blockIdx.x * 256 + threadIdx.x;
  const int t0 = blockIdx.y * 32;
  int col;
  if (c < 2048) {
    col = (c >> 7) * 768 + (c & 127);
  } else if (c < 4096) {
    const int c2 = c - 2048;
    col = (c2 >> 7) * 768 + 128 + (c2 & 127);
  } else {
    const int c2 = c - 4096;
    const int vh = c2 >> 7;
    col = (vh >> 1) * 768 + 256 + (vh & 1) * 128 + (c2 & 127);
  }
  const float4 w = *reinterpret_cast<const float4*>(&conv_w[c * 4]);
  float x0, x1, x2;
  if (t0 == 0) {
    x0 = 0.f; x1 = 0.f; x2 = 0.f;
  } else {
    x0 = qkvz[(size_t)(t0 - 3) * NQKVZ + col];
    x1 = qkvz[(size_t)(t0 - 2) * NQKVZ + col];
    x2 = qkvz[(size_t)(t0 - 1) * NQKVZ + col];
  }
#pragma unroll 4
  for (int tt = 0; tt < 32; ++tt) {
    const int t = t0 + tt;
    const float x3 = qkvz[(size_t)t * NQKVZ + col];
    float acc = x0 * w.x;
    acc = fmaf(x1, w.y, acc);
    acc = fmaf(x2, w.z, acc);
    acc = fmaf(x3, w.w, acc);
    const float y = acc / (1.f + expf(-acc));  // silu
    if (c < 4096) QK[(size_t)t * 4096 + c] = y;
    else          V[(size_t)t * 4096 + (c - 4096)] = y;
    x0 = x1; x1 = x2; x2 = x3;
  }
}

// ---------------- l2norm over DK for q and k (per t, per k-head) -------------
__global__ void l2norm_qk(float* __restrict__ QK) {
  const int h = blockIdx.x, t = blockIdx.y, l = threadIdx.x;  // 64 threads
  const size_t qb = (size_t)t * 4096 + h * 128;
  const size_t kb = qb + 2048;
  float q0 = QK[qb + l], q1 = QK[qb + l + 64];
  float k0 = QK[kb + l], k1 = QK[kb + l + 64];
  float sq = q0 * q0 + q1 * q1;
  float sk = k0 * k0 + k1 * k1;
#pragma unroll
  for (int off = 32; off; off >>= 1) {
    sq += __shfl_xor(sq, off);
    sk += __shfl_xor(sk, off);
  }
  const float rq = rsqrtf(sq + 1e-6f) * 0.08838834764831845f;  // * DK^-0.5
  const float rk = rsqrtf(sk + 1e-6f);
  QK[qb + l] = q0 * rq; QK[qb + l + 64] = q1 * rq;
  QK[kb + l] = k0 * rk; QK[kb + l + 64] = k1 * rk;
}

// ------ g/beta from split-K partials: sum 4 slices, then softplus/sigmoid ----
__global__ void compute_gb(const float* __restrict__ P,
                           const float* __restrict__ dt_bias,
                           const float* __restrict__ A_log,
                           float* __restrict__ gg, float* __restrict__ bet) {
  const int idx = blockIdx.x * 256 + threadIdx.x;  // t*32 + vh
  const int t = idx >> 5, vh = idx & 31;
  const int cb = (vh >> 1) * 4 + (vh & 1);
  float b = 0.f, a = 0.f;
#pragma unroll
  for (int s = 0; s < 4; ++s) {
    b += P[((size_t)s * 1024 + t) * 64 + cb];
    a += P[((size_t)s * 1024 + t) * 64 + cb + 2];
  }
  const float x = a + dt_bias[vh];
  const float sp = (x > 20.f) ? x : log1pf(expf(x));
  gg[idx] = -expf(A_log[vh]) * sp;
  bet[idx] = 1.f / (1.f + expf(-b));
}

// ---------------- phase 1: per (chunk, v-head) intra-chunk precompute --------
__global__ __launch_bounds__(256, 2) void phase1(
    const float* __restrict__ QK, const float* __restrict__ V,
    const float* __restrict__ g, const float* __restrict__ bet,
    float* __restrict__ U, __hip_bfloat16* __restrict__ Wb,
    __hip_bfloat16* __restrict__ KTb, __hip_bfloat16* __restrict__ Qgb,
    __hip_bfloat16* __restrict__ Bb, float* __restrict__ gend) {
  const int vh = blockIdx.x, ch = blockIdx.y, kh = vh >> 1;
  const int tid = threadIdx.x;
  const int t0 = ch * CHUNK;
  __shared__ __align__(16) float Kl[64][132];
  __shared__ float Al[64][65];
  __shared__ float bs[64], gams[64], bets[64], lams[64];

  const int row = tid >> 2;
  const size_t hb = (size_t)ch * 32 + vh;
  {
    const int cc = (tid & 3) * 32;
    const float* src = &QK[(size_t)(t0 + row) * 4096 + 2048 + kh * 128 + cc];
#pragma unroll
    for (int u = 0; u < 32; u += 4)
      *reinterpret_cast<float4*>(&Kl[row][cc + u]) =
          *reinterpret_cast<const float4*>(src + u);
  }
  if (tid < 64) {
    float b = g[(size_t)(t0 + tid) * 32 + vh];
#pragma unroll
    for (int off = 1; off < 64; off <<= 1) {
      const float o = __shfl_up(b, off);
      if (tid >= off) b += o;
    }
    const float b63 = __shfl(b, 63);
    const float ga = expf(b);
    bs[tid] = b;
    gams[tid] = ga;
    lams[tid] = expf(b63 - b);
    bets[tid] = bet[(size_t)(t0 + tid) * 32 + vh];
    if (tid == 63) gend[ch * 32 + vh] = ga;
  }
  __syncthreads();
  {
    const int i = tid & 63;
    const float li = lams[i];
    __hip_bfloat16* kt = &KTb[hb * 128 * 64];
    const int dbase = (tid >> 6) * 32;
#pragma unroll
    for (int dd = 0; dd < 32; ++dd) {
      const int d = dbase + dd;
      kt[(size_t)d * 64 + (i ^ ((d & 7) << 3))] = __float2bfloat16(li * Kl[i][d]);
    }
  }
  {
    const int j0 = (tid & 3) * 16;
    const float* qrow = &QK[(size_t)(t0 + row) * 4096 + kh * 128];
    const float gai = gams[row];
    __hip_bfloat16* qg = &Qgb[(hb * 64 + row) * 128];
    float accA[16], accB[16];
#pragma unroll
    for (int jj = 0; jj < 16; ++jj) { accA[jj] = 0.f; accB[jj] = 0.f; }
    for (int d = 0; d < 128; d += 4) {
      const float4 qi = *reinterpret_cast<const float4*>(qrow + d);
      const float4 ki = *reinterpret_cast<const float4*>(&Kl[row][d]);
      if ((d >> 5) == (tid & 3)) {
        ushort4 qq;
        qq.x = __bfloat16_as_ushort(__float2bfloat16(gai * qi.x));
        qq.y = __bfloat16_as_ushort(__float2bfloat16(gai * qi.y));
        qq.z = __bfloat16_as_ushort(__float2bfloat16(gai * qi.z));
        qq.w = __bfloat16_as_ushort(__float2bfloat16(gai * qi.w));
        *reinterpret_cast<ushort4*>(&qg[d ^ ((row & 7) << 3)]) = qq;
      }
#pragma unroll
      for (int jj = 0; jj < 16; ++jj) {
        const float4 kj = *reinterpret_cast<const float4*>(&Kl[j0 + jj][d]);
        accA[jj] += ki.x * kj.x + ki.y * kj.y + ki.z * kj.z + ki.w * kj.w;
        accB[jj] += qi.x * kj.x + qi.y * kj.y + qi.z * kj.z + qi.w * kj.w;
      }
    }
    const float bi = bets[row], bvi = bs[row];
    __hip_bfloat16* Bout = &Bb[(hb * 64 + row) * 64];
#pragma unroll
    for (int jj = 0; jj < 16; ++jj) {
      const int j = j0 + jj;
      const float dec = expf(bvi - bs[j]);
      Al[row][j] = (j < row) ? bi * dec * accA[jj] : 0.f;
      Bout[j ^ ((row & 7) << 3)] =
          __float2bfloat16((j <= row) ? dec * accB[jj] : 0.f);
    }
  }
  __syncthreads();
  // register-resident right-looking solve of (I+A) x = rhs, column tid.
  {
    const int cc = tid;
    float x[64];
    const bool isV = cc < 128;
    const float* src = isV ? &V[(size_t)t0 * 4096 + vh * 128 + cc]
                           : &QK[(size_t)t0 * 4096 + 2048 + kh * 128 + (cc - 128)];
#pragma unroll
    for (int i = 0; i < 64; ++i) {
      const float sc = isV ? bets[i] : bets[i] * gams[i];
      x[i] = sc * src[(size_t)i * 4096];
    }
#pragma unroll
    for (int j = 0; j < 63; ++j)
#pragma unroll
      for (int i = j + 1; i < 64; ++i)
        x[i] = fmaf(-Al[i][j], x[j], x[i]);
    if (isV) {
      float* dst = &U[hb * 64 * 128 + cc];
#pragma unroll
      for (int i = 0; i < 64; ++i) dst[(size_t)i * 128] = x[i];
    } else {
      const int d = cc - 128;
      __hip_bfloat16* dst = &Wb[hb * 64 * 128];
#pragma unroll
      for (int i = 0; i < 64; ++i)
        dst[(size_t)i * 128 + (d ^ ((i & 7) << 3))] = __float2bfloat16(-x[i]);
    }
  }
}

// ---------------- phaseB: serial MFMA state propagation ----------------------
__global__ __launch_bounds__(128) void phaseB(
    const float* __restrict__ Ug, const __hip_bfloat16* __restrict__ Wb,
    const __hip_bfloat16* __restrict__ KTb, const __hip_bfloat16* __restrict__ Qgb,
    const __hip_bfloat16* __restrict__ Bb, const float* __restrict__ gendg,
    float* __restrict__ Og) {
  const int vh = blockIdx.x, slice = blockIdx.y;
  const int tid = threadIdx.x, lane = tid & 63, w = tid >> 6;
  const int l15 = lane & 15, l4 = lane >> 4;
  const int cg = slice * 32 + w * 16;
  const int swz = (l15 & 7) << 3;

  __shared__ __hip_bfloat16 Wl[2][8192];
  __shared__ __hip_bfloat16 KTl[2][8192];
  __shared__ __hip_bfloat16 Qgl[2][8192];
  __shared__ __hip_bfloat16 Bl[2][4096];
  __shared__ __hip_bfloat16 Sop[2][2048];
  __shared__ __hip_bfloat16 dLs[2][1024];

  f32x4 accS[8] = {};
  for (int x = lane; x < 1024; x += 64) reinterpret_cast<uint*>(Sop[w])[x] = 0;

  float ubuf[4][4];
#define STAGE(b_, c_) do {                                                      \
    const size_t hb_ = ((size_t)(c_) * 32 + vh);                                \
    _Pragma("unroll") for (int it = 0; it < 8; ++it) {                          \
      __builtin_amdgcn_global_load_lds(                                         \
          (const __attribute__((address_space(1))) void*)(Wb + hb_ * 8192 + it * 1024 + tid * 8), \
          (__attribute__((address_space(3))) void*)(&Wl[b_][it * 1024 + tid * 8]), 16, 0, 0); \
      __builtin_amdgcn_global_load_lds(                                         \
          (const __attribute__((address_space(1))) void*)(KTb + hb_ * 8192 + it * 1024 + tid * 8), \
          (__attribute__((address_space(3))) void*)(&KTl[b_][it * 1024 + tid * 8]), 16, 0, 0); \
      __builtin_amdgcn_global_load_lds(                                         \
          (const __attribute__((address_space(1))) void*)(Qgb + hb_ * 8192 + it * 1024 + tid * 8), \
          (__attribute__((address_space(3))) void*)(&Qgl[b_][it * 1024 + tid * 8]), 16, 0, 0); \
      if (it < 4)                                                               \
        __builtin_amdgcn_global_load_lds(                                       \
            (const __attribute__((address_space(1))) void*)(Bb + hb_ * 4096 + it * 1024 + tid * 8), \
            (__attribute__((address_space(3))) void*)(&Bl[b_][it * 1024 + tid * 8]), 16, 0, 0); \
    }                                                                           \
  } while (0)
#define UPREF(c_) do {                                                          \
    const float* up_ = Ug + ((size_t)(c_) * 32 + vh) * 64 * 128 + cg + l15;     \
    _Pragma("unroll") for (int m_ = 0; m_ < 4; ++m_)                            \
      _Pragma("unroll") for (int r_ = 0; r_ < 4; ++r_)                          \
        ubuf[m_][r_] = up_[(size_t)(m_ * 16 + l4 * 4 + r_) * 128];              \
  } while (0)

  STAGE(0, 0);
  UPREF(0);
  __syncthreads();
  int buf = 0;
  for (int ch = 0; ch < NCHUNK; ++ch) {
    if (ch + 1 < NCHUNK) STAGE(buf ^ 1, ch + 1);
    f32x4 acc_d[4];
#pragma unroll
    for (int m = 0; m < 4; ++m) {
      f32x4 t;
      t[0] = ubuf[m][0]; t[1] = ubuf[m][1]; t[2] = ubuf[m][2]; t[3] = ubuf[m][3];
      acc_d[m] = t;
    }
    if (ch + 1 < NCHUNK) UPREF(ch + 1);
    // op1: delta = U + (-W) @ S
#pragma unroll
    for (int t = 0; t < 4; ++t) {
      const bf16x8 bS = *reinterpret_cast<const bf16x8*>(
          &Sop[w][l15 * 128 + ((t * 32 + l4 * 8) ^ swz)]);
#pragma unroll
      for (int m = 0; m < 4; ++m) {
        const bf16x8 aW = *reinterpret_cast<const bf16x8*>(
            &Wl[buf][(m * 16 + l15) * 128 + ((t * 32 + l4 * 8) ^ swz)]);
        acc_d[m] = __builtin_amdgcn_mfma_f32_16x16x32_bf16(aW, bS, acc_d[m], 0, 0, 0);
      }
    }
#pragma unroll
    for (int m = 0; m < 4; ++m)
      *reinterpret_cast<ushort4*>(&dLs[w][l15 * 64 + ((m * 16 + l4 * 4) ^ swz)]) =
          pack4(acc_d[m]);
    // opO: o = γq @ S + B @ δ
    f32x4 acc_o[4] = {};
#pragma unroll
    for (int t = 0; t < 4; ++t) {
      const bf16x8 bS = *reinterpret_cast<const bf16x8*>(
          &Sop[w][l15 * 128 + ((t * 32 + l4 * 8) ^ swz)]);
#pragma unroll
      for (int m = 0; m < 4; ++m) {
        const bf16x8 aQ = *reinterpret_cast<const bf16x8*>(
            &Qgl[buf][(m * 16 + l15) * 128 + ((t * 32 + l4 * 8) ^ swz)]);
        acc_o[m] = __builtin_amdgcn_mfma_f32_16x16x32_bf16(aQ, bS, acc_o[m], 0, 0, 0);
      }
    }
#pragma unroll
    for (int t2 = 0; t2 < 2; ++t2) {
      const bf16x8 bD = *reinterpret_cast<const bf16x8*>(
          &dLs[w][l15 * 64 + ((t2 * 32 + l4 * 8) ^ swz)]);
#pragma unroll
      for (int m = 0; m < 4; ++m) {
        const bf16x8 aB = *reinterpret_cast<const bf16x8*>(
            &Bl[buf][(m * 16 + l15) * 64 + ((t2 * 32 + l4 * 8) ^ swz)]);
        acc_o[m] = __builtin_amdgcn_mfma_f32_16x16x32_bf16(aB, bD, acc_o[m], 0, 0, 0);
      }
    }
    float* ob = Og + (size_t)(ch * 64) * 4096 + (size_t)vh * 128 + cg + l15;
#pragma unroll
    for (int m = 0; m < 4; ++m)
#pragma unroll
      for (int r = 0; r < 4; ++r)
        ob[(size_t)(m * 16 + l4 * 4 + r) * 4096] = acc_o[m][r];
    // op3: S = ge*S + Kᵀλ @ δ
    const float ge = gendg[ch * 32 + vh];
#pragma unroll
    for (int f = 0; f < 8; ++f) {
      accS[f][0] *= ge; accS[f][1] *= ge; accS[f][2] *= ge; accS[f][3] *= ge;
    }
#pragma unroll
    for (int t2 = 0; t2 < 2; ++t2) {
      const bf16x8 bD = *reinterpret_cast<const bf16x8*>(
          &dLs[w][l15 * 64 + ((t2 * 32 + l4 * 8) ^ swz)]);
#pragma unroll
      for (int f = 0; f < 8; ++f) {
        const bf16x8 aK = *reinterpret_cast<const bf16x8*>(
            &KTl[buf][(f * 16 + l15) * 64 + ((t2 * 32 + l4 * 8) ^ swz)]);
        accS[f] = __builtin_amdgcn_mfma_f32_16x16x32_bf16(aK, bD, accS[f], 0, 0, 0);
      }
    }
#pragma unroll
    for (int f = 0; f < 8; ++f)
      *reinterpret_cast<ushort4*>(&Sop[w][l15 * 128 + ((f * 16 + l4 * 4) ^ swz)]) =
          pack4(accS[f]);
    __syncthreads();
    buf ^= 1;
  }
#undef STAGE
#undef UPREF
}

// ------- gated = rmsnorm(o * silu(z)) * norm_w, emitted as bf16 --------------
__global__ void gate_norm(const float* __restrict__ O,
                          const float* __restrict__ qkvz,
                          const float* __restrict__ norm_w,
                          __hip_bfloat16* __restrict__ G) {
  const int vh = blockIdx.x, t = blockIdx.y, l = threadIdx.x;  // 64 threads
  const size_t ob = (size_t)t * 4096 + vh * 128;
  const size_t zb = (size_t)t * NQKVZ + (vh >> 1) * 768 + 512 + (vh & 1) * 128;
  const float o0 = O[ob + l], o1 = O[ob + l + 64];
  const float z0 = qkvz[zb + l], z1 = qkvz[zb + l + 64];
  const float g0 = o0 * z0 / (1.f + expf(-z0));
  const float g1 = o1 * z1 / (1.f + expf(-z1));
  float ss = g0 * g0 + g1 * g1;
#pragma unroll
  for (int off = 32; off; off >>= 1) ss += __shfl_xor(ss, off);
  const float rr = rsqrtf(ss * (1.f / 128.f) + 1e-6f);
  G[ob + l] = __float2bfloat16(g0 * rr * norm_w[l]);
  G[ob + l + 64] = __float2bfloat16(g1 * rr * norm_w[l + 64]);
}

extern "C" void kernel_launch(void* const* d_in, const int* in_sizes, int n_in,
                              void* d_out, int out_size, void* d_ws, size_t ws_size,
                              hipStream_t stream) {
  const float* X = (const float*)d_in[0];
  const float* W_qkvz = (const float*)d_in[1];
  const float* W_ba = (const float*)d_in[2];
  const float* conv_w = (const float*)d_in[3];
  const float* dt_bias = (const float*)d_in[4];
  const float* A_log = (const float*)d_in[5];
  const float* norm_w = (const float*)d_in[6];
  const float* W_out = (const float*)d_in[7];
  float* out = (float*)d_out;

  float* ws = (float*)d_ws;
  float* qkvz = ws;                                // 12,582,912 f
  float* P = qkvz + (size_t)T_LEN * NQKVZ;         //    262,144 f (ba partials)
  float* QK = P + 262144;                          //  4,194,304 f
  float* V = QK + (size_t)T_LEN * 4096;            //  4,194,304 f
  float* U = V + (size_t)T_LEN * 4096;             //  4,194,304 f
  float* Wb_f = U + (size_t)NCHUNK * 32 * 64 * 128;//  2,097,152 f (bf16 x 4.19M)
  float* KT_f = Wb_f + 2097152;                    //  2,097,152 f
  float* Qg_f = KT_f + 2097152;                    //  2,097,152 f
  float* Bb_f = Qg_f + 2097152;                    //  1,048,576 f (bf16 x 2.10M)
  float* gg = Bb_f + 1048576;                      //     32,768 f
  float* bet = gg + 32768;                         //     32,768 f
  float* gend = bet + 32768;                       //        512 f

  __hip_bfloat16* Wb = (__hip_bfloat16*)Wb_f;
  __hip_bfloat16* KTb = (__hip_bfloat16*)KT_f;
  __hip_bfloat16* Qgb = (__hip_bfloat16*)Qg_f;
  __hip_bfloat16* Bb = (__hip_bfloat16*)Bb_f;
  // lifetime aliases:
  __hip_bfloat16* Wqkvz_t = (__hip_bfloat16*)V;    // spans V+U+Wb+KT (dead after 1st gemm)
  __hip_bfloat16* Xb = (__hip_bfloat16*)Qg_f;      // dead after 1st gemm
  __hip_bfloat16* Gb = (__hip_bfloat16*)Bb_f;      // Bb dead after phaseB
  __hip_bfloat16* Wout_t = (__hip_bfloat16*)qkvz;  // qkvz dead after gate_norm
  float* O = V;                                    // V dead after phase1
  float* Pout = U;                                 // U dead after phaseB; 2x 2,097,152 f

  cast_bf16<<<dim3(T_LEN * 2048 / 4 / 256), 256, 0, stream>>>(X, Xb, T_LEN * 2048);
  transpose_cast<<<dim3(NQKVZ / 32, 2048 / 32), 256, 0, stream>>>(W_qkvz, Wqkvz_t, 2048, NQKVZ);
  gemm_bf16<<<dim3(NQKVZ / 128, T_LEN / 128, 1), 256, 0, stream>>>(Xb, Wqkvz_t, qkvz, T_LEN, NQKVZ, 2048, 2048);
  ba_gemm<<<dim3(64, 4), 256, 0, stream>>>(X, W_ba, P);
  conv_silu<<<dim3(CDIM / 256, T_LEN / 32), 256, 0, stream>>>(qkvz, conv_w, QK, V);
  l2norm_qk<<<dim3(HK_N, T_LEN), 64, 0, stream>>>(QK);
  compute_gb<<<dim3(T_LEN * 32 / 256), 256, 0, stream>>>(P, dt_bias, A_log, gg, bet);
  phase1<<<dim3(HV_N, NCHUNK), 256, 0, stream>>>(QK, V, gg, bet, U, Wb, KTb, Qgb, Bb, gend);
  phaseB<<<dim3(HV_N, 4), 128, 0, stream>>>(U, Wb, KTb, Qgb, Bb, gend, O);
  gate_norm<<<dim3(HV_N, T_LEN), 64, 0, stream>>>(O, qkvz, norm_w, Gb);
  transpose_cast<<<dim3(2048 / 32, 4096 / 32), 256, 0, stream>>>(W_out, Wout_t, 4096, 2048);
  gemm_bf16<<<dim3(2048 / 128, T_LEN / 128, 2), 256, 0, stream>>>(Gb, Wout_t, Pout, T_LEN, 2048, 2048, 4096);
  add2<<<dim3(T_LEN * 2048 / 4 / 256), 256, 0, stream>>>(Pout, out, T_LEN * 2048);
}

// Round 9
// 304.011 us; speedup vs baseline: 14.5594x; 1.0519x over previous
//
#include <hip/hip_runtime.h>
#include <hip/hip_bf16.h>
#include <math.h>

// Qwen3Next GatedDeltaNet — round 8: gemm_bf16 double-buffered with
// issue-early staging (T3 minimum 2-phase: prefetch next K-tile before
// compute so the pre-barrier vmcnt(0) drain lands after MFMA), out-GEMM
// split-K z=4 (+add4), transpose_cast ushort4 writes.

#define T_LEN 1024
#define HK_N 16
#define HV_N 32
#define NQKVZ 12288
#define CDIM 8192
#define CHUNK 64
#define NCHUNK 16

typedef __bf16 bf16x8 __attribute__((ext_vector_type(8)));
typedef float f32x4 __attribute__((ext_vector_type(4)));

__device__ __forceinline__ ushort4 pack4(const f32x4 v) {
  ushort4 o;
  o.x = __bfloat16_as_ushort(__float2bfloat16(v[0]));
  o.y = __bfloat16_as_ushort(__float2bfloat16(v[1]));
  o.z = __bfloat16_as_ushort(__float2bfloat16(v[2]));
  o.w = __bfloat16_as_ushort(__float2bfloat16(v[3]));
  return o;
}

// ------- bf16 MFMA GEMM: C[M,N] (z-partials) = A[M,ldk] @ B[N,ldk]^T ---------
// BK=64, T2 swizzle (pre-swizzled global source, XOR'd ds_read), double-
// buffered LDS with next-tile prefetch issued BEFORE compute.
__global__ __launch_bounds__(256) void gemm_bf16(const __hip_bfloat16* __restrict__ A,
                                                 const __hip_bfloat16* __restrict__ B,
                                                 float* __restrict__ C,
                                                 int M, int N, int Klen, int ldk) {
  __shared__ __align__(16) __hip_bfloat16 As[2][128 * 64];
  __shared__ __align__(16) __hip_bfloat16 Bs[2][128 * 64];
  const int tid = threadIdx.x;
  const int wid = tid >> 6, lane = tid & 63;
  const int wr = wid >> 1, wc = wid & 1;
  const int m0 = blockIdx.y * 128, n0 = blockIdx.x * 128;
  const size_t kbase = (size_t)blockIdx.z * Klen;
  float* Cz = C + (size_t)blockIdx.z * M * N;
  const int lrow = lane & 15, lk = lane >> 4;
  const int rswz = (lrow & 7) * 8;
  f32x4 acc[4][4] = {};

#define GSTAGE(b_, k0_) do {                                                    \
    _Pragma("unroll") for (int it = 0; it < 4; ++it) {                          \
      const int c_ = it * 256 + tid;                                            \
      const int row_ = c_ >> 3;                                                 \
      const int col8_ = ((c_ & 7) ^ (row_ & 7)) * 8;                            \
      const __hip_bfloat16* ga_ = A + (size_t)(m0 + row_) * ldk + kbase + (k0_) + col8_; \
      const __hip_bfloat16* gb_ = B + (size_t)(n0 + row_) * ldk + kbase + (k0_) + col8_; \
      __builtin_amdgcn_global_load_lds(                                         \
          (const __attribute__((address_space(1))) void*)ga_,                   \
          (__attribute__((address_space(3))) void*)(&As[b_][it * 2048 + tid * 8]), 16, 0, 0); \
      __builtin_amdgcn_global_load_lds(                                         \
          (const __attribute__((address_space(1))) void*)gb_,                   \
          (__attribute__((address_space(3))) void*)(&Bs[b_][it * 2048 + tid * 8]), 16, 0, 0); \
    }                                                                           \
  } while (0)

  GSTAGE(0, 0);
  __syncthreads();
  int buf = 0;
  for (int k0 = 0; k0 < Klen; k0 += 64) {
    if (k0 + 64 < Klen) GSTAGE(buf ^ 1, k0 + 64);  // prefetch BEFORE compute
#pragma unroll
    for (int kk = 0; kk < 2; ++kk) {
      bf16x8 af[4], bfv[4];
#pragma unroll
      for (int m = 0; m < 4; ++m)
        af[m] = *reinterpret_cast<const bf16x8*>(
            &As[buf][(wr * 64 + m * 16 + lrow) * 64 + ((kk * 32 + lk * 8) ^ rswz)]);
#pragma unroll
      for (int n = 0; n < 4; ++n)
        bfv[n] = *reinterpret_cast<const bf16x8*>(
            &Bs[buf][(wc * 64 + n * 16 + lrow) * 64 + ((kk * 32 + lk * 8) ^ rswz)]);
#pragma unroll
      for (int m = 0; m < 4; ++m)
#pragma unroll
        for (int n = 0; n < 4; ++n)
          acc[m][n] = __builtin_amdgcn_mfma_f32_16x16x32_bf16(af[m], bfv[n], acc[m][n], 0, 0, 0);
    }
    __syncthreads();  // compiler drains vmcnt(0) here — after MFMA
    buf ^= 1;
  }
#undef GSTAGE
#pragma unroll
  for (int m = 0; m < 4; ++m)
#pragma unroll
    for (int n = 0; n < 4; ++n)
#pragma unroll
      for (int r = 0; r < 4; ++r)
        Cz[(size_t)(m0 + wr * 64 + m * 16 + lk * 4 + r) * N + n0 + wc * 64 + n * 16 + lrow] =
            acc[m][n][r];
}

// ---------------- out = sum of 4 K-slice partials ----------------------------
__global__ void add4(const float* __restrict__ P, float* __restrict__ out, int n) {
  const int i = (blockIdx.x * 256 + threadIdx.x) * 4;
  if (i < n) {
    const float4 a = *reinterpret_cast<const float4*>(P + i);
    const float4 b = *reinterpret_cast<const float4*>(P + n + i);
    const float4 c = *reinterpret_cast<const float4*>(P + 2 * n + i);
    const float4 d = *reinterpret_cast<const float4*>(P + 3 * n + i);
    *reinterpret_cast<float4*>(out + i) =
        make_float4((a.x + b.x) + (c.x + d.x), (a.y + b.y) + (c.y + d.y),
                    (a.z + b.z) + (c.z + d.z), (a.w + b.w) + (c.w + d.w));
  }
}

// ---------------- fp32 -> bf16 elementwise cast ------------------------------
__global__ void cast_bf16(const float* __restrict__ src,
                          __hip_bfloat16* __restrict__ dst, int n) {
  const int i = (blockIdx.x * 256 + threadIdx.x) * 4;
  if (i < n) {
    const float4 v = *reinterpret_cast<const float4*>(src + i);
    ushort4 o;
    o.x = __bfloat16_as_ushort(__float2bfloat16(v.x));
    o.y = __bfloat16_as_ushort(__float2bfloat16(v.y));
    o.z = __bfloat16_as_ushort(__float2bfloat16(v.z));
    o.w = __bfloat16_as_ushort(__float2bfloat16(v.w));
    *reinterpret_cast<ushort4*>((void*)(dst + i)) = o;
  }
}

// ---------------- fp32 [K,N] -> bf16 [N,K] tiled transpose-cast --------------
// ushort4 writes (4 k-values per thread) for full-width stores.
__global__ __launch_bounds__(256) void transpose_cast(const float* __restrict__ src,
                                                      __hip_bfloat16* __restrict__ dst,
                                                      int K, int N) {
  __shared__ float tl[32][33];
  const int n0 = blockIdx.x * 32, k0 = blockIdx.y * 32;
  const int tx = threadIdx.x & 31, ty = threadIdx.x >> 5;  // ty 0..7
#pragma unroll
  for (int i = 0; i < 4; ++i)
    tl[ty + 8 * i][tx] = src[(size_t)(k0 + ty + 8 * i) * N + n0 + tx];
  __syncthreads();
  const int wtx = threadIdx.x & 7, wty = threadIdx.x >> 3;  // wty 0..31 = n
  ushort4 o;
  o.x = __bfloat16_as_ushort(__float2bfloat16(tl[wtx * 4 + 0][wty]));
  o.y = __bfloat16_as_ushort(__float2bfloat16(tl[wtx * 4 + 1][wty]));
  o.z = __bfloat16_as_ushort(__float2bfloat16(tl[wtx * 4 + 2][wty]));
  o.w = __bfloat16_as_ushort(__float2bfloat16(tl[wtx * 4 + 3][wty]));
  *reinterpret_cast<ushort4*>((void*)&dst[(size_t)(n0 + wty) * K + k0 + wtx * 4]) = o;
}

// --------- split-K ba GEMM: X[1024,2048] @ Wba[2048,64] -> P[4][1024][64] ----
__global__ __launch_bounds__(256) void ba_gemm(const float* __restrict__ X,
                                               const float* __restrict__ Wba,
                                               float* __restrict__ P) {
  __shared__ __align__(16) float Xs[16][512];
  const int tt = blockIdx.x, ks = blockIdx.y;
  const int tid = threadIdx.x;
  const int c = tid & 63, r4 = tid >> 6;
  const float* xsrc = X + (size_t)(tt * 16) * 2048 + ks * 512;
#pragma unroll
  for (int u = 0; u < 8; ++u) {
    const int flat = (u * 256 + tid) * 4;
    const int r = flat >> 9, k = flat & 511;
    *reinterpret_cast<float4*>(&Xs[r][k]) =
        *reinterpret_cast<const float4*>(&xsrc[(size_t)r * 2048 + k]);
  }
  __syncthreads();
  float acc[4] = {};
  const float* wp = Wba + (size_t)(ks * 512) * 64 + c;
  for (int k = 0; k < 512; k += 8) {
    float w[8];
#pragma unroll
    for (int u = 0; u < 8; ++u) w[u] = wp[(size_t)(k + u) * 64];
#pragma unroll
    for (int u = 0; u < 8; ++u)
#pragma unroll
      for (int i = 0; i < 4; ++i)
        acc[i] = fmaf(Xs[r4 * 4 + i][k + u], w[u], acc[i]);
  }
  float* pp = P + ((size_t)ks * 1024 + tt * 16 + r4 * 4) * 64 + c;
#pragma unroll
  for (int i = 0; i < 4; ++i) pp[(size_t)i * 64] = acc[i];
}

// ------ causal depthwise conv (K=4) + silu, rolling-window over t ------------
__global__ void conv_silu(const float* __restrict__ qkvz,
                          const float* __restrict__ conv_w,
                          float* __restrict__ QK, float* __restrict__ V) {
  const int c = blockIdx.x * 256 + threadIdx.x;
  const int t0 = blockIdx.y * 32;
  int col;
  if (c < 2048) {
    col = (c >> 7) * 768 + (c & 127);
  } else if (c < 4096) {
    const int c2 = c - 2048;
    col = (c2 >> 7) * 768 + 128 + (c2 & 127);
  } else {
    const int c2 = c - 4096;
    const int vh = c2 >> 7;
    col = (vh >> 1) * 768 + 256 + (vh & 1) * 128 + (c2 & 127);
  }
  const float4 w = *reinterpret_cast<const float4*>(&conv_w[c * 4]);
  float x0, x1, x2;
  if (t0 == 0) {
    x0 = 0.f; x1 = 0.f; x2 = 0.f;
  } else {
    x0 = qkvz[(size_t)(t0 - 3) * NQKVZ + col];
    x1 = qkvz[(size_t)(t0 - 2) * NQKVZ + col];
    x2 = qkvz[(size_t)(t0 - 1) * NQKVZ + col];
  }
#pragma unroll 4
  for (int tt = 0; tt < 32; ++tt) {
    const int t = t0 + tt;
    const float x3 = qkvz[(size_t)t * NQKVZ + col];
    float acc = x0 * w.x;
    acc = fmaf(x1, w.y, acc);
    acc = fmaf(x2, w.z, acc);
    acc = fmaf(x3, w.w, acc);
    const float y = acc / (1.f + expf(-acc));  // silu
    if (c < 4096) QK[(size_t)t * 4096 + c] = y;
    else          V[(size_t)t * 4096 + (c - 4096)] = y;
    x0 = x1; x1 = x2; x2 = x3;
  }
}

// ---------------- l2norm over DK for q and k (per t, per k-head) -------------
__global__ void l2norm_qk(float* __restrict__ QK) {
  const int h = blockIdx.x, t = blockIdx.y, l = threadIdx.x;  // 64 threads
  const size_t qb = (size_t)t * 4096 + h * 128;
  const size_t kb = qb + 2048;
  float q0 = QK[qb + l], q1 = QK[qb + l + 64];
  float k0 = QK[kb + l], k1 = QK[kb + l + 64];
  float sq = q0 * q0 + q1 * q1;
  float sk = k0 * k0 + k1 * k1;
#pragma unroll
  for (int off = 32; off; off >>= 1) {
    sq += __shfl_xor(sq, off);
    sk += __shfl_xor(sk, off);
  }
  const float rq = rsqrtf(sq + 1e-6f) * 0.08838834764831845f;  // * DK^-0.5
  const float rk = rsqrtf(sk + 1e-6f);
  QK[qb + l] = q0 * rq; QK[qb + l + 64] = q1 * rq;
  QK[kb + l] = k0 * rk; QK[kb + l + 64] = k1 * rk;
}

// ------ g/beta from split-K partials: sum 4 slices, then softplus/sigmoid ----
__global__ void compute_gb(const float* __restrict__ P,
                           const float* __restrict__ dt_bias,
                           const float* __restrict__ A_log,
                           float* __restrict__ gg, float* __restrict__ bet) {
  const int idx = blockIdx.x * 256 + threadIdx.x;  // t*32 + vh
  const int t = idx >> 5, vh = idx & 31;
  const int cb = (vh >> 1) * 4 + (vh & 1);
  float b = 0.f, a = 0.f;
#pragma unroll
  for (int s = 0; s < 4; ++s) {
    b += P[((size_t)s * 1024 + t) * 64 + cb];
    a += P[((size_t)s * 1024 + t) * 64 + cb + 2];
  }
  const float x = a + dt_bias[vh];
  const float sp = (x > 20.f) ? x : log1pf(expf(x));
  gg[idx] = -expf(A_log[vh]) * sp;
  bet[idx] = 1.f / (1.f + expf(-b));
}

// ---------------- phase 1: per (chunk, v-head) intra-chunk precompute --------
__global__ __launch_bounds__(256, 2) void phase1(
    const float* __restrict__ QK, const float* __restrict__ V,
    const float* __restrict__ g, const float* __restrict__ bet,
    float* __restrict__ U, __hip_bfloat16* __restrict__ Wb,
    __hip_bfloat16* __restrict__ KTb, __hip_bfloat16* __restrict__ Qgb,
    __hip_bfloat16* __restrict__ Bb, float* __restrict__ gend) {
  const int vh = blockIdx.x, ch = blockIdx.y, kh = vh >> 1;
  const int tid = threadIdx.x;
  const int t0 = ch * CHUNK;
  __shared__ __align__(16) float Kl[64][132];
  __shared__ float Al[64][65];
  __shared__ float bs[64], gams[64], bets[64], lams[64];

  const int row = tid >> 2;
  const size_t hb = (size_t)ch * 32 + vh;
  {
    const int cc = (tid & 3) * 32;
    const float* src = &QK[(size_t)(t0 + row) * 4096 + 2048 + kh * 128 + cc];
#pragma unroll
    for (int u = 0; u < 32; u += 4)
      *reinterpret_cast<float4*>(&Kl[row][cc + u]) =
          *reinterpret_cast<const float4*>(src + u);
  }
  if (tid < 64) {
    float b = g[(size_t)(t0 + tid) * 32 + vh];
#pragma unroll
    for (int off = 1; off < 64; off <<= 1) {
      const float o = __shfl_up(b, off);
      if (tid >= off) b += o;
    }
    const float b63 = __shfl(b, 63);
    const float ga = expf(b);
    bs[tid] = b;
    gams[tid] = ga;
    lams[tid] = expf(b63 - b);
    bets[tid] = bet[(size_t)(t0 + tid) * 32 + vh];
    if (tid == 63) gend[ch * 32 + vh] = ga;
  }
  __syncthreads();
  {
    const int i = tid & 63;
    const float li = lams[i];
    __hip_bfloat16* kt = &KTb[hb * 128 * 64];
    const int dbase = (tid >> 6) * 32;
#pragma unroll
    for (int dd = 0; dd < 32; ++dd) {
      const int d = dbase + dd;
      kt[(size_t)d * 64 + (i ^ ((d & 7) << 3))] = __float2bfloat16(li * Kl[i][d]);
    }
  }
  {
    const int j0 = (tid & 3) * 16;
    const float* qrow = &QK[(size_t)(t0 + row) * 4096 + kh * 128];
    const float gai = gams[row];
    __hip_bfloat16* qg = &Qgb[(hb * 64 + row) * 128];
    float accA[16], accB[16];
#pragma unroll
    for (int jj = 0; jj < 16; ++jj) { accA[jj] = 0.f; accB[jj] = 0.f; }
    for (int d = 0; d < 128; d += 4) {
      const float4 qi = *reinterpret_cast<const float4*>(qrow + d);
      const float4 ki = *reinterpret_cast<const float4*>(&Kl[row][d]);
      if ((d >> 5) == (tid & 3)) {
        ushort4 qq;
        qq.x = __bfloat16_as_ushort(__float2bfloat16(gai * qi.x));
        qq.y = __bfloat16_as_ushort(__float2bfloat16(gai * qi.y));
        qq.z = __bfloat16_as_ushort(__float2bfloat16(gai * qi.z));
        qq.w = __bfloat16_as_ushort(__float2bfloat16(gai * qi.w));
        *reinterpret_cast<ushort4*>(&qg[d ^ ((row & 7) << 3)]) = qq;
      }
#pragma unroll
      for (int jj = 0; jj < 16; ++jj) {
        const float4 kj = *reinterpret_cast<const float4*>(&Kl[j0 + jj][d]);
        accA[jj] += ki.x * kj.x + ki.y * kj.y + ki.z * kj.z + ki.w * kj.w;
        accB[jj] += qi.x * kj.x + qi.y * kj.y + qi.z * kj.z + qi.w * kj.w;
      }
    }
    const float bi = bets[row], bvi = bs[row];
    __hip_bfloat16* Bout = &Bb[(hb * 64 + row) * 64];
#pragma unroll
    for (int jj = 0; jj < 16; ++jj) {
      const int j = j0 + jj;
      const float dec = expf(bvi - bs[j]);
      Al[row][j] = (j < row) ? bi * dec * accA[jj] : 0.f;
      Bout[j ^ ((row & 7) << 3)] =
          __float2bfloat16((j <= row) ? dec * accB[jj] : 0.f);
    }
  }
  __syncthreads();
  // register-resident right-looking solve of (I+A) x = rhs, column tid.
  {
    const int cc = tid;
    float x[64];
    const bool isV = cc < 128;
    const float* src = isV ? &V[(size_t)t0 * 4096 + vh * 128 + cc]
                           : &QK[(size_t)t0 * 4096 + 2048 + kh * 128 + (cc - 128)];
#pragma unroll
    for (int i = 0; i < 64; ++i) {
      const float sc = isV ? bets[i] : bets[i] * gams[i];
      x[i] = sc * src[(size_t)i * 4096];
    }
#pragma unroll
    for (int j = 0; j < 63; ++j)
#pragma unroll
      for (int i = j + 1; i < 64; ++i)
        x[i] = fmaf(-Al[i][j], x[j], x[i]);
    if (isV) {
      float* dst = &U[hb * 64 * 128 + cc];
#pragma unroll
      for (int i = 0; i < 64; ++i) dst[(size_t)i * 128] = x[i];
    } else {
      const int d = cc - 128;
      __hip_bfloat16* dst = &Wb[hb * 64 * 128];
#pragma unroll
      for (int i = 0; i < 64; ++i)
        dst[(size_t)i * 128 + (d ^ ((i & 7) << 3))] = __float2bfloat16(-x[i]);
    }
  }
}

// ---------------- phaseB: serial MFMA state propagation ----------------------
__global__ __launch_bounds__(128) void phaseB(
    const float* __restrict__ Ug, const __hip_bfloat16* __restrict__ Wb,
    const __hip_bfloat16* __restrict__ KTb, const __hip_bfloat16* __restrict__ Qgb,
    const __hip_bfloat16* __restrict__ Bb, const float* __restrict__ gendg,
    float* __restrict__ Og) {
  const int vh = blockIdx.x, slice = blockIdx.y;
  const int tid = threadIdx.x, lane = tid & 63, w = tid >> 6;
  const int l15 = lane & 15, l4 = lane >> 4;
  const int cg = slice * 32 + w * 16;
  const int swz = (l15 & 7) << 3;

  __shared__ __hip_bfloat16 Wl[2][8192];
  __shared__ __hip_bfloat16 KTl[2][8192];
  __shared__ __hip_bfloat16 Qgl[2][8192];
  __shared__ __hip_bfloat16 Bl[2][4096];
  __shared__ __hip_bfloat16 Sop[2][2048];
  __shared__ __hip_bfloat16 dLs[2][1024];

  f32x4 accS[8] = {};
  for (int x = lane; x < 1024; x += 64) reinterpret_cast<uint*>(Sop[w])[x] = 0;

  float ubuf[4][4];
#define STAGE(b_, c_) do {                                                      \
    const size_t hb_ = ((size_t)(c_) * 32 + vh);                                \
    _Pragma("unroll") for (int it = 0; it < 8; ++it) {                          \
      __builtin_amdgcn_global_load_lds(                                         \
          (const __attribute__((address_space(1))) void*)(Wb + hb_ * 8192 + it * 1024 + tid * 8), \
          (__attribute__((address_space(3))) void*)(&Wl[b_][it * 1024 + tid * 8]), 16, 0, 0); \
      __builtin_amdgcn_global_load_lds(                                         \
          (const __attribute__((address_space(1))) void*)(KTb + hb_ * 8192 + it * 1024 + tid * 8), \
          (__attribute__((address_space(3))) void*)(&KTl[b_][it * 1024 + tid * 8]), 16, 0, 0); \
      __builtin_amdgcn_global_load_lds(                                         \
          (const __attribute__((address_space(1))) void*)(Qgb + hb_ * 8192 + it * 1024 + tid * 8), \
          (__attribute__((address_space(3))) void*)(&Qgl[b_][it * 1024 + tid * 8]), 16, 0, 0); \
      if (it < 4)                                                               \
        __builtin_amdgcn_global_load_lds(                                       \
            (const __attribute__((address_space(1))) void*)(Bb + hb_ * 4096 + it * 1024 + tid * 8), \
            (__attribute__((address_space(3))) void*)(&Bl[b_][it * 1024 + tid * 8]), 16, 0, 0); \
    }                                                                           \
  } while (0)
#define UPREF(c_) do {                                                          \
    const float* up_ = Ug + ((size_t)(c_) * 32 + vh) * 64 * 128 + cg + l15;     \
    _Pragma("unroll") for (int m_ = 0; m_ < 4; ++m_)                            \
      _Pragma("unroll") for (int r_ = 0; r_ < 4; ++r_)                          \
        ubuf[m_][r_] = up_[(size_t)(m_ * 16 + l4 * 4 + r_) * 128];              \
  } while (0)

  STAGE(0, 0);
  UPREF(0);
  __syncthreads();
  int buf = 0;
  for (int ch = 0; ch < NCHUNK; ++ch) {
    if (ch + 1 < NCHUNK) STAGE(buf ^ 1, ch + 1);
    f32x4 acc_d[4];
#pragma unroll
    for (int m = 0; m < 4; ++m) {
      f32x4 t;
      t[0] = ubuf[m][0]; t[1] = ubuf[m][1]; t[2] = ubuf[m][2]; t[3] = ubuf[m][3];
      acc_d[m] = t;
    }
    if (ch + 1 < NCHUNK) UPREF(ch + 1);
    // op1: delta = U + (-W) @ S
#pragma unroll
    for (int t = 0; t < 4; ++t) {
      const bf16x8 bS = *reinterpret_cast<const bf16x8*>(
          &Sop[w][l15 * 128 + ((t * 32 + l4 * 8) ^ swz)]);
#pragma unroll
      for (int m = 0; m < 4; ++m) {
        const bf16x8 aW = *reinterpret_cast<const bf16x8*>(
            &Wl[buf][(m * 16 + l15) * 128 + ((t * 32 + l4 * 8) ^ swz)]);
        acc_d[m] = __builtin_amdgcn_mfma_f32_16x16x32_bf16(aW, bS, acc_d[m], 0, 0, 0);
      }
    }
#pragma unroll
    for (int m = 0; m < 4; ++m)
      *reinterpret_cast<ushort4*>(&dLs[w][l15 * 64 + ((m * 16 + l4 * 4) ^ swz)]) =
          pack4(acc_d[m]);
    // opO: o = γq @ S + B @ δ
    f32x4 acc_o[4] = {};
#pragma unroll
    for (int t = 0; t < 4; ++t) {
      const bf16x8 bS = *reinterpret_cast<const bf16x8*>(
          &Sop[w][l15 * 128 + ((t * 32 + l4 * 8) ^ swz)]);
#pragma unroll
      for (int m = 0; m < 4; ++m) {
        const bf16x8 aQ = *reinterpret_cast<const bf16x8*>(
            &Qgl[buf][(m * 16 + l15) * 128 + ((t * 32 + l4 * 8) ^ swz)]);
        acc_o[m] = __builtin_amdgcn_mfma_f32_16x16x32_bf16(aQ, bS, acc_o[m], 0, 0, 0);
      }
    }
#pragma unroll
    for (int t2 = 0; t2 < 2; ++t2) {
      const bf16x8 bD = *reinterpret_cast<const bf16x8*>(
          &dLs[w][l15 * 64 + ((t2 * 32 + l4 * 8) ^ swz)]);
#pragma unroll
      for (int m = 0; m < 4; ++m) {
        const bf16x8 aB = *reinterpret_cast<const bf16x8*>(
            &Bl[buf][(m * 16 + l15) * 64 + ((t2 * 32 + l4 * 8) ^ swz)]);
        acc_o[m] = __builtin_amdgcn_mfma_f32_16x16x32_bf16(aB, bD, acc_o[m], 0, 0, 0);
      }
    }
    float* ob = Og + (size_t)(ch * 64) * 4096 + (size_t)vh * 128 + cg + l15;
#pragma unroll
    for (int m = 0; m < 4; ++m)
#pragma unroll
      for (int r = 0; r < 4; ++r)
        ob[(size_t)(m * 16 + l4 * 4 + r) * 4096] = acc_o[m][r];
    // op3: S = ge*S + Kᵀλ @ δ
    const float ge = gendg[ch * 32 + vh];
#pragma unroll
    for (int f = 0; f < 8; ++f) {
      accS[f][0] *= ge; accS[f][1] *= ge; accS[f][2] *= ge; accS[f][3] *= ge;
    }
#pragma unroll
    for (int t2 = 0; t2 < 2; ++t2) {
      const bf16x8 bD = *reinterpret_cast<const bf16x8*>(
          &dLs[w][l15 * 64 + ((t2 * 32 + l4 * 8) ^ swz)]);
#pragma unroll
      for (int f = 0; f < 8; ++f) {
        const bf16x8 aK = *reinterpret_cast<const bf16x8*>(
            &KTl[buf][(f * 16 + l15) * 64 + ((t2 * 32 + l4 * 8) ^ swz)]);
        accS[f] = __builtin_amdgcn_mfma_f32_16x16x32_bf16(aK, bD, accS[f], 0, 0, 0);
      }
    }
#pragma unroll
    for (int f = 0; f < 8; ++f)
      *reinterpret_cast<ushort4*>(&Sop[w][l15 * 128 + ((f * 16 + l4 * 4) ^ swz)]) =
          pack4(accS[f]);
    __syncthreads();
    buf ^= 1;
  }
#undef STAGE
#undef UPREF
}

// ------- gated = rmsnorm(o * silu(z)) * norm_w, emitted as bf16 --------------
__global__ void gate_norm(const float* __restrict__ O,
                          const float* __restrict__ qkvz,
                          const float* __restrict__ norm_w,
                          __hip_bfloat16* __restrict__ G) {
  const int vh = blockIdx.x, t = blockIdx.y, l = threadIdx.x;  // 64 threads
  const size_t ob = (size_t)t * 4096 + vh * 128;
  const size_t zb = (size_t)t * NQKVZ + (vh >> 1) * 768 + 512 + (vh & 1) * 128;
  const float o0 = O[ob + l], o1 = O[ob + l + 64];
  const float z0 = qkvz[zb + l], z1 = qkvz[zb + l + 64];
  const float g0 = o0 * z0 / (1.f + expf(-z0));
  const float g1 = o1 * z1 / (1.f + expf(-z1));
  float ss = g0 * g0 + g1 * g1;
#pragma unroll
  for (int off = 32; off; off >>= 1) ss += __shfl_xor(ss, off);
  const float rr = rsqrtf(ss * (1.f / 128.f) + 1e-6f);
  G[ob + l] = __float2bfloat16(g0 * rr * norm_w[l]);
  G[ob + l + 64] = __float2bfloat16(g1 * rr * norm_w[l + 64]);
}

extern "C" void kernel_launch(void* const* d_in, const int* in_sizes, int n_in,
                              void* d_out, int out_size, void* d_ws, size_t ws_size,
                              hipStream_t stream) {
  const float* X = (const float*)d_in[0];
  const float* W_qkvz = (const float*)d_in[1];
  const float* W_ba = (const float*)d_in[2];
  const float* conv_w = (const float*)d_in[3];
  const float* dt_bias = (const float*)d_in[4];
  const float* A_log = (const float*)d_in[5];
  const float* norm_w = (const float*)d_in[6];
  const float* W_out = (const float*)d_in[7];
  float* out = (float*)d_out;

  float* ws = (float*)d_ws;
  float* qkvz = ws;                                // 12,582,912 f
  float* P = qkvz + (size_t)T_LEN * NQKVZ;         //    262,144 f (ba partials)
  float* QK = P + 262144;                          //  4,194,304 f
  float* V = QK + (size_t)T_LEN * 4096;            //  4,194,304 f
  float* U = V + (size_t)T_LEN * 4096;             //  4,194,304 f
  float* Wb_f = U + (size_t)NCHUNK * 32 * 64 * 128;//  2,097,152 f (bf16 x 4.19M)
  float* KT_f = Wb_f + 2097152;                    //  2,097,152 f
  float* Qg_f = KT_f + 2097152;                    //  2,097,152 f
  float* Bb_f = Qg_f + 2097152;                    //  1,048,576 f (bf16 x 2.10M)
  float* gg = Bb_f + 1048576;                      //     32,768 f
  float* bet = gg + 32768;                         //     32,768 f
  float* gend = bet + 32768;                       //        512 f

  __hip_bfloat16* Wb = (__hip_bfloat16*)Wb_f;
  __hip_bfloat16* KTb = (__hip_bfloat16*)KT_f;
  __hip_bfloat16* Qgb = (__hip_bfloat16*)Qg_f;
  __hip_bfloat16* Bb = (__hip_bfloat16*)Bb_f;
  // lifetime aliases:
  __hip_bfloat16* Wqkvz_t = (__hip_bfloat16*)V;    // spans V+U+Wb+KT (dead after 1st gemm)
  __hip_bfloat16* Xb = (__hip_bfloat16*)Qg_f;      // dead after 1st gemm
  __hip_bfloat16* Gb = (__hip_bfloat16*)Bb_f;      // Bb dead after phaseB
  __hip_bfloat16* Wout_t = (__hip_bfloat16*)qkvz;  // qkvz dead after gate_norm
  float* O = V;                                    // V dead after phase1
  float* Pout = U;                                 // U+Wb+KT dead after phaseB: 8.38M f >= 4x2.10M

  cast_bf16<<<dim3(T_LEN * 2048 / 4 / 256), 256, 0, stream>>>(X, Xb, T_LEN * 2048);
  transpose_cast<<<dim3(NQKVZ / 32, 2048 / 32), 256, 0, stream>>>(W_qkvz, Wqkvz_t, 2048, NQKVZ);
  gemm_bf16<<<dim3(NQKVZ / 128, T_LEN / 128, 1), 256, 0, stream>>>(Xb, Wqkvz_t, qkvz, T_LEN, NQKVZ, 2048, 2048);
  ba_gemm<<<dim3(64, 4), 256, 0, stream>>>(X, W_ba, P);
  conv_silu<<<dim3(CDIM / 256, T_LEN / 32), 256, 0, stream>>>(qkvz, conv_w, QK, V);
  l2norm_qk<<<dim3(HK_N, T_LEN), 64, 0, stream>>>(QK);
  compute_gb<<<dim3(T_LEN * 32 / 256), 256, 0, stream>>>(P, dt_bias, A_log, gg, bet);
  phase1<<<dim3(HV_N, NCHUNK), 256, 0, stream>>>(QK, V, gg, bet, U, Wb, KTb, Qgb, Bb, gend);
  phaseB<<<dim3(HV_N, 4), 128, 0, stream>>>(U, Wb, KTb, Qgb, Bb, gend, O);
  gate_norm<<<dim3(HV_N, T_LEN), 64, 0, stream>>>(O, qkvz, norm_w, Gb);
  transpose_cast<<<dim3(2048 / 32, 4096 / 32), 256, 0, stream>>>(W_out, Wout_t, 4096, 2048);
  gemm_bf16<<<dim3(2048 / 128, T_LEN / 128, 4), 256, 0, stream>>>(Gb, Wout_t, Pout, T_LEN, 2048, 1024, 4096);
  add4<<<dim3(T_LEN * 2048 / 4 / 256), 256, 0, stream>>>(Pout, out, T_LEN * 2048);
}

// Round 10
// 295.221 us; speedup vs baseline: 14.9929x; 1.0298x over previous
//
#include <hip/hip_runtime.h>
#include <hip/hip_bf16.h>
#include <math.h>

// Qwen3Next GatedDeltaNet — round 9: gemm_bf16 with counted-vmcnt raw-barrier
// pipeline (T4: s_waitcnt vmcnt(8) + s_barrier instead of __syncthreads'
// vmcnt(0) drain — prefetched tile's loads stay in flight across the barrier).
// transpose_cast rewritten 64x64 float4-read / 16B-write.

#define T_LEN 1024
#define HK_N 16
#define HV_N 32
#define NQKVZ 12288
#define CDIM 8192
#define CHUNK 64
#define NCHUNK 16

typedef __bf16 bf16x8 __attribute__((ext_vector_type(8)));
typedef float f32x4 __attribute__((ext_vector_type(4)));

__device__ __forceinline__ ushort4 pack4(const f32x4 v) {
  ushort4 o;
  o.x = __bfloat16_as_ushort(__float2bfloat16(v[0]));
  o.y = __bfloat16_as_ushort(__float2bfloat16(v[1]));
  o.z = __bfloat16_as_ushort(__float2bfloat16(v[2]));
  o.w = __bfloat16_as_ushort(__float2bfloat16(v[3]));
  return o;
}

// ------- bf16 MFMA GEMM: C[M,N] (z-partials) = A[M,ldk] @ B[N,ldk]^T ---------
// BK=64, T2 swizzle, double-buffer, counted-vmcnt raw-barrier pipeline.
__global__ __launch_bounds__(256) void gemm_bf16(const __hip_bfloat16* __restrict__ A,
                                                 const __hip_bfloat16* __restrict__ B,
                                                 float* __restrict__ C,
                                                 int M, int N, int Klen, int ldk) {
  __shared__ __align__(16) __hip_bfloat16 As[2][128 * 64];
  __shared__ __align__(16) __hip_bfloat16 Bs[2][128 * 64];
  const int tid = threadIdx.x;
  const int wid = tid >> 6, lane = tid & 63;
  const int wr = wid >> 1, wc = wid & 1;
  const int m0 = blockIdx.y * 128, n0 = blockIdx.x * 128;
  const size_t kbase = (size_t)blockIdx.z * Klen;
  float* Cz = C + (size_t)blockIdx.z * M * N;
  const int lrow = lane & 15, lk = lane >> 4;
  const int rswz = (lrow & 7) * 8;
  f32x4 acc[4][4] = {};
  const int nk = Klen >> 6;

#define GSTAGE(b_, k0_) do {                                                    \
    _Pragma("unroll") for (int it = 0; it < 4; ++it) {                          \
      const int c_ = it * 256 + tid;                                            \
      const int row_ = c_ >> 3;                                                 \
      const int col8_ = ((c_ & 7) ^ (row_ & 7)) * 8;                            \
      const __hip_bfloat16* ga_ = A + (size_t)(m0 + row_) * ldk + kbase + (k0_) + col8_; \
      const __hip_bfloat16* gb_ = B + (size_t)(n0 + row_) * ldk + kbase + (k0_) + col8_; \
      __builtin_amdgcn_global_load_lds(                                         \
          (const __attribute__((address_space(1))) void*)ga_,                   \
          (__attribute__((address_space(3))) void*)(&As[b_][it * 2048 + tid * 8]), 16, 0, 0); \
      __builtin_amdgcn_global_load_lds(                                         \
          (const __attribute__((address_space(1))) void*)gb_,                   \
          (__attribute__((address_space(3))) void*)(&Bs[b_][it * 2048 + tid * 8]), 16, 0, 0); \
    }                                                                           \
  } while (0)

  GSTAGE(0, 0);
  int buf = 0;
  for (int k = 0; k < nk; ++k) {
    if (k + 1 < nk) {
      GSTAGE(buf ^ 1, (k + 1) << 6);                 // issue next tile's 8 loads
      asm volatile("s_waitcnt vmcnt(8)" ::: "memory");  // tile k done; k+1 in flight
    } else {
      asm volatile("s_waitcnt vmcnt(0)" ::: "memory");
    }
    __builtin_amdgcn_s_barrier();                    // collective: tile k ready
    __builtin_amdgcn_sched_barrier(0);
#pragma unroll
    for (int kk = 0; kk < 2; ++kk) {
      bf16x8 af[4], bfv[4];
#pragma unroll
      for (int m = 0; m < 4; ++m)
        af[m] = *reinterpret_cast<const bf16x8*>(
            &As[buf][(wr * 64 + m * 16 + lrow) * 64 + ((kk * 32 + lk * 8) ^ rswz)]);
#pragma unroll
      for (int n = 0; n < 4; ++n)
        bfv[n] = *reinterpret_cast<const bf16x8*>(
            &Bs[buf][(wc * 64 + n * 16 + lrow) * 64 + ((kk * 32 + lk * 8) ^ rswz)]);
#pragma unroll
      for (int m = 0; m < 4; ++m)
#pragma unroll
        for (int n = 0; n < 4; ++n)
          acc[m][n] = __builtin_amdgcn_mfma_f32_16x16x32_bf16(af[m], bfv[n], acc[m][n], 0, 0, 0);
    }
    __builtin_amdgcn_sched_barrier(0);
    __builtin_amdgcn_s_barrier();                    // readers done before overwrite
    buf ^= 1;
  }
#undef GSTAGE
#pragma unroll
  for (int m = 0; m < 4; ++m)
#pragma unroll
    for (int n = 0; n < 4; ++n)
#pragma unroll
      for (int r = 0; r < 4; ++r)
        Cz[(size_t)(m0 + wr * 64 + m * 16 + lk * 4 + r) * N + n0 + wc * 64 + n * 16 + lrow] =
            acc[m][n][r];
}

// ---------------- out = sum of 4 K-slice partials ----------------------------
__global__ void add4(const float* __restrict__ P, float* __restrict__ out, int n) {
  const int i = (blockIdx.x * 256 + threadIdx.x) * 4;
  if (i < n) {
    const float4 a = *reinterpret_cast<const float4*>(P + i);
    const float4 b = *reinterpret_cast<const float4*>(P + n + i);
    const float4 c = *reinterpret_cast<const float4*>(P + 2 * n + i);
    const float4 d = *reinterpret_cast<const float4*>(P + 3 * n + i);
    *reinterpret_cast<float4*>(out + i) =
        make_float4((a.x + b.x) + (c.x + d.x), (a.y + b.y) + (c.y + d.y),
                    (a.z + b.z) + (c.z + d.z), (a.w + b.w) + (c.w + d.w));
  }
}

// ---------------- fp32 -> bf16 elementwise cast ------------------------------
__global__ void cast_bf16(const float* __restrict__ src,
                          __hip_bfloat16* __restrict__ dst, int n) {
  const int i = (blockIdx.x * 256 + threadIdx.x) * 4;
  if (i < n) {
    const float4 v = *reinterpret_cast<const float4*>(src + i);
    ushort4 o;
    o.x = __bfloat16_as_ushort(__float2bfloat16(v.x));
    o.y = __bfloat16_as_ushort(__float2bfloat16(v.y));
    o.z = __bfloat16_as_ushort(__float2bfloat16(v.z));
    o.w = __bfloat16_as_ushort(__float2bfloat16(v.w));
    *reinterpret_cast<ushort4*>((void*)(dst + i)) = o;
  }
}

// ------- fp32 [K,N] -> bf16 [N,K], 64x64 tiles, float4 reads, 16B writes -----
__global__ __launch_bounds__(256) void transpose_cast(const float* __restrict__ src,
                                                      __hip_bfloat16* __restrict__ dst,
                                                      int K, int N) {
  __shared__ float tl[64][65];
  const int n0 = blockIdx.x * 64, k0 = blockIdx.y * 64;
  const int tid = threadIdx.x;
  const int rc = tid & 15, rr = tid >> 4;
#pragma unroll
  for (int i = 0; i < 4; ++i) {
    const int k = rr + 16 * i;
    const float4 v = *reinterpret_cast<const float4*>(&src[(size_t)(k0 + k) * N + n0 + rc * 4]);
    tl[k][rc * 4 + 0] = v.x;
    tl[k][rc * 4 + 1] = v.y;
    tl[k][rc * 4 + 2] = v.z;
    tl[k][rc * 4 + 3] = v.w;
  }
  __syncthreads();
  const int wcx = tid & 7, wry = tid >> 3;  // wry 0..31
#pragma unroll
  for (int i = 0; i < 2; ++i) {
    const int n = wry + 32 * i;
    uint u[8];
#pragma unroll
    for (int j = 0; j < 8; ++j)
      u[j] = __bfloat16_as_ushort(__float2bfloat16(tl[wcx * 8 + j][n]));
    uint4 o;
    o.x = u[0] | (u[1] << 16);
    o.y = u[2] | (u[3] << 16);
    o.z = u[4] | (u[5] << 16);
    o.w = u[6] | (u[7] << 16);
    *reinterpret_cast<uint4*>((void*)&dst[(size_t)(n0 + n) * K + k0 + wcx * 8]) = o;
  }
}

// --------- split-K ba GEMM: X[1024,2048] @ Wba[2048,64] -> P[4][1024][64] ----
__global__ __launch_bounds__(256) void ba_gemm(const float* __restrict__ X,
                                               const float* __restrict__ Wba,
                                               float* __restrict__ P) {
  __shared__ __align__(16) float Xs[16][512];
  const int tt = blockIdx.x, ks = blockIdx.y;
  const int tid = threadIdx.x;
  const int c = tid & 63, r4 = tid >> 6;
  const float* xsrc = X + (size_t)(tt * 16) * 2048 + ks * 512;
#pragma unroll
  for (int u = 0; u < 8; ++u) {
    const int flat = (u * 256 + tid) * 4;
    const int r = flat >> 9, k = flat & 511;
    *reinterpret_cast<float4*>(&Xs[r][k]) =
        *reinterpret_cast<const float4*>(&xsrc[(size_t)r * 2048 + k]);
  }
  __syncthreads();
  float acc[4] = {};
  const float* wp = Wba + (size_t)(ks * 512) * 64 + c;
  for (int k = 0; k < 512; k += 8) {
    float w[8];
#pragma unroll
    for (int u = 0; u < 8; ++u) w[u] = wp[(size_t)(k + u) * 64];
#pragma unroll
    for (int u = 0; u < 8; ++u)
#pragma unroll
      for (int i = 0; i < 4; ++i)
        acc[i] = fmaf(Xs[r4 * 4 + i][k + u], w[u], acc[i]);
  }
  float* pp = P + ((size_t)ks * 1024 + tt * 16 + r4 * 4) * 64 + c;
#pragma unroll
  for (int i = 0; i < 4; ++i) pp[(size_t)i * 64] = acc[i];
}

// ------ causal depthwise conv (K=4) + silu, rolling-window over t ------------
__global__ void conv_silu(const float* __restrict__ qkvz,
                          const float* __restrict__ conv_w,
                          float* __restrict__ QK, float* __restrict__ V) {
  const int c = blockIdx.x * 256 + threadIdx.x;
  const int t0 = blockIdx.y * 32;
  int col;
  if (c < 2048) {
    col = (c >> 7) * 768 + (c & 127);
  } else if (c < 4096) {
    const int c2 = c - 2048;
    col = (c2 >> 7) * 768 + 128 + (c2 & 127);
  } else {
    const int c2 = c - 4096;
    const int vh = c2 >> 7;
    col = (vh >> 1) * 768 + 256 + (vh & 1) * 128 + (c2 & 127);
  }
  const float4 w = *reinterpret_cast<const float4*>(&conv_w[c * 4]);
  float x0, x1, x2;
  if (t0 == 0) {
    x0 = 0.f; x1 = 0.f; x2 = 0.f;
  } else {
    x0 = qkvz[(size_t)(t0 - 3) * NQKVZ + col];
    x1 = qkvz[(size_t)(t0 - 2) * NQKVZ + col];
    x2 = qkvz[(size_t)(t0 - 1) * NQKVZ + col];
  }
#pragma unroll 4
  for (int tt = 0; tt < 32; ++tt) {
    const int t = t0 + tt;
    const float x3 = qkvz[(size_t)t * NQKVZ + col];
    float acc = x0 * w.x;
    acc = fmaf(x1, w.y, acc);
    acc = fmaf(x2, w.z, acc);
    acc = fmaf(x3, w.w, acc);
    const float y = acc / (1.f + expf(-acc));  // silu
    if (c < 4096) QK[(size_t)t * 4096 + c] = y;
    else          V[(size_t)t * 4096 + (c - 4096)] = y;
    x0 = x1; x1 = x2; x2 = x3;
  }
}

// ---------------- l2norm over DK for q and k (per t, per k-head) -------------
__global__ void l2norm_qk(float* __restrict__ QK) {
  const int h = blockIdx.x, t = blockIdx.y, l = threadIdx.x;  // 64 threads
  const size_t qb = (size_t)t * 4096 + h * 128;
  const size_t kb = qb + 2048;
  float q0 = QK[qb + l], q1 = QK[qb + l + 64];
  float k0 = QK[kb + l], k1 = QK[kb + l + 64];
  float sq = q0 * q0 + q1 * q1;
  float sk = k0 * k0 + k1 * k1;
#pragma unroll
  for (int off = 32; off; off >>= 1) {
    sq += __shfl_xor(sq, off);
    sk += __shfl_xor(sk, off);
  }
  const float rq = rsqrtf(sq + 1e-6f) * 0.08838834764831845f;  // * DK^-0.5
  const float rk = rsqrtf(sk + 1e-6f);
  QK[qb + l] = q0 * rq; QK[qb + l + 64] = q1 * rq;
  QK[kb + l] = k0 * rk; QK[kb + l + 64] = k1 * rk;
}

// ------ g/beta from split-K partials: sum 4 slices, then softplus/sigmoid ----
__global__ void compute_gb(const float* __restrict__ P,
                           const float* __restrict__ dt_bias,
                           const float* __restrict__ A_log,
                           float* __restrict__ gg, float* __restrict__ bet) {
  const int idx = blockIdx.x * 256 + threadIdx.x;  // t*32 + vh
  const int t = idx >> 5, vh = idx & 31;
  const int cb = (vh >> 1) * 4 + (vh & 1);
  float b = 0.f, a = 0.f;
#pragma unroll
  for (int s = 0; s < 4; ++s) {
    b += P[((size_t)s * 1024 + t) * 64 + cb];
    a += P[((size_t)s * 1024 + t) * 64 + cb + 2];
  }
  const float x = a + dt_bias[vh];
  const float sp = (x > 20.f) ? x : log1pf(expf(x));
  gg[idx] = -expf(A_log[vh]) * sp;
  bet[idx] = 1.f / (1.f + expf(-b));
}

// ---------------- phase 1: per (chunk, v-head) intra-chunk precompute --------
__global__ __launch_bounds__(256, 2) void phase1(
    const float* __restrict__ QK, const float* __restrict__ V,
    const float* __restrict__ g, const float* __restrict__ bet,
    float* __restrict__ U, __hip_bfloat16* __restrict__ Wb,
    __hip_bfloat16* __restrict__ KTb, __hip_bfloat16* __restrict__ Qgb,
    __hip_bfloat16* __restrict__ Bb, float* __restrict__ gend) {
  const int vh = blockIdx.x, ch = blockIdx.y, kh = vh >> 1;
  const int tid = threadIdx.x;
  const int t0 = ch * CHUNK;
  __shared__ __align__(16) float Kl[64][132];
  __shared__ float Al[64][65];
  __shared__ float bs[64], gams[64], bets[64], lams[64];

  const int row = tid >> 2;
  const size_t hb = (size_t)ch * 32 + vh;
  {
    const int cc = (tid & 3) * 32;
    const float* src = &QK[(size_t)(t0 + row) * 4096 + 2048 + kh * 128 + cc];
#pragma unroll
    for (int u = 0; u < 32; u += 4)
      *reinterpret_cast<float4*>(&Kl[row][cc + u]) =
          *reinterpret_cast<const float4*>(src + u);
  }
  if (tid < 64) {
    float b = g[(size_t)(t0 + tid) * 32 + vh];
#pragma unroll
    for (int off = 1; off < 64; off <<= 1) {
      const float o = __shfl_up(b, off);
      if (tid >= off) b += o;
    }
    const float b63 = __shfl(b, 63);
    const float ga = expf(b);
    bs[tid] = b;
    gams[tid] = ga;
    lams[tid] = expf(b63 - b);
    bets[tid] = bet[(size_t)(t0 + tid) * 32 + vh];
    if (tid == 63) gend[ch * 32 + vh] = ga;
  }
  __syncthreads();
  {
    const int i = tid & 63;
    const float li = lams[i];
    __hip_bfloat16* kt = &KTb[hb * 128 * 64];
    const int dbase = (tid >> 6) * 32;
#pragma unroll
    for (int dd = 0; dd < 32; ++dd) {
      const int d = dbase + dd;
      kt[(size_t)d * 64 + (i ^ ((d & 7) << 3))] = __float2bfloat16(li * Kl[i][d]);
    }
  }
  {
    const int j0 = (tid & 3) * 16;
    const float* qrow = &QK[(size_t)(t0 + row) * 4096 + kh * 128];
    const float gai = gams[row];
    __hip_bfloat16* qg = &Qgb[(hb * 64 + row) * 128];
    float accA[16], accB[16];
#pragma unroll
    for (int jj = 0; jj < 16; ++jj) { accA[jj] = 0.f; accB[jj] = 0.f; }
    for (int d = 0; d < 128; d += 4) {
      const float4 qi = *reinterpret_cast<const float4*>(qrow + d);
      const float4 ki = *reinterpret_cast<const float4*>(&Kl[row][d]);
      if ((d >> 5) == (tid & 3)) {
        ushort4 qq;
        qq.x = __bfloat16_as_ushort(__float2bfloat16(gai * qi.x));
        qq.y = __bfloat16_as_ushort(__float2bfloat16(gai * qi.y));
        qq.z = __bfloat16_as_ushort(__float2bfloat16(gai * qi.z));
        qq.w = __bfloat16_as_ushort(__float2bfloat16(gai * qi.w));
        *reinterpret_cast<ushort4*>(&qg[d ^ ((row & 7) << 3)]) = qq;
      }
#pragma unroll
      for (int jj = 0; jj < 16; ++jj) {
        const float4 kj = *reinterpret_cast<const float4*>(&Kl[j0 + jj][d]);
        accA[jj] += ki.x * kj.x + ki.y * kj.y + ki.z * kj.z + ki.w * kj.w;
        accB[jj] += qi.x * kj.x + qi.y * kj.y + qi.z * kj.z + qi.w * kj.w;
      }
    }
    const float bi = bets[row], bvi = bs[row];
    __hip_bfloat16* Bout = &Bb[(hb * 64 + row) * 64];
#pragma unroll
    for (int jj = 0; jj < 16; ++jj) {
      const int j = j0 + jj;
      const float dec = expf(bvi - bs[j]);
      Al[row][j] = (j < row) ? bi * dec * accA[jj] : 0.f;
      Bout[j ^ ((row & 7) << 3)] =
          __float2bfloat16((j <= row) ? dec * accB[jj] : 0.f);
    }
  }
  __syncthreads();
  // register-resident right-looking solve of (I+A) x = rhs, column tid.
  {
    const int cc = tid;
    float x[64];
    const bool isV = cc < 128;
    const float* src = isV ? &V[(size_t)t0 * 4096 + vh * 128 + cc]
                           : &QK[(size_t)t0 * 4096 + 2048 + kh * 128 + (cc - 128)];
#pragma unroll
    for (int i = 0; i < 64; ++i) {
      const float sc = isV ? bets[i] : bets[i] * gams[i];
      x[i] = sc * src[(size_t)i * 4096];
    }
#pragma unroll
    for (int j = 0; j < 63; ++j)
#pragma unroll
      for (int i = j + 1; i < 64; ++i)
        x[i] = fmaf(-Al[i][j], x[j], x[i]);
    if (isV) {
      float* dst = &U[hb * 64 * 128 + cc];
#pragma unroll
      for (int i = 0; i < 64; ++i) dst[(size_t)i * 128] = x[i];
    } else {
      const int d = cc - 128;
      __hip_bfloat16* dst = &Wb[hb * 64 * 128];
#pragma unroll
      for (int i = 0; i < 64; ++i)
        dst[(size_t)i * 128 + (d ^ ((i & 7) << 3))] = __float2bfloat16(-x[i]);
    }
  }
}

// ---------------- phaseB: serial MFMA state propagation ----------------------
__global__ __launch_bounds__(128) void phaseB(
    const float* __restrict__ Ug, const __hip_bfloat16* __restrict__ Wb,
    const __hip_bfloat16* __restrict__ KTb, const __hip_bfloat16* __restrict__ Qgb,
    const __hip_bfloat16* __restrict__ Bb, const float* __restrict__ gendg,
    float* __restrict__ Og) {
  const int vh = blockIdx.x, slice = blockIdx.y;
  const int tid = threadIdx.x, lane = tid & 63, w = tid >> 6;
  const int l15 = lane & 15, l4 = lane >> 4;
  const int cg = slice * 32 + w * 16;
  const int swz = (l15 & 7) << 3;

  __shared__ __hip_bfloat16 Wl[2][8192];
  __shared__ __hip_bfloat16 KTl[2][8192];
  __shared__ __hip_bfloat16 Qgl[2][8192];
  __shared__ __hip_bfloat16 Bl[2][4096];
  __shared__ __hip_bfloat16 Sop[2][2048];
  __shared__ __hip_bfloat16 dLs[2][1024];

  f32x4 accS[8] = {};
  for (int x = lane; x < 1024; x += 64) reinterpret_cast<uint*>(Sop[w])[x] = 0;

  float ubuf[4][4];
#define STAGE(b_, c_) do {                                                      \
    const size_t hb_ = ((size_t)(c_) * 32 + vh);                                \
    _Pragma("unroll") for (int it = 0; it < 8; ++it) {                          \
      __builtin_amdgcn_global_load_lds(                                         \
          (const __attribute__((address_space(1))) void*)(Wb + hb_ * 8192 + it * 1024 + tid * 8), \
          (__attribute__((address_space(3))) void*)(&Wl[b_][it * 1024 + tid * 8]), 16, 0, 0); \
      __builtin_amdgcn_global_load_lds(                                         \
          (const __attribute__((address_space(1))) void*)(KTb + hb_ * 8192 + it * 1024 + tid * 8), \
          (__attribute__((address_space(3))) void*)(&KTl[b_][it * 1024 + tid * 8]), 16, 0, 0); \
      __builtin_amdgcn_global_load_lds(                                         \
          (const __attribute__((address_space(1))) void*)(Qgb + hb_ * 8192 + it * 1024 + tid * 8), \
          (__attribute__((address_space(3))) void*)(&Qgl[b_][it * 1024 + tid * 8]), 16, 0, 0); \
      if (it < 4)                                                               \
        __builtin_amdgcn_global_load_lds(                                       \
            (const __attribute__((address_space(1))) void*)(Bb + hb_ * 4096 + it * 1024 + tid * 8), \
            (__attribute__((address_space(3))) void*)(&Bl[b_][it * 1024 + tid * 8]), 16, 0, 0); \
    }                                                                           \
  } while (0)
#define UPREF(c_) do {                                                          \
    const float* up_ = Ug + ((size_t)(c_) * 32 + vh) * 64 * 128 + cg + l15;     \
    _Pragma("unroll") for (int m_ = 0; m_ < 4; ++m_)                            \
      _Pragma("unroll") for (int r_ = 0; r_ < 4; ++r_)                          \
        ubuf[m_][r_] = up_[(size_t)(m_ * 16 + l4 * 4 + r_) * 128];              \
  } while (0)

  STAGE(0, 0);
  UPREF(0);
  __syncthreads();
  int buf = 0;
  for (int ch = 0; ch < NCHUNK; ++ch) {
    if (ch + 1 < NCHUNK) STAGE(buf ^ 1, ch + 1);
    f32x4 acc_d[4];
#pragma unroll
    for (int m = 0; m < 4; ++m) {
      f32x4 t;
      t[0] = ubuf[m][0]; t[1] = ubuf[m][1]; t[2] = ubuf[m][2]; t[3] = ubuf[m][3];
      acc_d[m] = t;
    }
    if (ch + 1 < NCHUNK) UPREF(ch + 1);
    // op1: delta = U + (-W) @ S
#pragma unroll
    for (int t = 0; t < 4; ++t) {
      const bf16x8 bS = *reinterpret_cast<const bf16x8*>(
          &Sop[w][l15 * 128 + ((t * 32 + l4 * 8) ^ swz)]);
#pragma unroll
      for (int m = 0; m < 4; ++m) {
        const bf16x8 aW = *reinterpret_cast<const bf16x8*>(
            &Wl[buf][(m * 16 + l15) * 128 + ((t * 32 + l4 * 8) ^ swz)]);
        acc_d[m] = __builtin_amdgcn_mfma_f32_16x16x32_bf16(aW, bS, acc_d[m], 0, 0, 0);
      }
    }
#pragma unroll
    for (int m = 0; m < 4; ++m)
      *reinterpret_cast<ushort4*>(&dLs[w][l15 * 64 + ((m * 16 + l4 * 4) ^ swz)]) =
          pack4(acc_d[m]);
    // opO: o = γq @ S + B @ δ
    f32x4 acc_o[4] = {};
#pragma unroll
    for (int t = 0; t < 4; ++t) {
      const bf16x8 bS = *reinterpret_cast<const bf16x8*>(
          &Sop[w][l15 * 128 + ((t * 32 + l4 * 8) ^ swz)]);
#pragma unroll
      for (int m = 0; m < 4; ++m) {
        const bf16x8 aQ = *reinterpret_cast<const bf16x8*>(
            &Qgl[buf][(m * 16 + l15) * 128 + ((t * 32 + l4 * 8) ^ swz)]);
        acc_o[m] = __builtin_amdgcn_mfma_f32_16x16x32_bf16(aQ, bS, acc_o[m], 0, 0, 0);
      }
    }
#pragma unroll
    for (int t2 = 0; t2 < 2; ++t2) {
      const bf16x8 bD = *reinterpret_cast<const bf16x8*>(
          &dLs[w][l15 * 64 + ((t2 * 32 + l4 * 8) ^ swz)]);
#pragma unroll
      for (int m = 0; m < 4; ++m) {
        const bf16x8 aB = *reinterpret_cast<const bf16x8*>(
            &Bl[buf][(m * 16 + l15) * 64 + ((t2 * 32 + l4 * 8) ^ swz)]);
        acc_o[m] = __builtin_amdgcn_mfma_f32_16x16x32_bf16(aB, bD, acc_o[m], 0, 0, 0);
      }
    }
    float* ob = Og + (size_t)(ch * 64) * 4096 + (size_t)vh * 128 + cg + l15;
#pragma unroll
    for (int m = 0; m < 4; ++m)
#pragma unroll
      for (int r = 0; r < 4; ++r)
        ob[(size_t)(m * 16 + l4 * 4 + r) * 4096] = acc_o[m][r];
    // op3: S = ge*S + Kᵀλ @ δ
    const float ge = gendg[ch * 32 + vh];
#pragma unroll
    for (int f = 0; f < 8; ++f) {
      accS[f][0] *= ge; accS[f][1] *= ge; accS[f][2] *= ge; accS[f][3] *= ge;
    }
#pragma unroll
    for (int t2 = 0; t2 < 2; ++t2) {
      const bf16x8 bD = *reinterpret_cast<const bf16x8*>(
          &dLs[w][l15 * 64 + ((t2 * 32 + l4 * 8) ^ swz)]);
#pragma unroll
      for (int f = 0; f < 8; ++f) {
        const bf16x8 aK = *reinterpret_cast<const bf16x8*>(
            &KTl[buf][(f * 16 + l15) * 64 + ((t2 * 32 + l4 * 8) ^ swz)]);
        accS[f] = __builtin_amdgcn_mfma_f32_16x16x32_bf16(aK, bD, accS[f], 0, 0, 0);
      }
    }
#pragma unroll
    for (int f = 0; f < 8; ++f)
      *reinterpret_cast<ushort4*>(&Sop[w][l15 * 128 + ((f * 16 + l4 * 4) ^ swz)]) =
          pack4(accS[f]);
    __syncthreads();
    buf ^= 1;
  }
#undef STAGE
#undef UPREF
}

// ------- gated = rmsnorm(o * silu(z)) * norm_w, emitted as bf16 --------------
__global__ void gate_norm(const float* __restrict__ O,
                          const float* __restrict__ qkvz,
                          const float* __restrict__ norm_w,
                          __hip_bfloat16* __restrict__ G) {
  const int vh = blockIdx.x, t = blockIdx.y, l = threadIdx.x;  // 64 threads
  const size_t ob = (size_t)t * 4096 + vh * 128;
  const size_t zb = (size_t)t * NQKVZ + (vh >> 1) * 768 + 512 + (vh & 1) * 128;
  const float o0 = O[ob + l], o1 = O[ob + l + 64];
  const float z0 = qkvz[zb + l], z1 = qkvz[zb + l + 64];
  const float g0 = o0 * z0 / (1.f + expf(-z0));
  const float g1 = o1 * z1 / (1.f + expf(-z1));
  float ss = g0 * g0 + g1 * g1;
#pragma unroll
  for (int off = 32; off; off >>= 1) ss += __shfl_xor(ss, off);
  const float rr = rsqrtf(ss * (1.f / 128.f) + 1e-6f);
  G[ob + l] = __float2bfloat16(g0 * rr * norm_w[l]);
  G[ob + l + 64] = __float2bfloat16(g1 * rr * norm_w[l + 64]);
}

extern "C" void kernel_launch(void* const* d_in, const int* in_sizes, int n_in,
                              void* d_out, int out_size, void* d_ws, size_t ws_size,
                              hipStream_t stream) {
  const float* X = (const float*)d_in[0];
  const float* W_qkvz = (const float*)d_in[1];
  const float* W_ba = (const float*)d_in[2];
  const float* conv_w = (const float*)d_in[3];
  const float* dt_bias = (const float*)d_in[4];
  const float* A_log = (const float*)d_in[5];
  const float* norm_w = (const float*)d_in[6];
  const float* W_out = (const float*)d_in[7];
  float* out = (float*)d_out;

  float* ws = (float*)d_ws;
  float* qkvz = ws;                                // 12,582,912 f
  float* P = qkvz + (size_t)T_LEN * NQKVZ;         //    262,144 f (ba partials)
  float* QK = P + 262144;                          //  4,194,304 f
  float* V = QK + (size_t)T_LEN * 4096;            //  4,194,304 f
  float* U = V + (size_t)T_LEN * 4096;             //  4,194,304 f
  float* Wb_f = U + (size_t)NCHUNK * 32 * 64 * 128;//  2,097,152 f (bf16 x 4.19M)
  float* KT_f = Wb_f + 2097152;                    //  2,097,152 f
  float* Qg_f = KT_f + 2097152;                    //  2,097,152 f
  float* Bb_f = Qg_f + 2097152;                    //  1,048,576 f (bf16 x 2.10M)
  float* gg = Bb_f + 1048576;                      //     32,768 f
  float* bet = gg + 32768;                         //     32,768 f
  float* gend = bet + 32768;                       //        512 f

  __hip_bfloat16* Wb = (__hip_bfloat16*)Wb_f;
  __hip_bfloat16* KTb = (__hip_bfloat16*)KT_f;
  __hip_bfloat16* Qgb = (__hip_bfloat16*)Qg_f;
  __hip_bfloat16* Bb = (__hip_bfloat16*)Bb_f;
  // lifetime aliases:
  __hip_bfloat16* Wqkvz_t = (__hip_bfloat16*)V;    // spans V+U+Wb+KT (dead after 1st gemm)
  __hip_bfloat16* Xb = (__hip_bfloat16*)Qg_f;      // dead after 1st gemm
  __hip_bfloat16* Gb = (__hip_bfloat16*)Bb_f;      // Bb dead after phaseB
  __hip_bfloat16* Wout_t = (__hip_bfloat16*)qkvz;  // qkvz dead after gate_norm
  float* O = V;                                    // V dead after phase1
  float* Pout = U;                                 // U+Wb+KT dead after phaseB

  cast_bf16<<<dim3(T_LEN * 2048 / 4 / 256), 256, 0, stream>>>(X, Xb, T_LEN * 2048);
  transpose_cast<<<dim3(NQKVZ / 64, 2048 / 64), 256, 0, stream>>>(W_qkvz, Wqkvz_t, 2048, NQKVZ);
  gemm_bf16<<<dim3(NQKVZ / 128, T_LEN / 128, 1), 256, 0, stream>>>(Xb, Wqkvz_t, qkvz, T_LEN, NQKVZ, 2048, 2048);
  ba_gemm<<<dim3(64, 4), 256, 0, stream>>>(X, W_ba, P);
  conv_silu<<<dim3(CDIM / 256, T_LEN / 32), 256, 0, stream>>>(qkvz, conv_w, QK, V);
  l2norm_qk<<<dim3(HK_N, T_LEN), 64, 0, stream>>>(QK);
  compute_gb<<<dim3(T_LEN * 32 / 256), 256, 0, stream>>>(P, dt_bias, A_log, gg, bet);
  phase1<<<dim3(HV_N, NCHUNK), 256, 0, stream>>>(QK, V, gg, bet, U, Wb, KTb, Qgb, Bb, gend);
  phaseB<<<dim3(HV_N, 4), 128, 0, stream>>>(U, Wb, KTb, Qgb, Bb, gend, O);
  gate_norm<<<dim3(HV_N, T_LEN), 64, 0, stream>>>(O, qkvz, norm_w, Gb);
  transpose_cast<<<dim3(2048 / 64, 4096 / 64), 256, 0, stream>>>(W_out, Wout_t, 4096, 2048);
  gemm_bf16<<<dim3(2048 / 128, T_LEN / 128, 4), 256, 0, stream>>>(Gb, Wout_t, Pout, T_LEN, 2048, 1024, 4096);
  add4<<<dim3(T_LEN * 2048 / 4 / 256), 256, 0, stream>>>(Pout, out, T_LEN * 2048);
}